// Round 1
// baseline (4664.130 us; speedup 1.0000x reference)
//
#include <hip/hip_runtime.h>

typedef unsigned int uint_t;

#define NGc     1024
#define Bc      64
#define LD      65            // padded leading dim (bank-conflict-free columns)
#define Rc      1000000
#define NNETc   4000000
#define EREPc   2000000
#define ROTLENc 9000002       // 2 + 9*R

// output element offsets (fp32 elements, concatenated in return order)
#define OFF_H     0
#define OFF_DQ    4194304
#define OFF_EREP  4259840
#define OFF_EORB  4260864
#define OFF_RHO   4326400
#define OFF_EELEC 8520704
#define OFF_EREF  8521728

// ---------------------------------------------------------------- k_hgather
__global__ void k_hgather(const int*   __restrict__ idx,
                          const float* __restrict__ rot_t,
                          const int*   __restrict__ gather_rot,
                          const float* __restrict__ net_vals,
                          float*       __restrict__ out)
{
    int t = blockIdx.x * 256 + threadIdx.x;
    if (t >= NGc * Bc * Bc) return;
    int id = idx[t];
    float hv;
    if (id >= 2 && id < ROTLENc) {
        int k = id - 2;
        int r = k / 9;
        int c = k - r * 9;
        const float* tt = rot_t + (size_t)r * 27 + (size_t)c * 3;
        const int*   gr = gather_rot + (size_t)r * 3;
        int i0 = gr[0], i1 = gr[1], i2 = gr[2];
        i0 = ((unsigned)i0 < (unsigned)NNETc) ? i0 : 0;
        i1 = ((unsigned)i1 < (unsigned)NNETc) ? i1 : 0;
        i2 = ((unsigned)i2 < (unsigned)NNETc) ? i2 : 0;
        hv = tt[0] * net_vals[i0] + tt[1] * net_vals[i1] + tt[2] * net_vals[i2];
    } else {
        hv = (id == 1) ? 1.0f : 0.0f;
    }
    out[OFF_H + t] = hv;
}

// ---------------------------------------------------------------- k_erep_seg
__global__ void k_erep_seg(const float* __restrict__ net_vals,
                           const int*   __restrict__ gather_rep,
                           const int*   __restrict__ segsum,
                           const float* __restrict__ zcounts,
                           const float* __restrict__ ref_vars,
                           float*       __restrict__ out)
{
    __shared__ int   sB[2];
    __shared__ float red[256];
    const int g = blockIdx.x, tid = threadIdx.x;

    if (tid < 2) {
        int target = g + tid;
        int lo = 0, hi = EREPc;
        while (lo < hi) {
            int mid = (lo + hi) >> 1;
            if (segsum[mid] < target) lo = mid + 1; else hi = mid;
        }
        sB[tid] = lo;
    }
    __syncthreads();
    const int s = sB[0], e = sB[1];
    float acc = 0.f;
    for (int i = s + tid; i < e; i += 256) {
        int gi = gather_rep[i];
        gi = ((unsigned)gi < (unsigned)NNETc) ? gi : 0;
        acc += net_vals[gi];
    }
    red[tid] = acc;
    __syncthreads();
    for (int sN = 128; sN > 0; sN >>= 1) {
        if (tid < sN) red[tid] += red[tid + sN];
        __syncthreads();
    }
    if (tid == 0) out[OFF_EREP + g] = red[0];

    if (g == 0 && tid == 0) {
        float er = 0.f;
        for (int j = 0; j < 7; j++) er += zcounts[j] * ref_vars[j];
        out[OFF_EREF] = er;
    }
}

// ---------------------------------------------------------------- k_geom
// One block per geometry. LDS cut to 2 matrices (Ab, Vb) -> 4 blocks/CU.
// phiS read from global (L1-resident, float4).  Jacobi: per-wave in-register
// angles (each wave-iteration owns exactly one pair) -> 2 barriers/round,
// no serial angle phase, no cs/pq LDS arrays.
__global__ __launch_bounds__(256, 4) void k_geom(
    const float* __restrict__ Sg_,  const float* __restrict__ Gg_,
    const float* __restrict__ rho_, const float* __restrict__ qn_,
    const float* __restrict__ mask_,const float* __restrict__ phiS_,
    float* out)
{
    __shared__ float Ab[Bc * LD];
    __shared__ float Vb[Bc * LD];
    __shared__ float dqs[Bc];
    __shared__ float epv[Bc];
    __shared__ float red[256];
    __shared__ float eig[Bc];
    __shared__ int   perm[Bc];
    __shared__ float sOffArr[4];

    const int g    = blockIdx.x;
    const int tid  = threadIdx.x;
    const int lane = tid & 63;
    const int wv   = tid >> 6;
    const size_t gb = (size_t)g * 4096;

    const float* Sp = Sg_  + gb;
    const float* Gp = Gg_  + gb;
    const float* Rp = rho_ + gb;
    const float* Mp = mask_+ gb;
    const float* Pp = phiS_+ gb;
    const float4* P4 = (const float4*)Pp;
    const float* Hp = out + OFF_H + gb;      // fp32 H (written by k_hgather)

    // 1) S -> Vb (temp)
    #pragma unroll
    for (int m = 0; m < 16; m++) {
        int e = tid + m * 256;               // 4096 floats
        int i = e >> 6, j = e & 63;
        Vb[i*LD + j] = Sp[e];
    }
    __syncthreads();

    // 2) dQ[i] = qneutral[i] - sum_j rho_ij * S_ij   (4 threads per row)
    {
        int i = tid >> 2, qr = tid & 3;
        float acc = 0.f;
        #pragma unroll
        for (int jj = 0; jj < 16; jj++) {
            int j = qr * 16 + jj;
            acc += Rp[i * 64 + j] * Vb[i*LD + j];
        }
        acc += __shfl_xor(acc, 1, 64);
        acc += __shfl_xor(acc, 2, 64);
        if (qr == 0) dqs[i] = qn_[(size_t)g * 64 + i] - acc;
    }
    // 3) G -> Ab (temp)
    #pragma unroll
    for (int m = 0; m < 16; m++) {
        int e = tid + m * 256;
        int i = e >> 6, j = e & 63;
        Ab[i*LD + j] = Gp[e];
    }
    __syncthreads();
    // ep = G * dQ
    {
        int i = tid >> 2, qr = tid & 3;
        float acc = 0.f;
        #pragma unroll
        for (int jj = 0; jj < 16; jj++) {
            int j = qr * 16 + jj;
            acc += Ab[i*LD + j] * dqs[j];
        }
        acc += __shfl_xor(acc, 1, 64);
        acc += __shfl_xor(acc, 2, 64);
        if (qr == 0) epv[i] = acc;
    }
    __syncthreads();
    float ener2r = 0.f;
    if (tid < 64) {     // ener2 = 0.5 * dQ^T ep  (kept in a tid-0 register)
        float v = dqs[tid] * epv[tid];
        #pragma unroll
        for (int o = 1; o < 64; o <<= 1) v += __shfl_xor(v, o, 64);
        if (tid == 0) ener2r = 0.5f * v;
    }
    // 4) F = H - 0.5*S*(ep_i + ep_j) -> Ab (overwrites G)
    #pragma unroll
    for (int m = 0; m < 16; m++) {
        int e = tid + m * 256;
        int i = e >> 6, j = e & 63;
        Ab[i*LD + j] = Hp[e] - 0.5f * Vb[i*LD + j] * (epv[i] + epv[j]);
    }
    __syncthreads();

    const int tx = tid & 15, ty = tid >> 4;
    const int row0 = ty * 4, col0 = tx * 4;
    float acc4[4][4];

    // 5) T1 = F @ phiS -> Vb   (phiS from global, float4; S dead)
    #pragma unroll
    for (int u = 0; u < 4; u++)
        #pragma unroll
        for (int v = 0; v < 4; v++) acc4[u][v] = 0.f;
    for (int k = 0; k < 64; k++) {
        float av[4];
        #pragma unroll
        for (int u = 0; u < 4; u++) av[u] = Ab[(row0 + u) * LD + k];
        union { float4 v4; float f[4]; } b4;
        b4.v4 = P4[k * 16 + tx];             // phiS[k, col0..col0+3]
        #pragma unroll
        for (int u = 0; u < 4; u++)
            #pragma unroll
            for (int v = 0; v < 4; v++) acc4[u][v] += av[u] * b4.f[v];
    }
    // nobody reads Vb in step 5 -> write directly
    #pragma unroll
    for (int u = 0; u < 4; u++)
        #pragma unroll
        for (int v = 0; v < 4; v++) Vb[(row0 + u) * LD + col0 + v] = acc4[u][v];
    __syncthreads();

    // 6) fockp = phiS^T @ T1 -> Ab; accumulate ||fockp||_F^2
    #pragma unroll
    for (int u = 0; u < 4; u++)
        #pragma unroll
        for (int v = 0; v < 4; v++) acc4[u][v] = 0.f;
    for (int k = 0; k < 64; k++) {
        union { float4 v4; float f[4]; } a4;
        a4.v4 = P4[k * 16 + ty];             // phiS[k, row0..row0+3]
        float bv[4];
        #pragma unroll
        for (int v = 0; v < 4; v++) bv[v] = Vb[k * LD + col0 + v];
        #pragma unroll
        for (int u = 0; u < 4; u++)
            #pragma unroll
            for (int v = 0; v < 4; v++) acc4[u][v] += a4.f[u] * bv[v];
    }
    {
        float fr = 0.f;
        #pragma unroll
        for (int u = 0; u < 4; u++)
            #pragma unroll
            for (int v = 0; v < 4; v++) {
                Ab[(row0 + u) * LD + col0 + v] = acc4[u][v];   // Ab not read in step 6
                fr += acc4[u][v] * acc4[u][v];
            }
        red[tid] = fr;
    }
    __syncthreads();
    for (int sN = 128; sN > 0; sN >>= 1) {
        if (tid < sN) red[tid] += red[tid + sN];
        __syncthreads();
    }
    const float anorm2 = red[0];             // valid for all threads after barrier

    // 7) V = I (T1 dead; step-6 Vb reads finished at red-reduce barrier)
    #pragma unroll
    for (int m = 0; m < 17; m++) {
        int e = tid + m * 256;
        if (e < Bc * LD) Vb[e] = 0.f;
    }
    __syncthreads();
    if (tid < 64) { Vb[tid * LD + tid] = 1.f; perm[tid] = tid; }

    const float skip2 = anorm2 * 1e-18f;
    const float conv2 = anorm2 * 1e-14f;

    // 8) parallel cyclic Jacobi: 63 rounds/sweep, 32 disjoint pairs/round.
    //    Each wave-iteration owns exactly one pair (pr = wv + 4m), so angles
    //    are computed wave-uniformly in the row phase (broadcast ds_reads of
    //    app/aqq/apq -- untouched by other pairs' row updates since rows are
    //    disjoint) and reused from registers in the col phase.
    for (int sweep = 0; sweep < 10; ++sweep) {
        float offacc = 0.f;                  // wave-uniform off-norm^2 accum
        for (int r = 0; r < 63; r++) {
            float cm[8], sm[8];
            int   pm[8], qm[8];
            // row phase: A <- J^T A  (angle folded in, wave-uniform)
            #pragma unroll
            for (int m = 0; m < 8; m++) {
                int pr = wv + (m << 2);
                int p, q;
                if (pr == 0) { p = 63; q = r; }
                else { p = (r + pr) % 63; q = (r + 63 - pr) % 63; }
                float app = Ab[p*LD + p], aqq = Ab[q*LD + q], apq = Ab[p*LD + q];
                float a2 = apq * apq;
                offacc += a2;
                float c = 1.f, s = 0.f;
                if (a2 > skip2) {            // wave-uniform branch
                    float tau = (aqq - app) / (2.f * apq);
                    float tt = 1.f / (fabsf(tau) + sqrtf(1.f + tau * tau));
                    tt = (tau < 0.f) ? -tt : tt;
                    c = 1.f / sqrtf(1.f + tt * tt);
                    s = tt * c;
                    float x = Ab[p*LD + lane], y = Ab[q*LD + lane];
                    Ab[p*LD + lane] = c * x - s * y;
                    Ab[q*LD + lane] = s * x + c * y;
                }
                pm[m] = p; qm[m] = q; cm[m] = c; sm[m] = s;
            }
            __syncthreads();
            // col phase: A <- A J ; V <- V J  (angles from registers)
            #pragma unroll
            for (int m = 0; m < 8; m++) {
                if (sm[m] != 0.f) {          // s==0 iff rotation skipped
                    int p = pm[m], q = qm[m];
                    float c = cm[m], s = sm[m];
                    float x = Ab[lane*LD + p], y = Ab[lane*LD + q];
                    Ab[lane*LD + p] = c * x - s * y;
                    Ab[lane*LD + q] = s * x + c * y;
                    float xv = Vb[lane*LD + p], yv = Vb[lane*LD + q];
                    Vb[lane*LD + p] = c * xv - s * yv;
                    Vb[lane*LD + q] = s * xv + c * yv;
                }
            }
            __syncthreads();
        }
        if (lane == 0) sOffArr[wv] = offacc;
        __syncthreads();
        if (sOffArr[0] + sOffArr[1] + sOffArr[2] + sOffArr[3] < conv2) break;
        // next write to sOffArr is 63 barrier-separated rounds away -> safe
    }

    // 9) eigenvalues + ascending sort (rank by comparison, index tiebreak)
    if (tid < 64) eig[tid] = Ab[tid * LD + tid];
    __syncthreads();
    if (tid < 64) {
        float e = eig[tid]; int rk = 0;
        for (int j = 0; j < 64; j++) {
            float ej = eig[j];
            rk += (ej < e || (ej == e && j < tid)) ? 1 : 0;
        }
        rk &= 63;
        perm[rk] = tid;
        out[OFF_EORB + (size_t)g * 64 + rk] = e;
    }
    __syncthreads();

    // 10) orb = phiS @ V[:, perm] -> Ab ; then apply occ mask elementwise
    {
        int pc0 = perm[col0 + 0] & 63, pc1 = perm[col0 + 1] & 63;
        int pc2 = perm[col0 + 2] & 63, pc3 = perm[col0 + 3] & 63;
        #pragma unroll
        for (int u = 0; u < 4; u++)
            #pragma unroll
            for (int v = 0; v < 4; v++) acc4[u][v] = 0.f;
        for (int kk = 0; kk < 16; kk++) {
            union { float4 v4; float f[4]; } a0, a1, a2u, a3;
            a0.v4  = P4[(row0 + 0) * 16 + kk];
            a1.v4  = P4[(row0 + 1) * 16 + kk];
            a2u.v4 = P4[(row0 + 2) * 16 + kk];
            a3.v4  = P4[(row0 + 3) * 16 + kk];
            #pragma unroll
            for (int t = 0; t < 4; t++) {
                int k = (kk << 2) + t;
                float b0 = Vb[k*LD + pc0], b1 = Vb[k*LD + pc1];
                float b2 = Vb[k*LD + pc2], b3 = Vb[k*LD + pc3];
                acc4[0][0] += a0.f[t]  * b0; acc4[0][1] += a0.f[t]  * b1;
                acc4[0][2] += a0.f[t]  * b2; acc4[0][3] += a0.f[t]  * b3;
                acc4[1][0] += a1.f[t]  * b0; acc4[1][1] += a1.f[t]  * b1;
                acc4[1][2] += a1.f[t]  * b2; acc4[1][3] += a1.f[t]  * b3;
                acc4[2][0] += a2u.f[t] * b0; acc4[2][1] += a2u.f[t] * b1;
                acc4[2][2] += a2u.f[t] * b2; acc4[2][3] += a2u.f[t] * b3;
                acc4[3][0] += a3.f[t]  * b0; acc4[3][1] += a3.f[t]  * b1;
                acc4[3][2] += a3.f[t]  * b2; acc4[3][3] += a3.f[t]  * b3;
            }
        }
        #pragma unroll
        for (int u = 0; u < 4; u++)
            #pragma unroll
            for (int v = 0; v < 4; v++) Ab[(row0 + u) * LD + col0 + v] = acc4[u][v];
    }
    __syncthreads();
    #pragma unroll
    for (int m = 0; m < 16; m++) {
        int e = tid + m * 256;
        int i = e >> 6, j = e & 63;
        Ab[i*LD + j] *= Mp[e];
    }
    __syncthreads();

    // 11) rho_out = 2 * Ab @ Ab^T ; ener1 = sum(rho_out * H)
    #pragma unroll
    for (int u = 0; u < 4; u++)
        #pragma unroll
        for (int v = 0; v < 4; v++) acc4[u][v] = 0.f;
    for (int k = 0; k < 64; k++) {
        float av[4], bv[4];
        #pragma unroll
        for (int u = 0; u < 4; u++) av[u] = Ab[(row0 + u) * LD + k];
        #pragma unroll
        for (int v = 0; v < 4; v++) bv[v] = Ab[(col0 + v) * LD + k];
        #pragma unroll
        for (int u = 0; u < 4; u++)
            #pragma unroll
            for (int v = 0; v < 4; v++) acc4[u][v] += av[u] * bv[v];
    }
    {
        float e1 = 0.f;
        float* outR = out + OFF_RHO + gb;
        #pragma unroll
        for (int u = 0; u < 4; u++)
            #pragma unroll
            for (int v = 0; v < 4; v++) {
                float rv = 2.f * acc4[u][v];
                int i = row0 + u, j = col0 + v;
                outR[i * 64 + j] = rv;
                e1 += rv * Hp[i * 64 + j];
            }
        red[tid] = e1;
    }
    __syncthreads();
    for (int sN = 128; sN > 0; sN >>= 1) {
        if (tid < sN) red[tid] += red[tid + sN];
        __syncthreads();
    }
    if (tid == 0) out[OFF_EELEC + g] = red[0] + ener2r;
    if (tid < 64) out[OFF_DQ + (size_t)g * 64 + tid] = dqs[tid];
}

// ---------------------------------------------------------------- launcher
extern "C" void kernel_launch(void* const* d_in, const int* in_sizes, int n_in,
                              void* d_out, int out_size, void* d_ws, size_t ws_size,
                              hipStream_t stream)
{
    (void)in_sizes; (void)n_in; (void)out_size; (void)d_ws; (void)ws_size;
    const float* net_vals    = (const float*)d_in[0];
    const float* rot_tensors = (const float*)d_in[1];
    const float* S           = (const float*)d_in[2];
    const float* G           = (const float*)d_in[3];
    const float* rho         = (const float*)d_in[4];
    const float* qneutral    = (const float*)d_in[5];
    const float* mask        = (const float*)d_in[6];
    const float* phiS        = (const float*)d_in[7];
    const float* zcounts     = (const float*)d_in[8];
    const float* ref_vars    = (const float*)d_in[9];
    const int* gather_rot    = (const int*)d_in[10];
    const int* gather_oper   = (const int*)d_in[11];
    const int* gather_rep    = (const int*)d_in[12];
    const int* segsum_rep    = (const int*)d_in[13];

    float* out = (float*)d_out;

    k_hgather<<<16384, 256, 0, stream>>>(gather_oper, rot_tensors, gather_rot,
                                         net_vals, out);
    k_erep_seg<<<NGc, 256, 0, stream>>>(net_vals, gather_rep, segsum_rep,
                                        zcounts, ref_vars, out);
    k_geom<<<NGc, 256, 0, stream>>>(S, G, rho, qneutral, mask, phiS, out);
}

// Round 2
// 3029.634 us; speedup vs baseline: 1.5395x; 1.5395x over previous
//
#include <hip/hip_runtime.h>

typedef unsigned int uint_t;

#define NGc     1024
#define Bc      64
#define LD      65            // padded leading dim (bank-conflict-free columns)
#define Rc      1000000
#define NNETc   4000000
#define EREPc   2000000
#define ROTLENc 9000002       // 2 + 9*R

// output element offsets (fp32 elements, concatenated in return order)
#define OFF_H     0
#define OFF_DQ    4194304
#define OFF_EREP  4259840
#define OFF_EORB  4260864
#define OFF_RHO   4326400
#define OFF_EELEC 8520704
#define OFF_EREF  8521728

// ---------------------------------------------------------------- k_hgather
__global__ void k_hgather(const int*   __restrict__ idx,
                          const float* __restrict__ rot_t,
                          const int*   __restrict__ gather_rot,
                          const float* __restrict__ net_vals,
                          float*       __restrict__ out)
{
    int t = blockIdx.x * 256 + threadIdx.x;
    if (t >= NGc * Bc * Bc) return;
    int id = idx[t];
    float hv;
    if (id >= 2 && id < ROTLENc) {
        int k = id - 2;
        int r = k / 9;
        int c = k - r * 9;
        const float* tt = rot_t + (size_t)r * 27 + (size_t)c * 3;
        const int*   gr = gather_rot + (size_t)r * 3;
        int i0 = gr[0], i1 = gr[1], i2 = gr[2];
        i0 = ((unsigned)i0 < (unsigned)NNETc) ? i0 : 0;
        i1 = ((unsigned)i1 < (unsigned)NNETc) ? i1 : 0;
        i2 = ((unsigned)i2 < (unsigned)NNETc) ? i2 : 0;
        hv = tt[0] * net_vals[i0] + tt[1] * net_vals[i1] + tt[2] * net_vals[i2];
    } else {
        hv = (id == 1) ? 1.0f : 0.0f;
    }
    out[OFF_H + t] = hv;
}

// ---------------------------------------------------------------- k_erep_seg
__global__ void k_erep_seg(const float* __restrict__ net_vals,
                           const int*   __restrict__ gather_rep,
                           const int*   __restrict__ segsum,
                           const float* __restrict__ zcounts,
                           const float* __restrict__ ref_vars,
                           float*       __restrict__ out)
{
    __shared__ int   sB[2];
    __shared__ float red[256];
    const int g = blockIdx.x, tid = threadIdx.x;

    if (tid < 2) {
        int target = g + tid;
        int lo = 0, hi = EREPc;
        while (lo < hi) {
            int mid = (lo + hi) >> 1;
            if (segsum[mid] < target) lo = mid + 1; else hi = mid;
        }
        sB[tid] = lo;
    }
    __syncthreads();
    const int s = sB[0], e = sB[1];
    float acc = 0.f;
    for (int i = s + tid; i < e; i += 256) {
        int gi = gather_rep[i];
        gi = ((unsigned)gi < (unsigned)NNETc) ? gi : 0;
        acc += net_vals[gi];
    }
    red[tid] = acc;
    __syncthreads();
    for (int sN = 128; sN > 0; sN >>= 1) {
        if (tid < sN) red[tid] += red[tid + sN];
        __syncthreads();
    }
    if (tid == 0) out[OFF_EREP + g] = red[0];

    if (g == 0 && tid == 0) {
        float er = 0.f;
        for (int j = 0; j < 7; j++) er += zcounts[j] * ref_vars[j];
        out[OFF_EREF] = er;
    }
}

// ---------------------------------------------------------------- k_geom
// One block per geometry. 2 LDS matrices (Ab, Vb) -> 4 blocks/CU.
// phiS read from global (L1-resident, float4).
// Jacobi: LANE-PARALLEL angle computation (lane l computes pair wv+4*(l&7):
// one div/sqrt chain per round per wave, 8 pairs at once), shuffle-broadcast
// c/s to the wave, 2 barriers/round, no angle LDS arrays.
__global__ __launch_bounds__(256, 4) void k_geom(
    const float* __restrict__ Sg_,  const float* __restrict__ Gg_,
    const float* __restrict__ rho_, const float* __restrict__ qn_,
    const float* __restrict__ mask_,const float* __restrict__ phiS_,
    float* out)
{
    __shared__ float Ab[Bc * LD];
    __shared__ float Vb[Bc * LD];
    __shared__ float dqs[Bc];
    __shared__ float epv[Bc];
    __shared__ float red[256];
    __shared__ float eig[Bc];
    __shared__ int   perm[Bc];
    __shared__ float sOffArr[4];

    const int g    = blockIdx.x;
    const int tid  = threadIdx.x;
    const int lane = tid & 63;
    const int wv   = tid >> 6;
    const size_t gb = (size_t)g * 4096;

    const float* Sp = Sg_  + gb;
    const float* Gp = Gg_  + gb;
    const float* Rp = rho_ + gb;
    const float* Mp = mask_+ gb;
    const float* Pp = phiS_+ gb;
    const float4* P4 = (const float4*)Pp;
    const float* Hp = out + OFF_H + gb;      // fp32 H (written by k_hgather)

    // 1) S -> Vb (temp)
    #pragma unroll
    for (int m = 0; m < 16; m++) {
        int e = tid + m * 256;               // 4096 floats
        int i = e >> 6, j = e & 63;
        Vb[i*LD + j] = Sp[e];
    }
    __syncthreads();

    // 2) dQ[i] = qneutral[i] - sum_j rho_ij * S_ij   (4 threads per row)
    {
        int i = tid >> 2, qr = tid & 3;
        float acc = 0.f;
        #pragma unroll
        for (int jj = 0; jj < 16; jj++) {
            int j = qr * 16 + jj;
            acc += Rp[i * 64 + j] * Vb[i*LD + j];
        }
        acc += __shfl_xor(acc, 1, 64);
        acc += __shfl_xor(acc, 2, 64);
        if (qr == 0) dqs[i] = qn_[(size_t)g * 64 + i] - acc;
    }
    // 3) G -> Ab (temp)
    #pragma unroll
    for (int m = 0; m < 16; m++) {
        int e = tid + m * 256;
        int i = e >> 6, j = e & 63;
        Ab[i*LD + j] = Gp[e];
    }
    __syncthreads();
    // ep = G * dQ
    {
        int i = tid >> 2, qr = tid & 3;
        float acc = 0.f;
        #pragma unroll
        for (int jj = 0; jj < 16; jj++) {
            int j = qr * 16 + jj;
            acc += Ab[i*LD + j] * dqs[j];
        }
        acc += __shfl_xor(acc, 1, 64);
        acc += __shfl_xor(acc, 2, 64);
        if (qr == 0) epv[i] = acc;
    }
    __syncthreads();
    float ener2r = 0.f;
    if (tid < 64) {     // ener2 = 0.5 * dQ^T ep  (kept in a tid-0 register)
        float v = dqs[tid] * epv[tid];
        #pragma unroll
        for (int o = 1; o < 64; o <<= 1) v += __shfl_xor(v, o, 64);
        if (tid == 0) ener2r = 0.5f * v;
    }
    // 4) F = H - 0.5*S*(ep_i + ep_j) -> Ab (overwrites G)
    #pragma unroll
    for (int m = 0; m < 16; m++) {
        int e = tid + m * 256;
        int i = e >> 6, j = e & 63;
        Ab[i*LD + j] = Hp[e] - 0.5f * Vb[i*LD + j] * (epv[i] + epv[j]);
    }
    __syncthreads();

    const int tx = tid & 15, ty = tid >> 4;
    const int row0 = ty * 4, col0 = tx * 4;
    float acc4[4][4];

    // 5) T1 = F @ phiS -> Vb   (phiS from global, float4; S dead)
    #pragma unroll
    for (int u = 0; u < 4; u++)
        #pragma unroll
        for (int v = 0; v < 4; v++) acc4[u][v] = 0.f;
    for (int k = 0; k < 64; k++) {
        float av[4];
        #pragma unroll
        for (int u = 0; u < 4; u++) av[u] = Ab[(row0 + u) * LD + k];
        union { float4 v4; float f[4]; } b4;
        b4.v4 = P4[k * 16 + tx];             // phiS[k, col0..col0+3]
        #pragma unroll
        for (int u = 0; u < 4; u++)
            #pragma unroll
            for (int v = 0; v < 4; v++) acc4[u][v] += av[u] * b4.f[v];
    }
    // nobody reads Vb in step 5 -> write directly
    #pragma unroll
    for (int u = 0; u < 4; u++)
        #pragma unroll
        for (int v = 0; v < 4; v++) Vb[(row0 + u) * LD + col0 + v] = acc4[u][v];
    __syncthreads();

    // 6) fockp = phiS^T @ T1 -> Ab; accumulate ||fockp||_F^2
    #pragma unroll
    for (int u = 0; u < 4; u++)
        #pragma unroll
        for (int v = 0; v < 4; v++) acc4[u][v] = 0.f;
    for (int k = 0; k < 64; k++) {
        union { float4 v4; float f[4]; } a4;
        a4.v4 = P4[k * 16 + ty];             // phiS[k, row0..row0+3]
        float bv[4];
        #pragma unroll
        for (int v = 0; v < 4; v++) bv[v] = Vb[k * LD + col0 + v];
        #pragma unroll
        for (int u = 0; u < 4; u++)
            #pragma unroll
            for (int v = 0; v < 4; v++) acc4[u][v] += a4.f[u] * bv[v];
    }
    {
        float fr = 0.f;
        #pragma unroll
        for (int u = 0; u < 4; u++)
            #pragma unroll
            for (int v = 0; v < 4; v++) {
                Ab[(row0 + u) * LD + col0 + v] = acc4[u][v];   // Ab not read in step 6
                fr += acc4[u][v] * acc4[u][v];
            }
        red[tid] = fr;
    }
    __syncthreads();
    for (int sN = 128; sN > 0; sN >>= 1) {
        if (tid < sN) red[tid] += red[tid + sN];
        __syncthreads();
    }
    const float anorm2 = red[0];             // valid for all threads after barrier

    // 7) V = I (T1 dead; step-6 Vb reads finished at red-reduce barrier)
    #pragma unroll
    for (int m = 0; m < 17; m++) {
        int e = tid + m * 256;
        if (e < Bc * LD) Vb[e] = 0.f;
    }
    __syncthreads();
    if (tid < 64) { Vb[tid * LD + tid] = 1.f; perm[tid] = tid; }

    const float skip2 = anorm2 * 1e-18f;
    const float conv2 = anorm2 * 1e-14f;

    // 8) parallel cyclic Jacobi: 63 rounds/sweep, 32 disjoint pairs/round.
    //    Wave wv owns pairs {wv, wv+4, ..., wv+28}. Lane l computes the angle
    //    for pair wv + 4*(l&7) (lane-parallel: ONE div/sqrt chain per wave per
    //    round covers all 8 pairs; groups of 8 lanes replicate — harmless).
    //    Angle inputs live in pair-disjoint rows, so reading all 8 up-front is
    //    identical to interleaved reads. __shfl broadcasts c/s for updates.
    for (int sweep = 0; sweep < 10; ++sweep) {
        float offacc = 0.f;                  // per-lane; each pair counted 8x
        for (int r = 0; r < 63; r++) {
            // --- lane-parallel angles
            float c, s;
            {
                int mm  = lane & 7;
                int prl = wv + (mm << 2);
                int pl, ql;
                if (prl == 0) { pl = 63; ql = r; }
                else { pl = (r + prl) % 63; ql = (r + 63 - prl) % 63; }
                float app = Ab[pl*LD + pl], aqq = Ab[ql*LD + ql];
                float apq = Ab[pl*LD + ql];
                float a2 = apq * apq;
                offacc += a2;
                c = 1.f; s = 0.f;
                if (a2 > skip2) {
                    float tau = (aqq - app) / (2.f * apq);
                    float tt = 1.f / (fabsf(tau) + sqrtf(1.f + tau * tau));
                    tt = (tau < 0.f) ? -tt : tt;
                    c = 1.f / sqrtf(1.f + tt * tt);
                    s = tt * c;
                }
            }
            float cm[8], sm[8];
            #pragma unroll
            for (int m = 0; m < 8; m++) {
                cm[m] = __shfl(c, m, 64);
                sm[m] = __shfl(s, m, 64);
            }
            // row phase: A <- J^T A
            #pragma unroll
            for (int m = 0; m < 8; m++) {
                if (sm[m] != 0.f) {          // s==0 iff rotation skipped
                    int pr = wv + (m << 2);
                    int p, q;
                    if (pr == 0) { p = 63; q = r; }
                    else { p = (r + pr) % 63; q = (r + 63 - pr) % 63; }
                    float cc = cm[m], ss = sm[m];
                    float x = Ab[p*LD + lane], y = Ab[q*LD + lane];
                    Ab[p*LD + lane] = cc * x - ss * y;
                    Ab[q*LD + lane] = ss * x + cc * y;
                }
            }
            __syncthreads();
            // col phase: A <- A J ; V <- V J
            #pragma unroll
            for (int m = 0; m < 8; m++) {
                if (sm[m] != 0.f) {
                    int pr = wv + (m << 2);
                    int p, q;
                    if (pr == 0) { p = 63; q = r; }
                    else { p = (r + pr) % 63; q = (r + 63 - pr) % 63; }
                    float cc = cm[m], ss = sm[m];
                    float x = Ab[lane*LD + p], y = Ab[lane*LD + q];
                    Ab[lane*LD + p] = cc * x - ss * y;
                    Ab[lane*LD + q] = ss * x + cc * y;
                    float xv = Vb[lane*LD + p], yv = Vb[lane*LD + q];
                    Vb[lane*LD + p] = cc * xv - ss * yv;
                    Vb[lane*LD + q] = ss * xv + cc * yv;
                }
            }
            __syncthreads();
        }
        // sweep-end convergence: each pair's apq^2 counted exactly 8x
        float t2 = offacc;
        #pragma unroll
        for (int o = 1; o < 64; o <<= 1) t2 += __shfl_xor(t2, o, 64);
        if (lane == 0) sOffArr[wv] = t2 * 0.125f;
        __syncthreads();
        if (sOffArr[0] + sOffArr[1] + sOffArr[2] + sOffArr[3] < conv2) break;
        // next write to sOffArr is 63 barrier-separated rounds away -> safe
    }

    // 9) eigenvalues + ascending sort (rank by comparison, index tiebreak)
    if (tid < 64) eig[tid] = Ab[tid * LD + tid];
    __syncthreads();
    if (tid < 64) {
        float e = eig[tid]; int rk = 0;
        for (int j = 0; j < 64; j++) {
            float ej = eig[j];
            rk += (ej < e || (ej == e && j < tid)) ? 1 : 0;
        }
        rk &= 63;
        perm[rk] = tid;
        out[OFF_EORB + (size_t)g * 64 + rk] = e;
    }
    __syncthreads();

    // 10) orb = phiS @ V[:, perm] -> Ab ; then apply occ mask elementwise
    {
        int pc0 = perm[col0 + 0] & 63, pc1 = perm[col0 + 1] & 63;
        int pc2 = perm[col0 + 2] & 63, pc3 = perm[col0 + 3] & 63;
        #pragma unroll
        for (int u = 0; u < 4; u++)
            #pragma unroll
            for (int v = 0; v < 4; v++) acc4[u][v] = 0.f;
        for (int kk = 0; kk < 16; kk++) {
            union { float4 v4; float f[4]; } a0, a1, a2u, a3;
            a0.v4  = P4[(row0 + 0) * 16 + kk];
            a1.v4  = P4[(row0 + 1) * 16 + kk];
            a2u.v4 = P4[(row0 + 2) * 16 + kk];
            a3.v4  = P4[(row0 + 3) * 16 + kk];
            #pragma unroll
            for (int t = 0; t < 4; t++) {
                int k = (kk << 2) + t;
                float b0 = Vb[k*LD + pc0], b1 = Vb[k*LD + pc1];
                float b2 = Vb[k*LD + pc2], b3 = Vb[k*LD + pc3];
                acc4[0][0] += a0.f[t]  * b0; acc4[0][1] += a0.f[t]  * b1;
                acc4[0][2] += a0.f[t]  * b2; acc4[0][3] += a0.f[t]  * b3;
                acc4[1][0] += a1.f[t]  * b0; acc4[1][1] += a1.f[t]  * b1;
                acc4[1][2] += a1.f[t]  * b2; acc4[1][3] += a1.f[t]  * b3;
                acc4[2][0] += a2u.f[t] * b0; acc4[2][1] += a2u.f[t] * b1;
                acc4[2][2] += a2u.f[t] * b2; acc4[2][3] += a2u.f[t] * b3;
                acc4[3][0] += a3.f[t]  * b0; acc4[3][1] += a3.f[t]  * b1;
                acc4[3][2] += a3.f[t]  * b2; acc4[3][3] += a3.f[t]  * b3;
            }
        }
        #pragma unroll
        for (int u = 0; u < 4; u++)
            #pragma unroll
            for (int v = 0; v < 4; v++) Ab[(row0 + u) * LD + col0 + v] = acc4[u][v];
    }
    __syncthreads();
    #pragma unroll
    for (int m = 0; m < 16; m++) {
        int e = tid + m * 256;
        int i = e >> 6, j = e & 63;
        Ab[i*LD + j] *= Mp[e];
    }
    __syncthreads();

    // 11) rho_out = 2 * Ab @ Ab^T ; ener1 = sum(rho_out * H)
    #pragma unroll
    for (int u = 0; u < 4; u++)
        #pragma unroll
        for (int v = 0; v < 4; v++) acc4[u][v] = 0.f;
    for (int k = 0; k < 64; k++) {
        float av[4], bv[4];
        #pragma unroll
        for (int u = 0; u < 4; u++) av[u] = Ab[(row0 + u) * LD + k];
        #pragma unroll
        for (int v = 0; v < 4; v++) bv[v] = Ab[(col0 + v) * LD + k];
        #pragma unroll
        for (int u = 0; u < 4; u++)
            #pragma unroll
            for (int v = 0; v < 4; v++) acc4[u][v] += av[u] * bv[v];
    }
    {
        float e1 = 0.f;
        float* outR = out + OFF_RHO + gb;
        #pragma unroll
        for (int u = 0; u < 4; u++)
            #pragma unroll
            for (int v = 0; v < 4; v++) {
                float rv = 2.f * acc4[u][v];
                int i = row0 + u, j = col0 + v;
                outR[i * 64 + j] = rv;
                e1 += rv * Hp[i * 64 + j];
            }
        red[tid] = e1;
    }
    __syncthreads();
    for (int sN = 128; sN > 0; sN >>= 1) {
        if (tid < sN) red[tid] += red[tid + sN];
        __syncthreads();
    }
    if (tid == 0) out[OFF_EELEC + g] = red[0] + ener2r;
    if (tid < 64) out[OFF_DQ + (size_t)g * 64 + tid] = dqs[tid];
}

// ---------------------------------------------------------------- launcher
extern "C" void kernel_launch(void* const* d_in, const int* in_sizes, int n_in,
                              void* d_out, int out_size, void* d_ws, size_t ws_size,
                              hipStream_t stream)
{
    (void)in_sizes; (void)n_in; (void)out_size; (void)d_ws; (void)ws_size;
    const float* net_vals    = (const float*)d_in[0];
    const float* rot_tensors = (const float*)d_in[1];
    const float* S           = (const float*)d_in[2];
    const float* G           = (const float*)d_in[3];
    const float* rho         = (const float*)d_in[4];
    const float* qneutral    = (const float*)d_in[5];
    const float* mask        = (const float*)d_in[6];
    const float* phiS        = (const float*)d_in[7];
    const float* zcounts     = (const float*)d_in[8];
    const float* ref_vars    = (const float*)d_in[9];
    const int* gather_rot    = (const int*)d_in[10];
    const int* gather_oper   = (const int*)d_in[11];
    const int* gather_rep    = (const int*)d_in[12];
    const int* segsum_rep    = (const int*)d_in[13];

    float* out = (float*)d_out;

    k_hgather<<<16384, 256, 0, stream>>>(gather_oper, rot_tensors, gather_rot,
                                         net_vals, out);
    k_erep_seg<<<NGc, 256, 0, stream>>>(net_vals, gather_rep, segsum_rep,
                                        zcounts, ref_vars, out);
    k_geom<<<NGc, 256, 0, stream>>>(S, G, rho, qneutral, mask, phiS, out);
}

// Round 3
// 2851.621 us; speedup vs baseline: 1.6356x; 1.0624x over previous
//
#include <hip/hip_runtime.h>

typedef unsigned int uint_t;

#define NGc     1024
#define Bc      64
#define LD      67            // 67: col-stride 3 mod 32 (free), apq reads 8m mod 32 (free)
#define Rc      1000000
#define NNETc   4000000
#define EREPc   2000000
#define ROTLENc 9000002       // 2 + 9*R

// output element offsets (fp32 elements, concatenated in return order)
#define OFF_H     0
#define OFF_DQ    4194304
#define OFF_EREP  4259840
#define OFF_EORB  4260864
#define OFF_RHO   4326400
#define OFF_EELEC 8520704
#define OFF_EREF  8521728

// ---------------------------------------------------------------- k_hgather
__global__ void k_hgather(const int*   __restrict__ idx,
                          const float* __restrict__ rot_t,
                          const int*   __restrict__ gather_rot,
                          const float* __restrict__ net_vals,
                          float*       __restrict__ out)
{
    int t = blockIdx.x * 256 + threadIdx.x;
    if (t >= NGc * Bc * Bc) return;
    int id = idx[t];
    float hv;
    if (id >= 2 && id < ROTLENc) {
        int k = id - 2;
        int r = k / 9;
        int c = k - r * 9;
        const float* tt = rot_t + (size_t)r * 27 + (size_t)c * 3;
        const int*   gr = gather_rot + (size_t)r * 3;
        int i0 = gr[0], i1 = gr[1], i2 = gr[2];
        i0 = ((unsigned)i0 < (unsigned)NNETc) ? i0 : 0;
        i1 = ((unsigned)i1 < (unsigned)NNETc) ? i1 : 0;
        i2 = ((unsigned)i2 < (unsigned)NNETc) ? i2 : 0;
        hv = tt[0] * net_vals[i0] + tt[1] * net_vals[i1] + tt[2] * net_vals[i2];
    } else {
        hv = (id == 1) ? 1.0f : 0.0f;
    }
    out[OFF_H + t] = hv;
}

// ---------------------------------------------------------------- k_erep_seg
__global__ void k_erep_seg(const float* __restrict__ net_vals,
                           const int*   __restrict__ gather_rep,
                           const int*   __restrict__ segsum,
                           const float* __restrict__ zcounts,
                           const float* __restrict__ ref_vars,
                           float*       __restrict__ out)
{
    __shared__ int   sB[2];
    __shared__ float red[256];
    const int g = blockIdx.x, tid = threadIdx.x;

    if (tid < 2) {
        int target = g + tid;
        int lo = 0, hi = EREPc;
        while (lo < hi) {
            int mid = (lo + hi) >> 1;
            if (segsum[mid] < target) lo = mid + 1; else hi = mid;
        }
        sB[tid] = lo;
    }
    __syncthreads();
    const int s = sB[0], e = sB[1];
    float acc = 0.f;
    for (int i = s + tid; i < e; i += 256) {
        int gi = gather_rep[i];
        gi = ((unsigned)gi < (unsigned)NNETc) ? gi : 0;
        acc += net_vals[gi];
    }
    red[tid] = acc;
    __syncthreads();
    for (int sN = 128; sN > 0; sN >>= 1) {
        if (tid < sN) red[tid] += red[tid + sN];
        __syncthreads();
    }
    if (tid == 0) out[OFF_EREP + g] = red[0];

    if (g == 0 && tid == 0) {
        float er = 0.f;
        for (int j = 0; j < 7; j++) er += zcounts[j] * ref_vars[j];
        out[OFF_EREF] = er;
    }
}

// ---------------------------------------------------------------- k_geom
// One block per geometry. 2 LDS matrices (Ab, Vb) -> 4 blocks/CU.
// phiS read from global (L1-resident, float4).
// Jacobi: lane-parallel angles + shuffle broadcast; pair indices maintained
// INCREMENTALLY in registers (p_{r+1} = p_r+1 mod 63; pair0 p pinned at 63)
// -> no integer modulo / multiply in the round loop. LD=67 makes the
// divergent angle reads and col-phase accesses bank-conflict-free.
__global__ __launch_bounds__(256, 4) void k_geom(
    const float* __restrict__ Sg_,  const float* __restrict__ Gg_,
    const float* __restrict__ rho_, const float* __restrict__ qn_,
    const float* __restrict__ mask_,const float* __restrict__ phiS_,
    float* out)
{
    __shared__ float Ab[Bc * LD];
    __shared__ float Vb[Bc * LD];
    __shared__ float dqs[Bc];
    __shared__ float epv[Bc];
    __shared__ float red[256];
    __shared__ float eig[Bc];
    __shared__ int   perm[Bc];
    __shared__ float sOffArr[4];

    const int g    = blockIdx.x;
    const int tid  = threadIdx.x;
    const int lane = tid & 63;
    const int wv   = tid >> 6;
    const size_t gb = (size_t)g * 4096;

    const float* Sp = Sg_  + gb;
    const float* Gp = Gg_  + gb;
    const float* Rp = rho_ + gb;
    const float* Mp = mask_+ gb;
    const float* Pp = phiS_+ gb;
    const float4* P4 = (const float4*)Pp;
    const float* Hp = out + OFF_H + gb;      // fp32 H (written by k_hgather)

    // 1) S -> Vb (temp)
    #pragma unroll
    for (int m = 0; m < 16; m++) {
        int e = tid + m * 256;               // 4096 floats
        int i = e >> 6, j = e & 63;
        Vb[i*LD + j] = Sp[e];
    }
    __syncthreads();

    // 2) dQ[i] = qneutral[i] - sum_j rho_ij * S_ij   (4 threads per row)
    {
        int i = tid >> 2, qr = tid & 3;
        float acc = 0.f;
        #pragma unroll
        for (int jj = 0; jj < 16; jj++) {
            int j = qr * 16 + jj;
            acc += Rp[i * 64 + j] * Vb[i*LD + j];
        }
        acc += __shfl_xor(acc, 1, 64);
        acc += __shfl_xor(acc, 2, 64);
        if (qr == 0) dqs[i] = qn_[(size_t)g * 64 + i] - acc;
    }
    // 3) G -> Ab (temp)
    #pragma unroll
    for (int m = 0; m < 16; m++) {
        int e = tid + m * 256;
        int i = e >> 6, j = e & 63;
        Ab[i*LD + j] = Gp[e];
    }
    __syncthreads();
    // ep = G * dQ
    {
        int i = tid >> 2, qr = tid & 3;
        float acc = 0.f;
        #pragma unroll
        for (int jj = 0; jj < 16; jj++) {
            int j = qr * 16 + jj;
            acc += Ab[i*LD + j] * dqs[j];
        }
        acc += __shfl_xor(acc, 1, 64);
        acc += __shfl_xor(acc, 2, 64);
        if (qr == 0) epv[i] = acc;
    }
    __syncthreads();
    float ener2r = 0.f;
    if (tid < 64) {     // ener2 = 0.5 * dQ^T ep  (kept in a tid-0 register)
        float v = dqs[tid] * epv[tid];
        #pragma unroll
        for (int o = 1; o < 64; o <<= 1) v += __shfl_xor(v, o, 64);
        if (tid == 0) ener2r = 0.5f * v;
    }
    // 4) F = H - 0.5*S*(ep_i + ep_j) -> Ab (overwrites G)
    #pragma unroll
    for (int m = 0; m < 16; m++) {
        int e = tid + m * 256;
        int i = e >> 6, j = e & 63;
        Ab[i*LD + j] = Hp[e] - 0.5f * Vb[i*LD + j] * (epv[i] + epv[j]);
    }
    __syncthreads();

    const int tx = tid & 15, ty = tid >> 4;
    const int row0 = ty * 4, col0 = tx * 4;
    float acc4[4][4];

    // 5) T1 = F @ phiS -> Vb   (phiS from global, float4; S dead)
    #pragma unroll
    for (int u = 0; u < 4; u++)
        #pragma unroll
        for (int v = 0; v < 4; v++) acc4[u][v] = 0.f;
    for (int k = 0; k < 64; k++) {
        float av[4];
        #pragma unroll
        for (int u = 0; u < 4; u++) av[u] = Ab[(row0 + u) * LD + k];
        union { float4 v4; float f[4]; } b4;
        b4.v4 = P4[k * 16 + tx];             // phiS[k, col0..col0+3]
        #pragma unroll
        for (int u = 0; u < 4; u++)
            #pragma unroll
            for (int v = 0; v < 4; v++) acc4[u][v] += av[u] * b4.f[v];
    }
    // nobody reads Vb in step 5 -> write directly
    #pragma unroll
    for (int u = 0; u < 4; u++)
        #pragma unroll
        for (int v = 0; v < 4; v++) Vb[(row0 + u) * LD + col0 + v] = acc4[u][v];
    __syncthreads();

    // 6) fockp = phiS^T @ T1 -> Ab; accumulate ||fockp||_F^2
    #pragma unroll
    for (int u = 0; u < 4; u++)
        #pragma unroll
        for (int v = 0; v < 4; v++) acc4[u][v] = 0.f;
    for (int k = 0; k < 64; k++) {
        union { float4 v4; float f[4]; } a4;
        a4.v4 = P4[k * 16 + ty];             // phiS[k, row0..row0+3]
        float bv[4];
        #pragma unroll
        for (int v = 0; v < 4; v++) bv[v] = Vb[k * LD + col0 + v];
        #pragma unroll
        for (int u = 0; u < 4; u++)
            #pragma unroll
            for (int v = 0; v < 4; v++) acc4[u][v] += a4.f[u] * bv[v];
    }
    {
        float fr = 0.f;
        #pragma unroll
        for (int u = 0; u < 4; u++)
            #pragma unroll
            for (int v = 0; v < 4; v++) {
                Ab[(row0 + u) * LD + col0 + v] = acc4[u][v];   // Ab not read in step 6
                fr += acc4[u][v] * acc4[u][v];
            }
        red[tid] = fr;
    }
    __syncthreads();
    for (int sN = 128; sN > 0; sN >>= 1) {
        if (tid < sN) red[tid] += red[tid + sN];
        __syncthreads();
    }
    const float anorm2 = red[0];             // valid for all threads after barrier

    // 7) V = I (T1 dead; step-6 Vb reads finished at red-reduce barrier)
    #pragma unroll
    for (int m = 0; m < 17; m++) {
        int e = tid + m * 256;
        if (e < Bc * LD) Vb[e] = 0.f;
    }
    __syncthreads();
    if (tid < 64) { Vb[tid * LD + tid] = 1.f; perm[tid] = tid; }

    const float skip2 = anorm2 * 1e-18f;
    const float conv2 = anorm2 * 1e-14f;

    // 8) parallel cyclic Jacobi: 63 rounds/sweep, 32 disjoint pairs/round.
    //    Pair indices evolve by +1 mod 63 per round (pair0: p pinned at 63,
    //    q = r). State initialized once and self-continues across sweeps
    //    (p(62)+1 wraps exactly to p(0)).
    int alP, alQ, alPLD, alQLD;              // per-lane angle pair (prl = wv+4*(lane&7))
    {
        int prl = wv + ((lane & 7) << 2);
        alP = (prl == 0) ? 63 : prl;
        alQ = (prl == 0) ? 0  : 63 - prl;
        alPLD = alP * LD;
        alQLD = alQ * LD;
    }
    int wpP[8], wpQ[8], wpPLD[8], wpQLD[8];  // wave-pair arrays (static-indexed)
    #pragma unroll
    for (int m = 0; m < 8; m++) {
        int pr = wv + (m << 2);
        int p = (pr == 0) ? 63 : pr;
        int q = (pr == 0) ? 0  : 63 - pr;
        wpP[m] = p; wpQ[m] = q; wpPLD[m] = p * LD; wpQLD[m] = q * LD;
    }
    const int laneLD = lane * LD;

    for (int sweep = 0; sweep < 10; ++sweep) {
        float offacc = 0.f;                  // per-lane; each pair counted 8x
        for (int r = 0; r < 63; r++) {
            // --- lane-parallel angles (addresses from incremental registers)
            float c, s;
            {
                float app = Ab[alPLD + alP];
                float aqq = Ab[alQLD + alQ];
                float apq = Ab[alPLD + alQ];
                float a2 = apq * apq;
                offacc += a2;
                c = 1.f; s = 0.f;
                if (a2 > skip2) {
                    float tau = (aqq - app) / (2.f * apq);
                    float tt = 1.f / (fabsf(tau) + sqrtf(1.f + tau * tau));
                    tt = (tau < 0.f) ? -tt : tt;
                    c = 1.f / sqrtf(1.f + tt * tt);
                    s = tt * c;
                }
            }
            float cm[8], sm[8];
            #pragma unroll
            for (int m = 0; m < 8; m++) {
                cm[m] = __shfl(c, m, 64);
                sm[m] = __shfl(s, m, 64);
            }
            // row phase: A <- J^T A
            #pragma unroll
            for (int m = 0; m < 8; m++) {
                if (sm[m] != 0.f) {          // s==0 iff rotation skipped
                    int ap = wpPLD[m] + lane, aq = wpQLD[m] + lane;
                    float cc = cm[m], ss = sm[m];
                    float x = Ab[ap], y = Ab[aq];
                    Ab[ap] = cc * x - ss * y;
                    Ab[aq] = ss * x + cc * y;
                }
            }
            __syncthreads();
            // col phase: A <- A J ; V <- V J
            #pragma unroll
            for (int m = 0; m < 8; m++) {
                if (sm[m] != 0.f) {
                    int ap = laneLD + wpP[m], aq = laneLD + wpQ[m];
                    float cc = cm[m], ss = sm[m];
                    float x = Ab[ap], y = Ab[aq];
                    Ab[ap] = cc * x - ss * y;
                    Ab[aq] = ss * x + cc * y;
                    float xv = Vb[ap], yv = Vb[aq];
                    Vb[ap] = cc * xv - ss * yv;
                    Vb[aq] = ss * xv + cc * yv;
                }
            }
            // advance pair indices r -> r+1 (register ops, overlap with barrier)
            {
                int nP   = (alP == 62) ? 0 : ((alP == 63) ? 63 : alP + 1);
                int nPLD = (alP == 62) ? 0 : ((alP == 63) ? alPLD : alPLD + LD);
                int nQ   = (alQ == 62) ? 0 : alQ + 1;
                int nQLD = (alQ == 62) ? 0 : alQLD + LD;
                alP = nP; alPLD = nPLD; alQ = nQ; alQLD = nQLD;
            }
            #pragma unroll
            for (int m = 0; m < 8; m++) {
                int p = wpP[m], q = wpQ[m];
                int nP   = (p == 62) ? 0 : ((p == 63) ? 63 : p + 1);
                int nPLD = (p == 62) ? 0 : ((p == 63) ? wpPLD[m] : wpPLD[m] + LD);
                int nQ   = (q == 62) ? 0 : q + 1;
                int nQLD = (q == 62) ? 0 : wpQLD[m] + LD;
                wpP[m] = nP; wpPLD[m] = nPLD; wpQ[m] = nQ; wpQLD[m] = nQLD;
            }
            __syncthreads();
        }
        // sweep-end convergence: each pair's apq^2 counted exactly 8x
        float t2 = offacc;
        #pragma unroll
        for (int o = 1; o < 64; o <<= 1) t2 += __shfl_xor(t2, o, 64);
        if (lane == 0) sOffArr[wv] = t2 * 0.125f;
        __syncthreads();
        if (sOffArr[0] + sOffArr[1] + sOffArr[2] + sOffArr[3] < conv2) break;
        // next write to sOffArr is 63 barrier-separated rounds away -> safe
    }

    // 9) eigenvalues + ascending sort (rank by comparison, index tiebreak)
    if (tid < 64) eig[tid] = Ab[tid * LD + tid];
    __syncthreads();
    if (tid < 64) {
        float e = eig[tid]; int rk = 0;
        for (int j = 0; j < 64; j++) {
            float ej = eig[j];
            rk += (ej < e || (ej == e && j < tid)) ? 1 : 0;
        }
        rk &= 63;
        perm[rk] = tid;
        out[OFF_EORB + (size_t)g * 64 + rk] = e;
    }
    __syncthreads();

    // 10) orb = phiS @ V[:, perm] -> Ab ; then apply occ mask elementwise
    {
        int pc0 = perm[col0 + 0] & 63, pc1 = perm[col0 + 1] & 63;
        int pc2 = perm[col0 + 2] & 63, pc3 = perm[col0 + 3] & 63;
        #pragma unroll
        for (int u = 0; u < 4; u++)
            #pragma unroll
            for (int v = 0; v < 4; v++) acc4[u][v] = 0.f;
        for (int kk = 0; kk < 16; kk++) {
            union { float4 v4; float f[4]; } a0, a1, a2u, a3;
            a0.v4  = P4[(row0 + 0) * 16 + kk];
            a1.v4  = P4[(row0 + 1) * 16 + kk];
            a2u.v4 = P4[(row0 + 2) * 16 + kk];
            a3.v4  = P4[(row0 + 3) * 16 + kk];
            #pragma unroll
            for (int t = 0; t < 4; t++) {
                int k = (kk << 2) + t;
                float b0 = Vb[k*LD + pc0], b1 = Vb[k*LD + pc1];
                float b2 = Vb[k*LD + pc2], b3 = Vb[k*LD + pc3];
                acc4[0][0] += a0.f[t]  * b0; acc4[0][1] += a0.f[t]  * b1;
                acc4[0][2] += a0.f[t]  * b2; acc4[0][3] += a0.f[t]  * b3;
                acc4[1][0] += a1.f[t]  * b0; acc4[1][1] += a1.f[t]  * b1;
                acc4[1][2] += a1.f[t]  * b2; acc4[1][3] += a1.f[t]  * b3;
                acc4[2][0] += a2u.f[t] * b0; acc4[2][1] += a2u.f[t] * b1;
                acc4[2][2] += a2u.f[t] * b2; acc4[2][3] += a2u.f[t] * b3;
                acc4[3][0] += a3.f[t]  * b0; acc4[3][1] += a3.f[t]  * b1;
                acc4[3][2] += a3.f[t]  * b2; acc4[3][3] += a3.f[t]  * b3;
            }
        }
        #pragma unroll
        for (int u = 0; u < 4; u++)
            #pragma unroll
            for (int v = 0; v < 4; v++) Ab[(row0 + u) * LD + col0 + v] = acc4[u][v];
    }
    __syncthreads();
    #pragma unroll
    for (int m = 0; m < 16; m++) {
        int e = tid + m * 256;
        int i = e >> 6, j = e & 63;
        Ab[i*LD + j] *= Mp[e];
    }
    __syncthreads();

    // 11) rho_out = 2 * Ab @ Ab^T ; ener1 = sum(rho_out * H)
    #pragma unroll
    for (int u = 0; u < 4; u++)
        #pragma unroll
        for (int v = 0; v < 4; v++) acc4[u][v] = 0.f;
    for (int k = 0; k < 64; k++) {
        float av[4], bv[4];
        #pragma unroll
        for (int u = 0; u < 4; u++) av[u] = Ab[(row0 + u) * LD + k];
        #pragma unroll
        for (int v = 0; v < 4; v++) bv[v] = Ab[(col0 + v) * LD + k];
        #pragma unroll
        for (int u = 0; u < 4; u++)
            #pragma unroll
            for (int v = 0; v < 4; v++) acc4[u][v] += av[u] * bv[v];
    }
    {
        float e1 = 0.f;
        float* outR = out + OFF_RHO + gb;
        #pragma unroll
        for (int u = 0; u < 4; u++)
            #pragma unroll
            for (int v = 0; v < 4; v++) {
                float rv = 2.f * acc4[u][v];
                int i = row0 + u, j = col0 + v;
                outR[i * 64 + j] = rv;
                e1 += rv * Hp[i * 64 + j];
            }
        red[tid] = e1;
    }
    __syncthreads();
    for (int sN = 128; sN > 0; sN >>= 1) {
        if (tid < sN) red[tid] += red[tid + sN];
        __syncthreads();
    }
    if (tid == 0) out[OFF_EELEC + g] = red[0] + ener2r;
    if (tid < 64) out[OFF_DQ + (size_t)g * 64 + tid] = dqs[tid];
}

// ---------------------------------------------------------------- launcher
extern "C" void kernel_launch(void* const* d_in, const int* in_sizes, int n_in,
                              void* d_out, int out_size, void* d_ws, size_t ws_size,
                              hipStream_t stream)
{
    (void)in_sizes; (void)n_in; (void)out_size; (void)d_ws; (void)ws_size;
    const float* net_vals    = (const float*)d_in[0];
    const float* rot_tensors = (const float*)d_in[1];
    const float* S           = (const float*)d_in[2];
    const float* G           = (const float*)d_in[3];
    const float* rho         = (const float*)d_in[4];
    const float* qneutral    = (const float*)d_in[5];
    const float* mask        = (const float*)d_in[6];
    const float* phiS        = (const float*)d_in[7];
    const float* zcounts     = (const float*)d_in[8];
    const float* ref_vars    = (const float*)d_in[9];
    const int* gather_rot    = (const int*)d_in[10];
    const int* gather_oper   = (const int*)d_in[11];
    const int* gather_rep    = (const int*)d_in[12];
    const int* segsum_rep    = (const int*)d_in[13];

    float* out = (float*)d_out;

    k_hgather<<<16384, 256, 0, stream>>>(gather_oper, rot_tensors, gather_rot,
                                         net_vals, out);
    k_erep_seg<<<NGc, 256, 0, stream>>>(net_vals, gather_rep, segsum_rep,
                                        zcounts, ref_vars, out);
    k_geom<<<NGc, 256, 0, stream>>>(S, G, rho, qneutral, mask, phiS, out);
}

// Round 4
// 2251.873 us; speedup vs baseline: 2.0712x; 1.2663x over previous
//
#include <hip/hip_runtime.h>

typedef unsigned int uint_t;

#define NGc     1024
#define Bc      64
#define LD      67            // col-stride 3 mod 32 (conflict-free col phase)
#define Rc      1000000
#define NNETc   4000000
#define EREPc   2000000
#define ROTLENc 9000002       // 2 + 9*R

// output element offsets (fp32 elements, concatenated in return order)
#define OFF_H     0
#define OFF_DQ    4194304
#define OFF_EREP  4259840
#define OFF_EORB  4260864
#define OFF_RHO   4326400
#define OFF_EELEC 8520704
#define OFF_EREF  8521728

// ---------------------------------------------------------------- k_rot
// Stage rot[R][9] into workspace: one thread per rotated block.
// Coalesced 108B read of rot_tensors + 3 random net_vals reads + 36B write.
__global__ void k_rot(const float* __restrict__ rot_t,
                      const int*   __restrict__ gather_rot,
                      const float* __restrict__ net_vals,
                      float*       __restrict__ ws)
{
    int r = blockIdx.x * 256 + threadIdx.x;
    if (r >= Rc) return;
    const int* gr = gather_rot + (size_t)r * 3;
    int i0 = gr[0], i1 = gr[1], i2 = gr[2];
    i0 = ((unsigned)i0 < (unsigned)NNETc) ? i0 : 0;
    i1 = ((unsigned)i1 < (unsigned)NNETc) ? i1 : 0;
    i2 = ((unsigned)i2 < (unsigned)NNETc) ? i2 : 0;
    float v0 = net_vals[i0], v1 = net_vals[i1], v2 = net_vals[i2];
    const float* tt = rot_t + (size_t)r * 27;
    float* wp = ws + (size_t)r * 9;
    #pragma unroll
    for (int c = 0; c < 9; c++)
        wp[c] = tt[c*3+0] * v0 + tt[c*3+1] * v1 + tt[c*3+2] * v2;
}

// ---------------------------------------------------------------- k_hgather4
// Pure gather from staged rot array: 4 elements per thread.
__global__ void k_hgather4(const int*   __restrict__ idx,
                           const float* __restrict__ ws,
                           float*       __restrict__ out)
{
    int t4 = blockIdx.x * 256 + threadIdx.x;      // 1,048,576 threads
    const int4 id4 = ((const int4*)idx)[t4];
    float4 hv;
    {
        int id = id4.x;
        hv.x = (id >= 2 && id < ROTLENc) ? ws[id - 2] : ((id == 1) ? 1.0f : 0.0f);
    }
    {
        int id = id4.y;
        hv.y = (id >= 2 && id < ROTLENc) ? ws[id - 2] : ((id == 1) ? 1.0f : 0.0f);
    }
    {
        int id = id4.z;
        hv.z = (id >= 2 && id < ROTLENc) ? ws[id - 2] : ((id == 1) ? 1.0f : 0.0f);
    }
    {
        int id = id4.w;
        hv.w = (id >= 2 && id < ROTLENc) ? ws[id - 2] : ((id == 1) ? 1.0f : 0.0f);
    }
    ((float4*)(out + OFF_H))[t4] = hv;
}

// ---------------------------------------------------------------- k_hgather
// Fallback (no workspace): fused rotation + operator gather.
__global__ void k_hgather(const int*   __restrict__ idx,
                          const float* __restrict__ rot_t,
                          const int*   __restrict__ gather_rot,
                          const float* __restrict__ net_vals,
                          float*       __restrict__ out)
{
    int t = blockIdx.x * 256 + threadIdx.x;
    if (t >= NGc * Bc * Bc) return;
    int id = idx[t];
    float hv;
    if (id >= 2 && id < ROTLENc) {
        int k = id - 2;
        int r = k / 9;
        int c = k - r * 9;
        const float* tt = rot_t + (size_t)r * 27 + (size_t)c * 3;
        const int*   gr = gather_rot + (size_t)r * 3;
        int i0 = gr[0], i1 = gr[1], i2 = gr[2];
        i0 = ((unsigned)i0 < (unsigned)NNETc) ? i0 : 0;
        i1 = ((unsigned)i1 < (unsigned)NNETc) ? i1 : 0;
        i2 = ((unsigned)i2 < (unsigned)NNETc) ? i2 : 0;
        hv = tt[0] * net_vals[i0] + tt[1] * net_vals[i1] + tt[2] * net_vals[i2];
    } else {
        hv = (id == 1) ? 1.0f : 0.0f;
    }
    out[OFF_H + t] = hv;
}

// ---------------------------------------------------------------- k_erep_seg
__global__ void k_erep_seg(const float* __restrict__ net_vals,
                           const int*   __restrict__ gather_rep,
                           const int*   __restrict__ segsum,
                           const float* __restrict__ zcounts,
                           const float* __restrict__ ref_vars,
                           float*       __restrict__ out)
{
    __shared__ int   sB[2];
    __shared__ float red[256];
    const int g = blockIdx.x, tid = threadIdx.x;

    if (tid < 2) {
        int target = g + tid;
        int lo = 0, hi = EREPc;
        while (lo < hi) {
            int mid = (lo + hi) >> 1;
            if (segsum[mid] < target) lo = mid + 1; else hi = mid;
        }
        sB[tid] = lo;
    }
    __syncthreads();
    const int s = sB[0], e = sB[1];
    float acc = 0.f;
    for (int i = s + tid; i < e; i += 256) {
        int gi = gather_rep[i];
        gi = ((unsigned)gi < (unsigned)NNETc) ? gi : 0;
        acc += net_vals[gi];
    }
    red[tid] = acc;
    __syncthreads();
    for (int sN = 128; sN > 0; sN >>= 1) {
        if (tid < sN) red[tid] += red[tid + sN];
        __syncthreads();
    }
    if (tid == 0) out[OFF_EREP + g] = red[0];

    if (g == 0 && tid == 0) {
        float er = 0.f;
        for (int j = 0; j < 7; j++) er += zcounts[j] * ref_vars[j];
        out[OFF_EREF] = er;
    }
}

// ---------------------------------------------------------------- k_geom
// One block per geometry. 2 LDS matrices (Ab, Vb) -> 4 blocks/CU.
// Jacobi: lane-parallel angles; c/s broadcast via v_readlane (no LDS pipe);
// pair-index state seeded from readfirstlane(wv) -> uniform, advance runs
// on SALU; only 4 v_adds/pair for addresses.
__global__ __launch_bounds__(256, 4) void k_geom(
    const float* __restrict__ Sg_,  const float* __restrict__ Gg_,
    const float* __restrict__ rho_, const float* __restrict__ qn_,
    const float* __restrict__ mask_,const float* __restrict__ phiS_,
    float* out)
{
    __shared__ float Ab[Bc * LD];
    __shared__ float Vb[Bc * LD];
    __shared__ float dqs[Bc];
    __shared__ float epv[Bc];
    __shared__ float red[256];
    __shared__ float eig[Bc];
    __shared__ int   perm[Bc];
    __shared__ float sOffArr[4];

    const int g    = blockIdx.x;
    const int tid  = threadIdx.x;
    const int lane = tid & 63;
    const int wv   = tid >> 6;
    const size_t gb = (size_t)g * 4096;

    const float* Sp = Sg_  + gb;
    const float* Gp = Gg_  + gb;
    const float* Rp = rho_ + gb;
    const float* Mp = mask_+ gb;
    const float* Pp = phiS_+ gb;
    const float4* P4 = (const float4*)Pp;
    const float* Hp = out + OFF_H + gb;      // fp32 H (written by gather stage)

    // 1) S -> Vb (temp)
    #pragma unroll
    for (int m = 0; m < 16; m++) {
        int e = tid + m * 256;               // 4096 floats
        int i = e >> 6, j = e & 63;
        Vb[i*LD + j] = Sp[e];
    }
    __syncthreads();

    // 2) dQ[i] = qneutral[i] - sum_j rho_ij * S_ij   (4 threads per row)
    {
        int i = tid >> 2, qr = tid & 3;
        float acc = 0.f;
        #pragma unroll
        for (int jj = 0; jj < 16; jj++) {
            int j = qr * 16 + jj;
            acc += Rp[i * 64 + j] * Vb[i*LD + j];
        }
        acc += __shfl_xor(acc, 1, 64);
        acc += __shfl_xor(acc, 2, 64);
        if (qr == 0) dqs[i] = qn_[(size_t)g * 64 + i] - acc;
    }
    // 3) G -> Ab (temp)
    #pragma unroll
    for (int m = 0; m < 16; m++) {
        int e = tid + m * 256;
        int i = e >> 6, j = e & 63;
        Ab[i*LD + j] = Gp[e];
    }
    __syncthreads();
    // ep = G * dQ
    {
        int i = tid >> 2, qr = tid & 3;
        float acc = 0.f;
        #pragma unroll
        for (int jj = 0; jj < 16; jj++) {
            int j = qr * 16 + jj;
            acc += Ab[i*LD + j] * dqs[j];
        }
        acc += __shfl_xor(acc, 1, 64);
        acc += __shfl_xor(acc, 2, 64);
        if (qr == 0) epv[i] = acc;
    }
    __syncthreads();
    float ener2r = 0.f;
    if (tid < 64) {     // ener2 = 0.5 * dQ^T ep  (kept in a tid-0 register)
        float v = dqs[tid] * epv[tid];
        #pragma unroll
        for (int o = 1; o < 64; o <<= 1) v += __shfl_xor(v, o, 64);
        if (tid == 0) ener2r = 0.5f * v;
    }
    // 4) F = H - 0.5*S*(ep_i + ep_j) -> Ab (overwrites G)
    #pragma unroll
    for (int m = 0; m < 16; m++) {
        int e = tid + m * 256;
        int i = e >> 6, j = e & 63;
        Ab[i*LD + j] = Hp[e] - 0.5f * Vb[i*LD + j] * (epv[i] + epv[j]);
    }
    __syncthreads();

    const int tx = tid & 15, ty = tid >> 4;
    const int row0 = ty * 4, col0 = tx * 4;
    float acc4[4][4];

    // 5) T1 = F @ phiS -> Vb   (phiS from global, float4; S dead)
    #pragma unroll
    for (int u = 0; u < 4; u++)
        #pragma unroll
        for (int v = 0; v < 4; v++) acc4[u][v] = 0.f;
    for (int k = 0; k < 64; k++) {
        float av[4];
        #pragma unroll
        for (int u = 0; u < 4; u++) av[u] = Ab[(row0 + u) * LD + k];
        union { float4 v4; float f[4]; } b4;
        b4.v4 = P4[k * 16 + tx];             // phiS[k, col0..col0+3]
        #pragma unroll
        for (int u = 0; u < 4; u++)
            #pragma unroll
            for (int v = 0; v < 4; v++) acc4[u][v] += av[u] * b4.f[v];
    }
    // nobody reads Vb in step 5 -> write directly
    #pragma unroll
    for (int u = 0; u < 4; u++)
        #pragma unroll
        for (int v = 0; v < 4; v++) Vb[(row0 + u) * LD + col0 + v] = acc4[u][v];
    __syncthreads();

    // 6) fockp = phiS^T @ T1 -> Ab; accumulate ||fockp||_F^2
    #pragma unroll
    for (int u = 0; u < 4; u++)
        #pragma unroll
        for (int v = 0; v < 4; v++) acc4[u][v] = 0.f;
    for (int k = 0; k < 64; k++) {
        union { float4 v4; float f[4]; } a4;
        a4.v4 = P4[k * 16 + ty];             // phiS[k, row0..row0+3]
        float bv[4];
        #pragma unroll
        for (int v = 0; v < 4; v++) bv[v] = Vb[k * LD + col0 + v];
        #pragma unroll
        for (int u = 0; u < 4; u++)
            #pragma unroll
            for (int v = 0; v < 4; v++) acc4[u][v] += a4.f[u] * bv[v];
    }
    {
        float fr = 0.f;
        #pragma unroll
        for (int u = 0; u < 4; u++)
            #pragma unroll
            for (int v = 0; v < 4; v++) {
                Ab[(row0 + u) * LD + col0 + v] = acc4[u][v];   // Ab not read in step 6
                fr += acc4[u][v] * acc4[u][v];
            }
        red[tid] = fr;
    }
    __syncthreads();
    for (int sN = 128; sN > 0; sN >>= 1) {
        if (tid < sN) red[tid] += red[tid + sN];
        __syncthreads();
    }
    const float anorm2 = red[0];             // valid for all threads after barrier

    // 7) V = I (T1 dead; step-6 Vb reads finished at red-reduce barrier)
    #pragma unroll
    for (int m = 0; m < 17; m++) {
        int e = tid + m * 256;
        if (e < Bc * LD) Vb[e] = 0.f;
    }
    __syncthreads();
    if (tid < 64) { Vb[tid * LD + tid] = 1.f; perm[tid] = tid; }

    const float skip2 = anorm2 * 1e-18f;
    const float conv2 = anorm2 * 1e-14f;

    // 8) parallel cyclic Jacobi. Pair indices evolve by +1 mod 63 per round
    //    (pair0: p pinned at 63, q = r). Wave-pair state is UNIFORM (seeded
    //    from readfirstlane(wv)) -> advance runs on SALU.
    int alP, alQ, alPLD, alQLD;              // per-lane angle pair (prl = wv+4*(lane&7))
    {
        int prl = wv + ((lane & 7) << 2);
        alP = (prl == 0) ? 63 : prl;
        alQ = (prl == 0) ? 0  : 63 - prl;
        alPLD = alP * LD;
        alQLD = alQ * LD;
    }
    const int swv = __builtin_amdgcn_readfirstlane(wv);
    int wpP[8], wpQ[8];                      // uniform, static-indexed
    #pragma unroll
    for (int m = 0; m < 8; m++) {
        int pr = swv + (m << 2);
        wpP[m] = (pr == 0) ? 63 : pr;
        wpQ[m] = (pr == 0) ? 0  : 63 - pr;
    }
    const int laneLD = lane * LD;

    for (int sweep = 0; sweep < 10; ++sweep) {
        float offacc = 0.f;                  // per-lane; each pair counted 8x
        for (int r = 0; r < 63; r++) {
            // --- lane-parallel angles (addresses from incremental registers)
            float c, s;
            {
                float app = Ab[alPLD + alP];
                float aqq = Ab[alQLD + alQ];
                float apq = Ab[alPLD + alQ];
                float a2 = apq * apq;
                offacc += a2;
                c = 1.f; s = 0.f;
                if (a2 > skip2) {
                    float tau = (aqq - app) / (2.f * apq);
                    float tt = 1.f / (fabsf(tau) + sqrtf(1.f + tau * tau));
                    tt = (tau < 0.f) ? -tt : tt;
                    c = 1.f / sqrtf(1.f + tt * tt);
                    s = tt * c;
                }
            }
            // broadcast via readlane -> uniform (SGPR) angles
            float cm[8], sm[8];
            #pragma unroll
            for (int m = 0; m < 8; m++) {
                cm[m] = __int_as_float(__builtin_amdgcn_readlane(__float_as_int(c), m));
                sm[m] = __int_as_float(__builtin_amdgcn_readlane(__float_as_int(s), m));
            }
            // row phase: A <- J^T A
            #pragma unroll
            for (int m = 0; m < 8; m++) {
                if (sm[m] != 0.f) {          // uniform -> scalar branch
                    int ap = wpP[m] * LD + lane;   // s_mul + v_add
                    int aq = wpQ[m] * LD + lane;
                    float cc = cm[m], ss = sm[m];
                    float x = Ab[ap], y = Ab[aq];
                    Ab[ap] = cc * x - ss * y;
                    Ab[aq] = ss * x + cc * y;
                }
            }
            __syncthreads();
            // col phase: A <- A J ; V <- V J
            #pragma unroll
            for (int m = 0; m < 8; m++) {
                if (sm[m] != 0.f) {
                    int ap = laneLD + wpP[m];
                    int aq = laneLD + wpQ[m];
                    float cc = cm[m], ss = sm[m];
                    float x = Ab[ap], y = Ab[aq];
                    Ab[ap] = cc * x - ss * y;
                    Ab[aq] = ss * x + cc * y;
                    float xv = Vb[ap], yv = Vb[aq];
                    Vb[ap] = cc * xv - ss * yv;
                    Vb[aq] = ss * xv + cc * yv;
                }
            }
            // advance pair indices r -> r+1 (per-lane: VALU; wave-pair: SALU)
            {
                int nP   = (alP == 62) ? 0 : ((alP == 63) ? 63 : alP + 1);
                int nPLD = (alP == 62) ? 0 : ((alP == 63) ? alPLD : alPLD + LD);
                int nQ   = (alQ == 62) ? 0 : alQ + 1;
                int nQLD = (alQ == 62) ? 0 : alQLD + LD;
                alP = nP; alPLD = nPLD; alQ = nQ; alQLD = nQLD;
            }
            #pragma unroll
            for (int m = 0; m < 8; m++) {
                int p = wpP[m], q = wpQ[m];
                wpP[m] = (p == 62) ? 0 : ((p == 63) ? 63 : p + 1);
                wpQ[m] = (q == 62) ? 0 : q + 1;
            }
            __syncthreads();
        }
        // sweep-end convergence: each pair's apq^2 counted exactly 8x
        float t2 = offacc;
        #pragma unroll
        for (int o = 1; o < 64; o <<= 1) t2 += __shfl_xor(t2, o, 64);
        if (lane == 0) sOffArr[wv] = t2 * 0.125f;
        __syncthreads();
        if (sOffArr[0] + sOffArr[1] + sOffArr[2] + sOffArr[3] < conv2) break;
        // next write to sOffArr is 63 barrier-separated rounds away -> safe
    }

    // 9) eigenvalues + ascending sort (rank by comparison, index tiebreak)
    if (tid < 64) eig[tid] = Ab[tid * LD + tid];
    __syncthreads();
    if (tid < 64) {
        float e = eig[tid]; int rk = 0;
        for (int j = 0; j < 64; j++) {
            float ej = eig[j];
            rk += (ej < e || (ej == e && j < tid)) ? 1 : 0;
        }
        rk &= 63;
        perm[rk] = tid;
        out[OFF_EORB + (size_t)g * 64 + rk] = e;
    }
    __syncthreads();

    // 10) orb = phiS @ V[:, perm] -> Ab ; then apply occ mask elementwise
    {
        int pc0 = perm[col0 + 0] & 63, pc1 = perm[col0 + 1] & 63;
        int pc2 = perm[col0 + 2] & 63, pc3 = perm[col0 + 3] & 63;
        #pragma unroll
        for (int u = 0; u < 4; u++)
            #pragma unroll
            for (int v = 0; v < 4; v++) acc4[u][v] = 0.f;
        for (int kk = 0; kk < 16; kk++) {
            union { float4 v4; float f[4]; } a0, a1, a2u, a3;
            a0.v4  = P4[(row0 + 0) * 16 + kk];
            a1.v4  = P4[(row0 + 1) * 16 + kk];
            a2u.v4 = P4[(row0 + 2) * 16 + kk];
            a3.v4  = P4[(row0 + 3) * 16 + kk];
            #pragma unroll
            for (int t = 0; t < 4; t++) {
                int k = (kk << 2) + t;
                float b0 = Vb[k*LD + pc0], b1 = Vb[k*LD + pc1];
                float b2 = Vb[k*LD + pc2], b3 = Vb[k*LD + pc3];
                acc4[0][0] += a0.f[t]  * b0; acc4[0][1] += a0.f[t]  * b1;
                acc4[0][2] += a0.f[t]  * b2; acc4[0][3] += a0.f[t]  * b3;
                acc4[1][0] += a1.f[t]  * b0; acc4[1][1] += a1.f[t]  * b1;
                acc4[1][2] += a1.f[t]  * b2; acc4[1][3] += a1.f[t]  * b3;
                acc4[2][0] += a2u.f[t] * b0; acc4[2][1] += a2u.f[t] * b1;
                acc4[2][2] += a2u.f[t] * b2; acc4[2][3] += a2u.f[t] * b3;
                acc4[3][0] += a3.f[t]  * b0; acc4[3][1] += a3.f[t]  * b1;
                acc4[3][2] += a3.f[t]  * b2; acc4[3][3] += a3.f[t]  * b3;
            }
        }
        #pragma unroll
        for (int u = 0; u < 4; u++)
            #pragma unroll
            for (int v = 0; v < 4; v++) Ab[(row0 + u) * LD + col0 + v] = acc4[u][v];
    }
    __syncthreads();
    #pragma unroll
    for (int m = 0; m < 16; m++) {
        int e = tid + m * 256;
        int i = e >> 6, j = e & 63;
        Ab[i*LD + j] *= Mp[e];
    }
    __syncthreads();

    // 11) rho_out = 2 * Ab @ Ab^T ; ener1 = sum(rho_out * H)
    #pragma unroll
    for (int u = 0; u < 4; u++)
        #pragma unroll
        for (int v = 0; v < 4; v++) acc4[u][v] = 0.f;
    for (int k = 0; k < 64; k++) {
        float av[4], bv[4];
        #pragma unroll
        for (int u = 0; u < 4; u++) av[u] = Ab[(row0 + u) * LD + k];
        #pragma unroll
        for (int v = 0; v < 4; v++) bv[v] = Ab[(col0 + v) * LD + k];
        #pragma unroll
        for (int u = 0; u < 4; u++)
            #pragma unroll
            for (int v = 0; v < 4; v++) acc4[u][v] += av[u] * bv[v];
    }
    {
        float e1 = 0.f;
        float* outR = out + OFF_RHO + gb;
        #pragma unroll
        for (int u = 0; u < 4; u++)
            #pragma unroll
            for (int v = 0; v < 4; v++) {
                float rv = 2.f * acc4[u][v];
                int i = row0 + u, j = col0 + v;
                outR[i * 64 + j] = rv;
                e1 += rv * Hp[i * 64 + j];
            }
        red[tid] = e1;
    }
    __syncthreads();
    for (int sN = 128; sN > 0; sN >>= 1) {
        if (tid < sN) red[tid] += red[tid + sN];
        __syncthreads();
    }
    if (tid == 0) out[OFF_EELEC + g] = red[0] + ener2r;
    if (tid < 64) out[OFF_DQ + (size_t)g * 64 + tid] = dqs[tid];
}

// ---------------------------------------------------------------- launcher
extern "C" void kernel_launch(void* const* d_in, const int* in_sizes, int n_in,
                              void* d_out, int out_size, void* d_ws, size_t ws_size,
                              hipStream_t stream)
{
    (void)in_sizes; (void)n_in; (void)out_size;
    const float* net_vals    = (const float*)d_in[0];
    const float* rot_tensors = (const float*)d_in[1];
    const float* S           = (const float*)d_in[2];
    const float* G           = (const float*)d_in[3];
    const float* rho         = (const float*)d_in[4];
    const float* qneutral    = (const float*)d_in[5];
    const float* mask        = (const float*)d_in[6];
    const float* phiS        = (const float*)d_in[7];
    const float* zcounts     = (const float*)d_in[8];
    const float* ref_vars    = (const float*)d_in[9];
    const int* gather_rot    = (const int*)d_in[10];
    const int* gather_oper   = (const int*)d_in[11];
    const int* gather_rep    = (const int*)d_in[12];
    const int* segsum_rep    = (const int*)d_in[13];

    float* out = (float*)d_out;

    const size_t need = (size_t)Rc * 9 * sizeof(float);   // 36 MB
    if (d_ws && ws_size >= need) {
        k_rot<<<(Rc + 255) / 256, 256, 0, stream>>>(rot_tensors, gather_rot,
                                                    net_vals, (float*)d_ws);
        k_hgather4<<<4096, 256, 0, stream>>>(gather_oper, (const float*)d_ws, out);
    } else {
        k_hgather<<<16384, 256, 0, stream>>>(gather_oper, rot_tensors, gather_rot,
                                             net_vals, out);
    }
    k_erep_seg<<<NGc, 256, 0, stream>>>(net_vals, gather_rep, segsum_rep,
                                        zcounts, ref_vars, out);
    k_geom<<<NGc, 256, 0, stream>>>(S, G, rho, qneutral, mask, phiS, out);
}

// Round 5
// 1846.942 us; speedup vs baseline: 2.5253x; 1.2192x over previous
//
#include <hip/hip_runtime.h>

typedef unsigned int uint_t;

#define NGc     1024
#define Bc      64
#define LD      66            // even (b64-aligned rows: 264B); (2P+c)&31 -> ~2-way
#define Rc      1000000
#define NNETc   4000000
#define EREPc   2000000
#define ROTLENc 9000002       // 2 + 9*R

// output element offsets (fp32 elements, concatenated in return order)
#define OFF_H     0
#define OFF_DQ    4194304
#define OFF_EREP  4259840
#define OFF_EORB  4260864
#define OFF_RHO   4326400
#define OFF_EELEC 8520704
#define OFF_EREF  8521728

// ---------------------------------------------------------------- k_rot
__global__ void k_rot(const float* __restrict__ rot_t,
                      const int*   __restrict__ gather_rot,
                      const float* __restrict__ net_vals,
                      float*       __restrict__ ws)
{
    int r = blockIdx.x * 256 + threadIdx.x;
    if (r >= Rc) return;
    const int* gr = gather_rot + (size_t)r * 3;
    int i0 = gr[0], i1 = gr[1], i2 = gr[2];
    i0 = ((unsigned)i0 < (unsigned)NNETc) ? i0 : 0;
    i1 = ((unsigned)i1 < (unsigned)NNETc) ? i1 : 0;
    i2 = ((unsigned)i2 < (unsigned)NNETc) ? i2 : 0;
    float v0 = net_vals[i0], v1 = net_vals[i1], v2 = net_vals[i2];
    const float* tt = rot_t + (size_t)r * 27;
    float* wp = ws + (size_t)r * 9;
    #pragma unroll
    for (int c = 0; c < 9; c++)
        wp[c] = tt[c*3+0] * v0 + tt[c*3+1] * v1 + tt[c*3+2] * v2;
}

// ---------------------------------------------------------------- k_hgather4
__global__ void k_hgather4(const int*   __restrict__ idx,
                           const float* __restrict__ ws,
                           float*       __restrict__ out)
{
    int t4 = blockIdx.x * 256 + threadIdx.x;      // 1,048,576 threads
    const int4 id4 = ((const int4*)idx)[t4];
    float4 hv;
    {
        int id = id4.x;
        hv.x = (id >= 2 && id < ROTLENc) ? ws[id - 2] : ((id == 1) ? 1.0f : 0.0f);
    }
    {
        int id = id4.y;
        hv.y = (id >= 2 && id < ROTLENc) ? ws[id - 2] : ((id == 1) ? 1.0f : 0.0f);
    }
    {
        int id = id4.z;
        hv.z = (id >= 2 && id < ROTLENc) ? ws[id - 2] : ((id == 1) ? 1.0f : 0.0f);
    }
    {
        int id = id4.w;
        hv.w = (id >= 2 && id < ROTLENc) ? ws[id - 2] : ((id == 1) ? 1.0f : 0.0f);
    }
    ((float4*)(out + OFF_H))[t4] = hv;
}

// ---------------------------------------------------------------- k_hgather
// Fallback (no workspace): fused rotation + operator gather.
__global__ void k_hgather(const int*   __restrict__ idx,
                          const float* __restrict__ rot_t,
                          const int*   __restrict__ gather_rot,
                          const float* __restrict__ net_vals,
                          float*       __restrict__ out)
{
    int t = blockIdx.x * 256 + threadIdx.x;
    if (t >= NGc * Bc * Bc) return;
    int id = idx[t];
    float hv;
    if (id >= 2 && id < ROTLENc) {
        int k = id - 2;
        int r = k / 9;
        int c = k - r * 9;
        const float* tt = rot_t + (size_t)r * 27 + (size_t)c * 3;
        const int*   gr = gather_rot + (size_t)r * 3;
        int i0 = gr[0], i1 = gr[1], i2 = gr[2];
        i0 = ((unsigned)i0 < (unsigned)NNETc) ? i0 : 0;
        i1 = ((unsigned)i1 < (unsigned)NNETc) ? i1 : 0;
        i2 = ((unsigned)i2 < (unsigned)NNETc) ? i2 : 0;
        hv = tt[0] * net_vals[i0] + tt[1] * net_vals[i1] + tt[2] * net_vals[i2];
    } else {
        hv = (id == 1) ? 1.0f : 0.0f;
    }
    out[OFF_H + t] = hv;
}

// ---------------------------------------------------------------- k_erep_seg
__global__ void k_erep_seg(const float* __restrict__ net_vals,
                           const int*   __restrict__ gather_rep,
                           const int*   __restrict__ segsum,
                           const float* __restrict__ zcounts,
                           const float* __restrict__ ref_vars,
                           float*       __restrict__ out)
{
    __shared__ int   sB[2];
    __shared__ float red[256];
    const int g = blockIdx.x, tid = threadIdx.x;

    if (tid < 2) {
        int target = g + tid;
        int lo = 0, hi = EREPc;
        while (lo < hi) {
            int mid = (lo + hi) >> 1;
            if (segsum[mid] < target) lo = mid + 1; else hi = mid;
        }
        sB[tid] = lo;
    }
    __syncthreads();
    const int s = sB[0], e = sB[1];
    float acc = 0.f;
    for (int i = s + tid; i < e; i += 256) {
        int gi = gather_rep[i];
        gi = ((unsigned)gi < (unsigned)NNETc) ? gi : 0;
        acc += net_vals[gi];
    }
    red[tid] = acc;
    __syncthreads();
    for (int sN = 128; sN > 0; sN >>= 1) {
        if (tid < sN) red[tid] += red[tid + sN];
        __syncthreads();
    }
    if (tid == 0) out[OFF_EREP + g] = red[0];

    if (g == 0 && tid == 0) {
        float er = 0.f;
        for (int j = 0; j < 7; j++) er += zcounts[j] * ref_vars[j];
        out[OFF_EREF] = er;
    }
}

// ---------------------------------------------------------------- k_geom
// One block per geometry. 2 LDS matrices (Ab, Vt) -> 4 blocks/CU.
// Jacobi round = ONE fused in-place 2x2-block update (A traffic halved vs
// row+col phases): thread t owns row-pair i=t&31 x col-pairs {t>>5 + 8k}.
// out(2x2) = Ri^T * [2x2] * Rj -- blocks are closed under the update, so
// in-place is race-free. Angles: each thread computes its own row-pair's
// angle (8x redundant, no readlane chain); col angles via 32-entry LDS
// broadcast. V kept TRANSPOSED (Vt <- Ji^T Vt = row update, own angle,
// float2-vectorized over an 8-col chunk per thread).
__global__ __launch_bounds__(256, 4) void k_geom(
    const float* __restrict__ Sg_,  const float* __restrict__ Gg_,
    const float* __restrict__ rho_, const float* __restrict__ qn_,
    const float* __restrict__ mask_,const float* __restrict__ phiS_,
    float* out)
{
    __shared__ float Ab[Bc * LD];
    __shared__ float Vb[Bc * LD];        // holds T1 temp, then Vt
    __shared__ float dqs[Bc];
    __shared__ float epv[Bc];
    __shared__ float red[256];
    __shared__ float eig[Bc];
    __shared__ int   perm[Bc];
    __shared__ float csC[32], csS[32];
    __shared__ float sOffArr[4];

    const int g    = blockIdx.x;
    const int tid  = threadIdx.x;
    const int wv   = tid >> 6;
    const size_t gb = (size_t)g * 4096;

    const float* Sp = Sg_  + gb;
    const float* Gp = Gg_  + gb;
    const float* Rp = rho_ + gb;
    const float* Mp = mask_+ gb;
    const float* Pp = phiS_+ gb;
    const float4* P4 = (const float4*)Pp;
    const float* Hp = out + OFF_H + gb;      // fp32 H (written by gather stage)

    // 1) S -> Vb (temp)
    #pragma unroll
    for (int m = 0; m < 16; m++) {
        int e = tid + m * 256;               // 4096 floats
        int i = e >> 6, j = e & 63;
        Vb[i*LD + j] = Sp[e];
    }
    __syncthreads();

    // 2) dQ[i] = qneutral[i] - sum_j rho_ij * S_ij   (4 threads per row)
    {
        int i = tid >> 2, qr = tid & 3;
        float acc = 0.f;
        #pragma unroll
        for (int jj = 0; jj < 16; jj++) {
            int j = qr * 16 + jj;
            acc += Rp[i * 64 + j] * Vb[i*LD + j];
        }
        acc += __shfl_xor(acc, 1, 64);
        acc += __shfl_xor(acc, 2, 64);
        if (qr == 0) dqs[i] = qn_[(size_t)g * 64 + i] - acc;
    }
    // 3) G -> Ab (temp)
    #pragma unroll
    for (int m = 0; m < 16; m++) {
        int e = tid + m * 256;
        int i = e >> 6, j = e & 63;
        Ab[i*LD + j] = Gp[e];
    }
    __syncthreads();
    // ep = G * dQ
    {
        int i = tid >> 2, qr = tid & 3;
        float acc = 0.f;
        #pragma unroll
        for (int jj = 0; jj < 16; jj++) {
            int j = qr * 16 + jj;
            acc += Ab[i*LD + j] * dqs[j];
        }
        acc += __shfl_xor(acc, 1, 64);
        acc += __shfl_xor(acc, 2, 64);
        if (qr == 0) epv[i] = acc;
    }
    __syncthreads();
    float ener2r = 0.f;
    if (tid < 64) {     // ener2 = 0.5 * dQ^T ep  (kept in a tid-0 register)
        float v = dqs[tid] * epv[tid];
        #pragma unroll
        for (int o = 1; o < 64; o <<= 1) v += __shfl_xor(v, o, 64);
        if (tid == 0) ener2r = 0.5f * v;
    }
    // 4) F = H - 0.5*S*(ep_i + ep_j) -> Ab (overwrites G)
    #pragma unroll
    for (int m = 0; m < 16; m++) {
        int e = tid + m * 256;
        int i = e >> 6, j = e & 63;
        Ab[i*LD + j] = Hp[e] - 0.5f * Vb[i*LD + j] * (epv[i] + epv[j]);
    }
    __syncthreads();

    const int tx = tid & 15, ty = tid >> 4;
    const int row0 = ty * 4, col0 = tx * 4;
    float acc4[4][4];

    // 5) T1 = F @ phiS -> Vb   (phiS from global, float4; S dead)
    #pragma unroll
    for (int u = 0; u < 4; u++)
        #pragma unroll
        for (int v = 0; v < 4; v++) acc4[u][v] = 0.f;
    for (int k = 0; k < 64; k++) {
        float av[4];
        #pragma unroll
        for (int u = 0; u < 4; u++) av[u] = Ab[(row0 + u) * LD + k];
        union { float4 v4; float f[4]; } b4;
        b4.v4 = P4[k * 16 + tx];             // phiS[k, col0..col0+3]
        #pragma unroll
        for (int u = 0; u < 4; u++)
            #pragma unroll
            for (int v = 0; v < 4; v++) acc4[u][v] += av[u] * b4.f[v];
    }
    #pragma unroll
    for (int u = 0; u < 4; u++)
        #pragma unroll
        for (int v = 0; v < 4; v++) Vb[(row0 + u) * LD + col0 + v] = acc4[u][v];
    __syncthreads();

    // 6) fockp = phiS^T @ T1 -> Ab; accumulate ||fockp||_F^2
    #pragma unroll
    for (int u = 0; u < 4; u++)
        #pragma unroll
        for (int v = 0; v < 4; v++) acc4[u][v] = 0.f;
    for (int k = 0; k < 64; k++) {
        union { float4 v4; float f[4]; } a4;
        a4.v4 = P4[k * 16 + ty];             // phiS[k, row0..row0+3]
        float bv[4];
        #pragma unroll
        for (int v = 0; v < 4; v++) bv[v] = Vb[k * LD + col0 + v];
        #pragma unroll
        for (int u = 0; u < 4; u++)
            #pragma unroll
            for (int v = 0; v < 4; v++) acc4[u][v] += a4.f[u] * bv[v];
    }
    {
        float fr = 0.f;
        #pragma unroll
        for (int u = 0; u < 4; u++)
            #pragma unroll
            for (int v = 0; v < 4; v++) {
                Ab[(row0 + u) * LD + col0 + v] = acc4[u][v];
                fr += acc4[u][v] * acc4[u][v];
            }
        red[tid] = fr;
    }
    __syncthreads();
    for (int sN = 128; sN > 0; sN >>= 1) {
        if (tid < sN) red[tid] += red[tid + sN];
        __syncthreads();
    }
    const float anorm2 = red[0];             // valid for all threads after barrier

    // 7) Vt = I (T1 dead)
    #pragma unroll
    for (int m = 0; m < 17; m++) {
        int e = tid + m * 256;
        if (e < Bc * LD) Vb[e] = 0.f;
    }
    __syncthreads();
    if (tid < 64) { Vb[tid * LD + tid] = 1.f; perm[tid] = tid; }

    const float skip2 = anorm2 * 1e-18f;
    const float conv2 = anorm2 * 1e-14f;

    // 8) fused-2x2 parallel cyclic Jacobi: 63 rounds/sweep.
    //    Thread state: own row-pair (iP,iQ, x66 bases) + 4 col-pairs.
    //    All pairs advance +1 mod 63 per round (pair0: p pinned at 63).
    const int myi = tid & 31;                // own (row-)pair index
    const int jb  = tid >> 5;                // col-pair base (0..7)
    const int cb  = jb << 3;                 // Vt col chunk (8 cols)

    int iP, iQ, iP66, iQ66;
    {
        iP = (myi == 0) ? 63 : myi;
        iQ = (myi == 0) ? 0  : 63 - myi;
        iP66 = iP * LD; iQ66 = iQ * LD;
    }
    int jP[4], jQ[4];
    #pragma unroll
    for (int k = 0; k < 4; k++) {
        int x = jb + (k << 3);
        jP[k] = (x == 0) ? 63 : x;
        jQ[k] = (x == 0) ? 0  : 63 - x;
    }

    for (int sweep = 0; sweep < 10; ++sweep) {
        float offacc = 0.f;                  // own pair counted once/round; 8x over block
        for (int r = 0; r < 63; r++) {
            // --- own angle (every thread; redundancy 8x across block)
            float cO = 1.f, sO = 0.f;
            {
                float app = Ab[iP66 + iP];
                float aqq = Ab[iQ66 + iQ];
                float apq = Ab[iP66 + iQ];
                float a2 = apq * apq;
                offacc += a2;
                if (a2 > skip2) {
                    float tau = (aqq - app) / (2.f * apq);
                    float tt = 1.f / (fabsf(tau) + sqrtf(1.f + tau * tau));
                    tt = (tau < 0.f) ? -tt : tt;
                    cO = 1.f / sqrtf(1.f + tt * tt);
                    sO = tt * cO;
                }
            }
            if (tid < 32) { csC[tid] = cO; csS[tid] = sO; }
            __syncthreads();                 // angles visible; all angle reads done

            // --- fused A update: 4 disjoint 2x2 blocks per thread, in place
            #pragma unroll
            for (int k = 0; k < 4; k++) {
                float cc = csC[jb + (k << 3)];
                float ss = csS[jb + (k << 3)];
                if (sO != 0.f || ss != 0.f) {
                    int aPP = iP66 + jP[k], aPQ = iP66 + jQ[k];
                    int aQP = iQ66 + jP[k], aQQ = iQ66 + jQ[k];
                    float a = Ab[aPP], b = Ab[aPQ];
                    float d = Ab[aQP], e = Ab[aQQ];
                    float a1 = cc * a - ss * b, b1 = ss * a + cc * b;
                    float d1 = cc * d - ss * e, e1 = ss * d + cc * e;
                    Ab[aPP] = cO * a1 - sO * d1;
                    Ab[aQP] = sO * a1 + cO * d1;
                    Ab[aPQ] = cO * b1 - sO * e1;
                    Ab[aQQ] = sO * b1 + cO * e1;
                }
            }
            // --- Vt row update (own angle, 8-col chunk, float2)
            if (sO != 0.f) {
                float2* vp = (float2*)&Vb[iP66 + cb];
                float2* vq = (float2*)&Vb[iQ66 + cb];
                #pragma unroll
                for (int e2 = 0; e2 < 4; e2++) {
                    float2 xp = vp[e2], xq = vq[e2];
                    float2 np, nq;
                    np.x = cO * xp.x - sO * xq.x;  np.y = cO * xp.y - sO * xq.y;
                    nq.x = sO * xp.x + cO * xq.x;  nq.y = sO * xp.y + cO * xq.y;
                    vp[e2] = np; vq[e2] = nq;
                }
            }
            // --- advance pair indices r -> r+1 (wraps continue across sweeps)
            {
                int nP   = (iP == 62) ? 0 : ((iP == 63) ? 63 : iP + 1);
                int nP66 = (iP == 62) ? 0 : ((iP == 63) ? iP66 : iP66 + LD);
                int nQ   = (iQ == 62) ? 0 : iQ + 1;
                int nQ66 = (iQ == 62) ? 0 : iQ66 + LD;
                iP = nP; iP66 = nP66; iQ = nQ; iQ66 = nQ66;
            }
            #pragma unroll
            for (int k = 0; k < 4; k++) {
                int p = jP[k], q = jQ[k];
                jP[k] = (p == 62) ? 0 : ((p == 63) ? 63 : p + 1);
                jQ[k] = (q == 62) ? 0 : q + 1;
            }
            __syncthreads();                 // all writes done before next angles
        }
        // sweep-end convergence: each pair's apq^2 counted exactly 8x per block
        float t2 = offacc;
        #pragma unroll
        for (int o = 1; o < 64; o <<= 1) t2 += __shfl_xor(t2, o, 64);
        if ((tid & 63) == 0) sOffArr[wv] = t2;
        __syncthreads();
        if ((sOffArr[0] + sOffArr[1] + sOffArr[2] + sOffArr[3]) * 0.125f * 0.25f < conv2)
            break;
        // (each pair appears twice per wave: lanes x and x+32 -> wave sum = 2x
        //  per-pair; 4 waves -> 8x total; scale 1/32... handled: 0.125*0.25 = 1/32)
    }

    // 9) eigenvalues + ascending sort (rank by comparison, index tiebreak)
    if (tid < 64) eig[tid] = Ab[tid * LD + tid];
    __syncthreads();
    if (tid < 64) {
        float e = eig[tid]; int rk = 0;
        for (int j = 0; j < 64; j++) {
            float ej = eig[j];
            rk += (ej < e || (ej == e && j < tid)) ? 1 : 0;
        }
        rk &= 63;
        perm[rk] = tid;
        out[OFF_EORB + (size_t)g * 64 + rk] = e;
    }
    __syncthreads();

    // 10) orb = phiS @ V[:, perm] -> Ab ; V[k][pc] = Vt[pc][k]
    {
        int pc0 = perm[col0 + 0] & 63, pc1 = perm[col0 + 1] & 63;
        int pc2 = perm[col0 + 2] & 63, pc3 = perm[col0 + 3] & 63;
        #pragma unroll
        for (int u = 0; u < 4; u++)
            #pragma unroll
            for (int v = 0; v < 4; v++) acc4[u][v] = 0.f;
        for (int kk = 0; kk < 16; kk++) {
            union { float4 v4; float f[4]; } a0, a1, a2u, a3;
            a0.v4  = P4[(row0 + 0) * 16 + kk];
            a1.v4  = P4[(row0 + 1) * 16 + kk];
            a2u.v4 = P4[(row0 + 2) * 16 + kk];
            a3.v4  = P4[(row0 + 3) * 16 + kk];
            #pragma unroll
            for (int t = 0; t < 4; t++) {
                int k = (kk << 2) + t;
                float b0 = Vb[pc0*LD + k], b1 = Vb[pc1*LD + k];
                float b2 = Vb[pc2*LD + k], b3 = Vb[pc3*LD + k];
                acc4[0][0] += a0.f[t]  * b0; acc4[0][1] += a0.f[t]  * b1;
                acc4[0][2] += a0.f[t]  * b2; acc4[0][3] += a0.f[t]  * b3;
                acc4[1][0] += a1.f[t]  * b0; acc4[1][1] += a1.f[t]  * b1;
                acc4[1][2] += a1.f[t]  * b2; acc4[1][3] += a1.f[t]  * b3;
                acc4[2][0] += a2u.f[t] * b0; acc4[2][1] += a2u.f[t] * b1;
                acc4[2][2] += a2u.f[t] * b2; acc4[2][3] += a2u.f[t] * b3;
                acc4[3][0] += a3.f[t]  * b0; acc4[3][1] += a3.f[t]  * b1;
                acc4[3][2] += a3.f[t]  * b2; acc4[3][3] += a3.f[t]  * b3;
            }
        }
        __syncthreads();
        #pragma unroll
        for (int u = 0; u < 4; u++)
            #pragma unroll
            for (int v = 0; v < 4; v++) Ab[(row0 + u) * LD + col0 + v] = acc4[u][v];
    }
    __syncthreads();
    #pragma unroll
    for (int m = 0; m < 16; m++) {
        int e = tid + m * 256;
        int i = e >> 6, j = e & 63;
        Ab[i*LD + j] *= Mp[e];
    }
    __syncthreads();

    // 11) rho_out = 2 * Ab @ Ab^T ; ener1 = sum(rho_out * H)
    #pragma unroll
    for (int u = 0; u < 4; u++)
        #pragma unroll
        for (int v = 0; v < 4; v++) acc4[u][v] = 0.f;
    for (int k = 0; k < 64; k++) {
        float av[4], bv[4];
        #pragma unroll
        for (int u = 0; u < 4; u++) av[u] = Ab[(row0 + u) * LD + k];
        #pragma unroll
        for (int v = 0; v < 4; v++) bv[v] = Ab[(col0 + v) * LD + k];
        #pragma unroll
        for (int u = 0; u < 4; u++)
            #pragma unroll
            for (int v = 0; v < 4; v++) acc4[u][v] += av[u] * bv[v];
    }
    {
        float e1 = 0.f;
        float* outR = out + OFF_RHO + gb;
        #pragma unroll
        for (int u = 0; u < 4; u++)
            #pragma unroll
            for (int v = 0; v < 4; v++) {
                float rv = 2.f * acc4[u][v];
                int i = row0 + u, j = col0 + v;
                outR[i * 64 + j] = rv;
                e1 += rv * Hp[i * 64 + j];
            }
        red[tid] = e1;
    }
    __syncthreads();
    for (int sN = 128; sN > 0; sN >>= 1) {
        if (tid < sN) red[tid] += red[tid + sN];
        __syncthreads();
    }
    if (tid == 0) out[OFF_EELEC + g] = red[0] + ener2r;
    if (tid < 64) out[OFF_DQ + (size_t)g * 64 + tid] = dqs[tid];
}

// ---------------------------------------------------------------- launcher
extern "C" void kernel_launch(void* const* d_in, const int* in_sizes, int n_in,
                              void* d_out, int out_size, void* d_ws, size_t ws_size,
                              hipStream_t stream)
{
    (void)in_sizes; (void)n_in; (void)out_size;
    const float* net_vals    = (const float*)d_in[0];
    const float* rot_tensors = (const float*)d_in[1];
    const float* S           = (const float*)d_in[2];
    const float* G           = (const float*)d_in[3];
    const float* rho         = (const float*)d_in[4];
    const float* qneutral    = (const float*)d_in[5];
    const float* mask        = (const float*)d_in[6];
    const float* phiS        = (const float*)d_in[7];
    const float* zcounts     = (const float*)d_in[8];
    const float* ref_vars    = (const float*)d_in[9];
    const int* gather_rot    = (const int*)d_in[10];
    const int* gather_oper   = (const int*)d_in[11];
    const int* gather_rep    = (const int*)d_in[12];
    const int* segsum_rep    = (const int*)d_in[13];

    float* out = (float*)d_out;

    const size_t need = (size_t)Rc * 9 * sizeof(float);   // 36 MB
    if (d_ws && ws_size >= need) {
        k_rot<<<(Rc + 255) / 256, 256, 0, stream>>>(rot_tensors, gather_rot,
                                                    net_vals, (float*)d_ws);
        k_hgather4<<<4096, 256, 0, stream>>>(gather_oper, (const float*)d_ws, out);
    } else {
        k_hgather<<<16384, 256, 0, stream>>>(gather_oper, rot_tensors, gather_rot,
                                             net_vals, out);
    }
    k_erep_seg<<<NGc, 256, 0, stream>>>(net_vals, gather_rep, segsum_rep,
                                        zcounts, ref_vars, out);
    k_geom<<<NGc, 256, 0, stream>>>(S, G, rho, qneutral, mask, phiS, out);
}

// Round 6
// 1470.143 us; speedup vs baseline: 3.1726x; 1.2563x over previous
//
#include <hip/hip_runtime.h>

typedef unsigned int uint_t;

#define NGc     1024
#define Bc      64
#define LD      66            // even (b64-aligned rows: 264B); (2P+c)&31 -> ~2-way
#define Rc      1000000
#define NNETc   4000000
#define EREPc   2000000
#define ROTLENc 9000002       // 2 + 9*R

// output element offsets (fp32 elements, concatenated in return order)
#define OFF_H     0
#define OFF_DQ    4194304
#define OFF_EREP  4259840
#define OFF_EORB  4260864
#define OFF_RHO   4326400
#define OFF_EELEC 8520704
#define OFF_EREF  8521728

// ---------------------------------------------------------------- k_rot
__global__ void k_rot(const float* __restrict__ rot_t,
                      const int*   __restrict__ gather_rot,
                      const float* __restrict__ net_vals,
                      float*       __restrict__ ws)
{
    int r = blockIdx.x * 256 + threadIdx.x;
    if (r >= Rc) return;
    const int* gr = gather_rot + (size_t)r * 3;
    int i0 = gr[0], i1 = gr[1], i2 = gr[2];
    i0 = ((unsigned)i0 < (unsigned)NNETc) ? i0 : 0;
    i1 = ((unsigned)i1 < (unsigned)NNETc) ? i1 : 0;
    i2 = ((unsigned)i2 < (unsigned)NNETc) ? i2 : 0;
    float v0 = net_vals[i0], v1 = net_vals[i1], v2 = net_vals[i2];
    const float* tt = rot_t + (size_t)r * 27;
    float* wp = ws + (size_t)r * 9;
    #pragma unroll
    for (int c = 0; c < 9; c++)
        wp[c] = tt[c*3+0] * v0 + tt[c*3+1] * v1 + tt[c*3+2] * v2;
}

// ---------------------------------------------------------------- k_hgather4
__global__ void k_hgather4(const int*   __restrict__ idx,
                           const float* __restrict__ ws,
                           float*       __restrict__ out)
{
    int t4 = blockIdx.x * 256 + threadIdx.x;      // 1,048,576 threads
    const int4 id4 = ((const int4*)idx)[t4];
    float4 hv;
    {
        int id = id4.x;
        hv.x = (id >= 2 && id < ROTLENc) ? ws[id - 2] : ((id == 1) ? 1.0f : 0.0f);
    }
    {
        int id = id4.y;
        hv.y = (id >= 2 && id < ROTLENc) ? ws[id - 2] : ((id == 1) ? 1.0f : 0.0f);
    }
    {
        int id = id4.z;
        hv.z = (id >= 2 && id < ROTLENc) ? ws[id - 2] : ((id == 1) ? 1.0f : 0.0f);
    }
    {
        int id = id4.w;
        hv.w = (id >= 2 && id < ROTLENc) ? ws[id - 2] : ((id == 1) ? 1.0f : 0.0f);
    }
    ((float4*)(out + OFF_H))[t4] = hv;
}

// ---------------------------------------------------------------- k_hgather
// Fallback (no workspace): fused rotation + operator gather.
__global__ void k_hgather(const int*   __restrict__ idx,
                          const float* __restrict__ rot_t,
                          const int*   __restrict__ gather_rot,
                          const float* __restrict__ net_vals,
                          float*       __restrict__ out)
{
    int t = blockIdx.x * 256 + threadIdx.x;
    if (t >= NGc * Bc * Bc) return;
    int id = idx[t];
    float hv;
    if (id >= 2 && id < ROTLENc) {
        int k = id - 2;
        int r = k / 9;
        int c = k - r * 9;
        const float* tt = rot_t + (size_t)r * 27 + (size_t)c * 3;
        const int*   gr = gather_rot + (size_t)r * 3;
        int i0 = gr[0], i1 = gr[1], i2 = gr[2];
        i0 = ((unsigned)i0 < (unsigned)NNETc) ? i0 : 0;
        i1 = ((unsigned)i1 < (unsigned)NNETc) ? i1 : 0;
        i2 = ((unsigned)i2 < (unsigned)NNETc) ? i2 : 0;
        hv = tt[0] * net_vals[i0] + tt[1] * net_vals[i1] + tt[2] * net_vals[i2];
    } else {
        hv = (id == 1) ? 1.0f : 0.0f;
    }
    out[OFF_H + t] = hv;
}

// ---------------------------------------------------------------- k_erep_seg
__global__ void k_erep_seg(const float* __restrict__ net_vals,
                           const int*   __restrict__ gather_rep,
                           const int*   __restrict__ segsum,
                           const float* __restrict__ zcounts,
                           const float* __restrict__ ref_vars,
                           float*       __restrict__ out)
{
    __shared__ int   sB[2];
    __shared__ float red[256];
    const int g = blockIdx.x, tid = threadIdx.x;

    if (tid < 2) {
        int target = g + tid;
        int lo = 0, hi = EREPc;
        while (lo < hi) {
            int mid = (lo + hi) >> 1;
            if (segsum[mid] < target) lo = mid + 1; else hi = mid;
        }
        sB[tid] = lo;
    }
    __syncthreads();
    const int s = sB[0], e = sB[1];
    float acc = 0.f;
    for (int i = s + tid; i < e; i += 256) {
        int gi = gather_rep[i];
        gi = ((unsigned)gi < (unsigned)NNETc) ? gi : 0;
        acc += net_vals[gi];
    }
    red[tid] = acc;
    __syncthreads();
    for (int sN = 128; sN > 0; sN >>= 1) {
        if (tid < sN) red[tid] += red[tid + sN];
        __syncthreads();
    }
    if (tid == 0) out[OFF_EREP + g] = red[0];

    if (g == 0 && tid == 0) {
        float er = 0.f;
        for (int j = 0; j < 7; j++) er += zcounts[j] * ref_vars[j];
        out[OFF_EREF] = er;
    }
}

// ---------------------------------------------------------------- k_geom
// One block per geometry. 2 LDS matrices (Ab, Vt) -> 4 blocks/CU.
// Jacobi round: phase1 = wave-0 lanes 0-31 compute all 32 angles with
// fast-math intrinsics, write float2 csCS[32], and apply the closed-form
// DIAGONAL 2x2 update (pp'=app-t*apq, qq'=aqq+t*apq, pq'=qp'=0).
// phase2 = all threads apply fused in-place 2x2 off-diag block updates
// (skipping the diag-k, handled in phase1) + transposed-V row update.
// Waves 1-3 skip phase1 entirely (wave-uniform branch) -> 8x-redundant
// angle chain eliminated for 3/4 of threads.
__global__ __launch_bounds__(256, 4) void k_geom(
    const float* __restrict__ Sg_,  const float* __restrict__ Gg_,
    const float* __restrict__ rho_, const float* __restrict__ qn_,
    const float* __restrict__ mask_,const float* __restrict__ phiS_,
    float* out)
{
    __shared__ float Ab[Bc * LD];
    __shared__ float Vb[Bc * LD];        // holds T1 temp, then Vt
    __shared__ float dqs[Bc];
    __shared__ float epv[Bc];
    __shared__ float red[256];
    __shared__ float eig[Bc];
    __shared__ int   perm[Bc];
    __shared__ float2 csCS[32];
    __shared__ float sOffArr[4];

    const int g    = blockIdx.x;
    const int tid  = threadIdx.x;
    const int wv   = tid >> 6;
    const size_t gb = (size_t)g * 4096;
    (void)wv;

    const float* Sp = Sg_  + gb;
    const float* Gp = Gg_  + gb;
    const float* Rp = rho_ + gb;
    const float* Mp = mask_+ gb;
    const float* Pp = phiS_+ gb;
    const float4* P4 = (const float4*)Pp;
    const float* Hp = out + OFF_H + gb;      // fp32 H (written by gather stage)

    // 1) S -> Vb (temp)
    #pragma unroll
    for (int m = 0; m < 16; m++) {
        int e = tid + m * 256;               // 4096 floats
        int i = e >> 6, j = e & 63;
        Vb[i*LD + j] = Sp[e];
    }
    __syncthreads();

    // 2) dQ[i] = qneutral[i] - sum_j rho_ij * S_ij   (4 threads per row)
    {
        int i = tid >> 2, qr = tid & 3;
        float acc = 0.f;
        #pragma unroll
        for (int jj = 0; jj < 16; jj++) {
            int j = qr * 16 + jj;
            acc += Rp[i * 64 + j] * Vb[i*LD + j];
        }
        acc += __shfl_xor(acc, 1, 64);
        acc += __shfl_xor(acc, 2, 64);
        if (qr == 0) dqs[i] = qn_[(size_t)g * 64 + i] - acc;
    }
    // 3) G -> Ab (temp)
    #pragma unroll
    for (int m = 0; m < 16; m++) {
        int e = tid + m * 256;
        int i = e >> 6, j = e & 63;
        Ab[i*LD + j] = Gp[e];
    }
    __syncthreads();
    // ep = G * dQ
    {
        int i = tid >> 2, qr = tid & 3;
        float acc = 0.f;
        #pragma unroll
        for (int jj = 0; jj < 16; jj++) {
            int j = qr * 16 + jj;
            acc += Ab[i*LD + j] * dqs[j];
        }
        acc += __shfl_xor(acc, 1, 64);
        acc += __shfl_xor(acc, 2, 64);
        if (qr == 0) epv[i] = acc;
    }
    __syncthreads();
    float ener2r = 0.f;
    if (tid < 64) {     // ener2 = 0.5 * dQ^T ep  (kept in a tid-0 register)
        float v = dqs[tid] * epv[tid];
        #pragma unroll
        for (int o = 1; o < 64; o <<= 1) v += __shfl_xor(v, o, 64);
        if (tid == 0) ener2r = 0.5f * v;
    }
    // 4) F = H - 0.5*S*(ep_i + ep_j) -> Ab (overwrites G)
    #pragma unroll
    for (int m = 0; m < 16; m++) {
        int e = tid + m * 256;
        int i = e >> 6, j = e & 63;
        Ab[i*LD + j] = Hp[e] - 0.5f * Vb[i*LD + j] * (epv[i] + epv[j]);
    }
    __syncthreads();

    const int tx = tid & 15, ty = tid >> 4;
    const int row0 = ty * 4, col0 = tx * 4;
    float acc4[4][4];

    // 5) T1 = F @ phiS -> Vb   (phiS from global, float4; S dead)
    #pragma unroll
    for (int u = 0; u < 4; u++)
        #pragma unroll
        for (int v = 0; v < 4; v++) acc4[u][v] = 0.f;
    for (int k = 0; k < 64; k++) {
        float av[4];
        #pragma unroll
        for (int u = 0; u < 4; u++) av[u] = Ab[(row0 + u) * LD + k];
        union { float4 v4; float f[4]; } b4;
        b4.v4 = P4[k * 16 + tx];             // phiS[k, col0..col0+3]
        #pragma unroll
        for (int u = 0; u < 4; u++)
            #pragma unroll
            for (int v = 0; v < 4; v++) acc4[u][v] += av[u] * b4.f[v];
    }
    #pragma unroll
    for (int u = 0; u < 4; u++)
        #pragma unroll
        for (int v = 0; v < 4; v++) Vb[(row0 + u) * LD + col0 + v] = acc4[u][v];
    __syncthreads();

    // 6) fockp = phiS^T @ T1 -> Ab; accumulate ||fockp||_F^2
    #pragma unroll
    for (int u = 0; u < 4; u++)
        #pragma unroll
        for (int v = 0; v < 4; v++) acc4[u][v] = 0.f;
    for (int k = 0; k < 64; k++) {
        union { float4 v4; float f[4]; } a4;
        a4.v4 = P4[k * 16 + ty];             // phiS[k, row0..row0+3]
        float bv[4];
        #pragma unroll
        for (int v = 0; v < 4; v++) bv[v] = Vb[k * LD + col0 + v];
        #pragma unroll
        for (int u = 0; u < 4; u++)
            #pragma unroll
            for (int v = 0; v < 4; v++) acc4[u][v] += a4.f[u] * bv[v];
    }
    {
        float fr = 0.f;
        #pragma unroll
        for (int u = 0; u < 4; u++)
            #pragma unroll
            for (int v = 0; v < 4; v++) {
                Ab[(row0 + u) * LD + col0 + v] = acc4[u][v];
                fr += acc4[u][v] * acc4[u][v];
            }
        red[tid] = fr;
    }
    __syncthreads();
    for (int sN = 128; sN > 0; sN >>= 1) {
        if (tid < sN) red[tid] += red[tid + sN];
        __syncthreads();
    }
    const float anorm2 = red[0];             // valid for all threads after barrier

    // 7) Vt = I (T1 dead)
    #pragma unroll
    for (int m = 0; m < 17; m++) {
        int e = tid + m * 256;
        if (e < Bc * LD) Vb[e] = 0.f;
    }
    __syncthreads();
    if (tid < 64) { Vb[tid * LD + tid] = 1.f; perm[tid] = tid; }

    const float skip2 = anorm2 * 1e-18f;
    const float conv2 = anorm2 * 4e-14f;     // == r5's effective threshold

    // 8) fused-2x2 parallel cyclic Jacobi: 63 rounds/sweep.
    const int myi = tid & 31;                // own (row-)pair index
    const int jb  = tid >> 5;                // col-pair base (0..7)
    const int cb  = jb << 3;                 // Vt col chunk (8 cols)

    int iP, iQ, iP66, iQ66;
    {
        iP = (myi == 0) ? 63 : myi;
        iQ = (myi == 0) ? 0  : 63 - myi;
        iP66 = iP * LD; iQ66 = iQ * LD;
    }
    int jP[4], jQ[4];
    #pragma unroll
    for (int k = 0; k < 4; k++) {
        int x = jb + (k << 3);
        jP[k] = (x == 0) ? 63 : x;
        jQ[k] = (x == 0) ? 0  : 63 - x;
    }
    const bool dgk[4] = { myi == jb, myi == jb + 8,
                          myi == jb + 16, myi == jb + 24 };

    for (int sweep = 0; sweep < 10; ++sweep) {
        float offacc = 0.f;                  // valid in lanes tid<32 only
        for (int r = 0; r < 63; r++) {
            // --- phase 1: wave0 lanes 0-31: angles + diagonal update
            if (tid < 32) {
                float app = Ab[iP66 + iP];
                float aqq = Ab[iQ66 + iQ];
                float apq = Ab[iP66 + iQ];
                float a2 = apq * apq;
                offacc += a2;
                float c = 1.f, s = 0.f;
                if (a2 > skip2) {
                    float tau = (aqq - app) * __builtin_amdgcn_rcpf(apq + apq);
                    float tt = __builtin_amdgcn_rcpf(
                        fabsf(tau) + __builtin_amdgcn_sqrtf(1.f + tau * tau));
                    tt = (tau < 0.f) ? -tt : tt;
                    c = __builtin_amdgcn_rsqf(1.f + tt * tt);
                    s = tt * c;
                    // closed-form diagonal 2x2 (both symmetric copies)
                    Ab[iP66 + iP] = app - tt * apq;
                    Ab[iQ66 + iQ] = aqq + tt * apq;
                    Ab[iP66 + iQ] = 0.f;
                    Ab[iQ66 + iP] = 0.f;
                }
                csCS[myi] = make_float2(c, s);
            }
            __syncthreads();                 // angles + diag visible

            // --- phase 2: fused off-diag A update (4 blocks/thread, in place)
            float2 me = csCS[myi];
            const float cO = me.x, sO = me.y;
            #pragma unroll
            for (int k = 0; k < 4; k++) {
                float2 cj = csCS[jb + (k << 3)];
                float cc = cj.x, ss = cj.y;
                if (!dgk[k] && (sO != 0.f || ss != 0.f)) {
                    int aPP = iP66 + jP[k], aPQ = iP66 + jQ[k];
                    int aQP = iQ66 + jP[k], aQQ = iQ66 + jQ[k];
                    float a = Ab[aPP], b = Ab[aPQ];
                    float d = Ab[aQP], e = Ab[aQQ];
                    float a1 = cc * a - ss * b, b1 = ss * a + cc * b;
                    float d1 = cc * d - ss * e, e1 = ss * d + cc * e;
                    Ab[aPP] = cO * a1 - sO * d1;
                    Ab[aQP] = sO * a1 + cO * d1;
                    Ab[aPQ] = cO * b1 - sO * e1;
                    Ab[aQQ] = sO * b1 + cO * e1;
                }
            }
            // --- Vt row update (own angle, 8-col chunk, float2)
            if (sO != 0.f) {
                float2* vp = (float2*)&Vb[iP66 + cb];
                float2* vq = (float2*)&Vb[iQ66 + cb];
                #pragma unroll
                for (int e2 = 0; e2 < 4; e2++) {
                    float2 xp = vp[e2], xq = vq[e2];
                    float2 np, nq;
                    np.x = cO * xp.x - sO * xq.x;  np.y = cO * xp.y - sO * xq.y;
                    nq.x = sO * xp.x + cO * xq.x;  nq.y = sO * xp.y + cO * xq.y;
                    vp[e2] = np; vq[e2] = nq;
                }
            }
            // --- advance pair indices r -> r+1 (wraps continue across sweeps)
            {
                int nP   = (iP == 62) ? 0 : ((iP == 63) ? 63 : iP + 1);
                int nP66 = (iP == 62) ? 0 : ((iP == 63) ? iP66 : iP66 + LD);
                int nQ   = (iQ == 62) ? 0 : iQ + 1;
                int nQ66 = (iQ == 62) ? 0 : iQ66 + LD;
                iP = nP; iP66 = nP66; iQ = nQ; iQ66 = nQ66;
            }
            #pragma unroll
            for (int k = 0; k < 4; k++) {
                int p = jP[k], q = jQ[k];
                jP[k] = (p == 62) ? 0 : ((p == 63) ? 63 : p + 1);
                jQ[k] = (q == 62) ? 0 : q + 1;
            }
            __syncthreads();                 // all writes done before next angles
        }
        // sweep-end convergence: each pair counted exactly once (lanes 0-31)
        float t2 = offacc;
        #pragma unroll
        for (int o = 1; o < 32; o <<= 1) t2 += __shfl_xor(t2, o, 64);
        if (tid == 0) sOffArr[0] = t2;
        __syncthreads();
        if (sOffArr[0] < conv2) break;
        // next write to sOffArr is 63 barrier-separated rounds away -> safe
    }

    // 9) eigenvalues + ascending sort (rank by comparison, index tiebreak)
    if (tid < 64) eig[tid] = Ab[tid * LD + tid];
    __syncthreads();
    if (tid < 64) {
        float e = eig[tid]; int rk = 0;
        for (int j = 0; j < 64; j++) {
            float ej = eig[j];
            rk += (ej < e || (ej == e && j < tid)) ? 1 : 0;
        }
        rk &= 63;
        perm[rk] = tid;
        out[OFF_EORB + (size_t)g * 64 + rk] = e;
    }
    __syncthreads();

    // 10) orb = phiS @ V[:, perm] -> Ab ; V[k][pc] = Vt[pc][k]
    {
        int pc0 = perm[col0 + 0] & 63, pc1 = perm[col0 + 1] & 63;
        int pc2 = perm[col0 + 2] & 63, pc3 = perm[col0 + 3] & 63;
        #pragma unroll
        for (int u = 0; u < 4; u++)
            #pragma unroll
            for (int v = 0; v < 4; v++) acc4[u][v] = 0.f;
        for (int kk = 0; kk < 16; kk++) {
            union { float4 v4; float f[4]; } a0, a1, a2u, a3;
            a0.v4  = P4[(row0 + 0) * 16 + kk];
            a1.v4  = P4[(row0 + 1) * 16 + kk];
            a2u.v4 = P4[(row0 + 2) * 16 + kk];
            a3.v4  = P4[(row0 + 3) * 16 + kk];
            #pragma unroll
            for (int t = 0; t < 4; t++) {
                int k = (kk << 2) + t;
                float b0 = Vb[pc0*LD + k], b1 = Vb[pc1*LD + k];
                float b2 = Vb[pc2*LD + k], b3 = Vb[pc3*LD + k];
                acc4[0][0] += a0.f[t]  * b0; acc4[0][1] += a0.f[t]  * b1;
                acc4[0][2] += a0.f[t]  * b2; acc4[0][3] += a0.f[t]  * b3;
                acc4[1][0] += a1.f[t]  * b0; acc4[1][1] += a1.f[t]  * b1;
                acc4[1][2] += a1.f[t]  * b2; acc4[1][3] += a1.f[t]  * b3;
                acc4[2][0] += a2u.f[t] * b0; acc4[2][1] += a2u.f[t] * b1;
                acc4[2][2] += a2u.f[t] * b2; acc4[2][3] += a2u.f[t] * b3;
                acc4[3][0] += a3.f[t]  * b0; acc4[3][1] += a3.f[t]  * b1;
                acc4[3][2] += a3.f[t]  * b2; acc4[3][3] += a3.f[t]  * b3;
            }
        }
        __syncthreads();
        #pragma unroll
        for (int u = 0; u < 4; u++)
            #pragma unroll
            for (int v = 0; v < 4; v++) Ab[(row0 + u) * LD + col0 + v] = acc4[u][v];
    }
    __syncthreads();
    #pragma unroll
    for (int m = 0; m < 16; m++) {
        int e = tid + m * 256;
        int i = e >> 6, j = e & 63;
        Ab[i*LD + j] *= Mp[e];
    }
    __syncthreads();

    // 11) rho_out = 2 * Ab @ Ab^T ; ener1 = sum(rho_out * H)
    #pragma unroll
    for (int u = 0; u < 4; u++)
        #pragma unroll
        for (int v = 0; v < 4; v++) acc4[u][v] = 0.f;
    for (int k = 0; k < 64; k++) {
        float av[4], bv[4];
        #pragma unroll
        for (int u = 0; u < 4; u++) av[u] = Ab[(row0 + u) * LD + k];
        #pragma unroll
        for (int v = 0; v < 4; v++) bv[v] = Ab[(col0 + v) * LD + k];
        #pragma unroll
        for (int u = 0; u < 4; u++)
            #pragma unroll
            for (int v = 0; v < 4; v++) acc4[u][v] += av[u] * bv[v];
    }
    {
        float e1 = 0.f;
        float* outR = out + OFF_RHO + gb;
        #pragma unroll
        for (int u = 0; u < 4; u++)
            #pragma unroll
            for (int v = 0; v < 4; v++) {
                float rv = 2.f * acc4[u][v];
                int i = row0 + u, j = col0 + v;
                outR[i * 64 + j] = rv;
                e1 += rv * Hp[i * 64 + j];
            }
        red[tid] = e1;
    }
    __syncthreads();
    for (int sN = 128; sN > 0; sN >>= 1) {
        if (tid < sN) red[tid] += red[tid + sN];
        __syncthreads();
    }
    if (tid == 0) out[OFF_EELEC + g] = red[0] + ener2r;
    if (tid < 64) out[OFF_DQ + (size_t)g * 64 + tid] = dqs[tid];
}

// ---------------------------------------------------------------- launcher
extern "C" void kernel_launch(void* const* d_in, const int* in_sizes, int n_in,
                              void* d_out, int out_size, void* d_ws, size_t ws_size,
                              hipStream_t stream)
{
    (void)in_sizes; (void)n_in; (void)out_size;
    const float* net_vals    = (const float*)d_in[0];
    const float* rot_tensors = (const float*)d_in[1];
    const float* S           = (const float*)d_in[2];
    const float* G           = (const float*)d_in[3];
    const float* rho         = (const float*)d_in[4];
    const float* qneutral    = (const float*)d_in[5];
    const float* mask        = (const float*)d_in[6];
    const float* phiS        = (const float*)d_in[7];
    const float* zcounts     = (const float*)d_in[8];
    const float* ref_vars    = (const float*)d_in[9];
    const int* gather_rot    = (const int*)d_in[10];
    const int* gather_oper   = (const int*)d_in[11];
    const int* gather_rep    = (const int*)d_in[12];
    const int* segsum_rep    = (const int*)d_in[13];

    float* out = (float*)d_out;

    const size_t need = (size_t)Rc * 9 * sizeof(float);   // 36 MB
    if (d_ws && ws_size >= need) {
        k_rot<<<(Rc + 255) / 256, 256, 0, stream>>>(rot_tensors, gather_rot,
                                                    net_vals, (float*)d_ws);
        k_hgather4<<<4096, 256, 0, stream>>>(gather_oper, (const float*)d_ws, out);
    } else {
        k_hgather<<<16384, 256, 0, stream>>>(gather_oper, rot_tensors, gather_rot,
                                             net_vals, out);
    }
    k_erep_seg<<<NGc, 256, 0, stream>>>(net_vals, gather_rep, segsum_rep,
                                        zcounts, ref_vars, out);
    k_geom<<<NGc, 256, 0, stream>>>(S, G, rho, qneutral, mask, phiS, out);
}

// Round 7
// 1387.622 us; speedup vs baseline: 3.3612x; 1.0595x over previous
//
#include <hip/hip_runtime.h>

typedef unsigned int uint_t;

#define NGc     1024
#define Bc      64
#define LDA     67            // A stride: odd bank stride (3 mod 32) -> uniform banks
#define LDV     66            // V stride: 264B rows, 8B-aligned -> b64 float2 updates
#define Rc      1000000
#define NNETc   4000000
#define EREPc   2000000
#define ROTLENc 9000002       // 2 + 9*R

// output element offsets (fp32 elements, concatenated in return order)
#define OFF_H     0
#define OFF_DQ    4194304
#define OFF_EREP  4259840
#define OFF_EORB  4260864
#define OFF_RHO   4326400
#define OFF_EELEC 8520704
#define OFF_EREF  8521728

// ---------------------------------------------------------------- k_rot
__global__ void k_rot(const float* __restrict__ rot_t,
                      const int*   __restrict__ gather_rot,
                      const float* __restrict__ net_vals,
                      float*       __restrict__ ws)
{
    int r = blockIdx.x * 256 + threadIdx.x;
    if (r >= Rc) return;
    const int* gr = gather_rot + (size_t)r * 3;
    int i0 = gr[0], i1 = gr[1], i2 = gr[2];
    i0 = ((unsigned)i0 < (unsigned)NNETc) ? i0 : 0;
    i1 = ((unsigned)i1 < (unsigned)NNETc) ? i1 : 0;
    i2 = ((unsigned)i2 < (unsigned)NNETc) ? i2 : 0;
    float v0 = net_vals[i0], v1 = net_vals[i1], v2 = net_vals[i2];
    const float* tt = rot_t + (size_t)r * 27;
    float* wp = ws + (size_t)r * 9;
    #pragma unroll
    for (int c = 0; c < 9; c++)
        wp[c] = tt[c*3+0] * v0 + tt[c*3+1] * v1 + tt[c*3+2] * v2;
}

// ---------------------------------------------------------------- k_hgather4
__global__ void k_hgather4(const int*   __restrict__ idx,
                           const float* __restrict__ ws,
                           float*       __restrict__ out)
{
    int t4 = blockIdx.x * 256 + threadIdx.x;      // 1,048,576 threads
    const int4 id4 = ((const int4*)idx)[t4];
    float4 hv;
    {
        int id = id4.x;
        hv.x = (id >= 2 && id < ROTLENc) ? ws[id - 2] : ((id == 1) ? 1.0f : 0.0f);
    }
    {
        int id = id4.y;
        hv.y = (id >= 2 && id < ROTLENc) ? ws[id - 2] : ((id == 1) ? 1.0f : 0.0f);
    }
    {
        int id = id4.z;
        hv.z = (id >= 2 && id < ROTLENc) ? ws[id - 2] : ((id == 1) ? 1.0f : 0.0f);
    }
    {
        int id = id4.w;
        hv.w = (id >= 2 && id < ROTLENc) ? ws[id - 2] : ((id == 1) ? 1.0f : 0.0f);
    }
    ((float4*)(out + OFF_H))[t4] = hv;
}

// ---------------------------------------------------------------- k_hgather
// Fallback (no workspace): fused rotation + operator gather.
__global__ void k_hgather(const int*   __restrict__ idx,
                          const float* __restrict__ rot_t,
                          const int*   __restrict__ gather_rot,
                          const float* __restrict__ net_vals,
                          float*       __restrict__ out)
{
    int t = blockIdx.x * 256 + threadIdx.x;
    if (t >= NGc * Bc * Bc) return;
    int id = idx[t];
    float hv;
    if (id >= 2 && id < ROTLENc) {
        int k = id - 2;
        int r = k / 9;
        int c = k - r * 9;
        const float* tt = rot_t + (size_t)r * 27 + (size_t)c * 3;
        const int*   gr = gather_rot + (size_t)r * 3;
        int i0 = gr[0], i1 = gr[1], i2 = gr[2];
        i0 = ((unsigned)i0 < (unsigned)NNETc) ? i0 : 0;
        i1 = ((unsigned)i1 < (unsigned)NNETc) ? i1 : 0;
        i2 = ((unsigned)i2 < (unsigned)NNETc) ? i2 : 0;
        hv = tt[0] * net_vals[i0] + tt[1] * net_vals[i1] + tt[2] * net_vals[i2];
    } else {
        hv = (id == 1) ? 1.0f : 0.0f;
    }
    out[OFF_H + t] = hv;
}

// ---------------------------------------------------------------- k_erep_seg
__global__ void k_erep_seg(const float* __restrict__ net_vals,
                           const int*   __restrict__ gather_rep,
                           const int*   __restrict__ segsum,
                           const float* __restrict__ zcounts,
                           const float* __restrict__ ref_vars,
                           float*       __restrict__ out)
{
    __shared__ int   sB[2];
    __shared__ float red[256];
    const int g = blockIdx.x, tid = threadIdx.x;

    if (tid < 2) {
        int target = g + tid;
        int lo = 0, hi = EREPc;
        while (lo < hi) {
            int mid = (lo + hi) >> 1;
            if (segsum[mid] < target) lo = mid + 1; else hi = mid;
        }
        sB[tid] = lo;
    }
    __syncthreads();
    const int s = sB[0], e = sB[1];
    float acc = 0.f;
    for (int i = s + tid; i < e; i += 256) {
        int gi = gather_rep[i];
        gi = ((unsigned)gi < (unsigned)NNETc) ? gi : 0;
        acc += net_vals[gi];
    }
    red[tid] = acc;
    __syncthreads();
    for (int sN = 128; sN > 0; sN >>= 1) {
        if (tid < sN) red[tid] += red[tid + sN];
        __syncthreads();
    }
    if (tid == 0) out[OFF_EREP + g] = red[0];

    if (g == 0 && tid == 0) {
        float er = 0.f;
        for (int j = 0; j < 7; j++) er += zcounts[j] * ref_vars[j];
        out[OFF_EREF] = er;
    }
}

// ---------------------------------------------------------------- k_geom
// One block per geometry. Split LDS layout: Ab stride 67 (odd bank stride ->
// scattered 2x2 phase-2 accesses conflict-free), Vb stride 66 (b64-aligned
// float2 Vt updates, exactly-uniform banks), diagonal in separate diagA[64]
// (stride-1 banks; also serves as the eigenvalue array).
// Jacobi round: phase1 = wave-0 lanes 0-31 compute angles (fast-math) +
// closed-form diagonal update into diagA; phase2 = all threads fused
// off-diag 2x2 updates + transposed-V row update.
__global__ __launch_bounds__(256, 4) void k_geom(
    const float* __restrict__ Sg_,  const float* __restrict__ Gg_,
    const float* __restrict__ rho_, const float* __restrict__ qn_,
    const float* __restrict__ mask_,const float* __restrict__ phiS_,
    float* out)
{
    __shared__ float Ab[Bc * LDA];
    __shared__ float Vb[Bc * LDV];       // holds T1 temp, then Vt
    __shared__ float dqs[Bc];
    __shared__ float epv[Bc];
    __shared__ float red[256];
    __shared__ float diagA[Bc];          // A diagonal (becomes eigenvalues)
    __shared__ int   perm[Bc];
    __shared__ float2 csCS[32];
    __shared__ float sOffArr[4];

    const int g    = blockIdx.x;
    const int tid  = threadIdx.x;
    const size_t gb = (size_t)g * 4096;

    const float* Sp = Sg_  + gb;
    const float* Gp = Gg_  + gb;
    const float* Rp = rho_ + gb;
    const float* Mp = mask_+ gb;
    const float* Pp = phiS_+ gb;
    const float4* P4 = (const float4*)Pp;
    const float* Hp = out + OFF_H + gb;      // fp32 H (written by gather stage)

    // 1) S -> Vb (temp)
    #pragma unroll
    for (int m = 0; m < 16; m++) {
        int e = tid + m * 256;               // 4096 floats
        int i = e >> 6, j = e & 63;
        Vb[i*LDV + j] = Sp[e];
    }
    __syncthreads();

    // 2) dQ[i] = qneutral[i] - sum_j rho_ij * S_ij   (4 threads per row)
    {
        int i = tid >> 2, qr = tid & 3;
        float acc = 0.f;
        #pragma unroll
        for (int jj = 0; jj < 16; jj++) {
            int j = qr * 16 + jj;
            acc += Rp[i * 64 + j] * Vb[i*LDV + j];
        }
        acc += __shfl_xor(acc, 1, 64);
        acc += __shfl_xor(acc, 2, 64);
        if (qr == 0) dqs[i] = qn_[(size_t)g * 64 + i] - acc;
    }
    // 3) G -> Ab (temp)
    #pragma unroll
    for (int m = 0; m < 16; m++) {
        int e = tid + m * 256;
        int i = e >> 6, j = e & 63;
        Ab[i*LDA + j] = Gp[e];
    }
    __syncthreads();
    // ep = G * dQ
    {
        int i = tid >> 2, qr = tid & 3;
        float acc = 0.f;
        #pragma unroll
        for (int jj = 0; jj < 16; jj++) {
            int j = qr * 16 + jj;
            acc += Ab[i*LDA + j] * dqs[j];
        }
        acc += __shfl_xor(acc, 1, 64);
        acc += __shfl_xor(acc, 2, 64);
        if (qr == 0) epv[i] = acc;
    }
    __syncthreads();
    float ener2r = 0.f;
    if (tid < 64) {     // ener2 = 0.5 * dQ^T ep  (kept in a tid-0 register)
        float v = dqs[tid] * epv[tid];
        #pragma unroll
        for (int o = 1; o < 64; o <<= 1) v += __shfl_xor(v, o, 64);
        if (tid == 0) ener2r = 0.5f * v;
    }
    // 4) F = H - 0.5*S*(ep_i + ep_j) -> Ab (overwrites G)
    #pragma unroll
    for (int m = 0; m < 16; m++) {
        int e = tid + m * 256;
        int i = e >> 6, j = e & 63;
        Ab[i*LDA + j] = Hp[e] - 0.5f * Vb[i*LDV + j] * (epv[i] + epv[j]);
    }
    __syncthreads();

    const int tx = tid & 15, ty = tid >> 4;
    const int row0 = ty * 4, col0 = tx * 4;
    float acc4[4][4];

    // 5) T1 = F @ phiS -> Vb   (phiS from global, float4; S dead)
    #pragma unroll
    for (int u = 0; u < 4; u++)
        #pragma unroll
        for (int v = 0; v < 4; v++) acc4[u][v] = 0.f;
    for (int k = 0; k < 64; k++) {
        float av[4];
        #pragma unroll
        for (int u = 0; u < 4; u++) av[u] = Ab[(row0 + u) * LDA + k];
        union { float4 v4; float f[4]; } b4;
        b4.v4 = P4[k * 16 + tx];             // phiS[k, col0..col0+3]
        #pragma unroll
        for (int u = 0; u < 4; u++)
            #pragma unroll
            for (int v = 0; v < 4; v++) acc4[u][v] += av[u] * b4.f[v];
    }
    #pragma unroll
    for (int u = 0; u < 4; u++)
        #pragma unroll
        for (int v = 0; v < 4; v++) Vb[(row0 + u) * LDV + col0 + v] = acc4[u][v];
    __syncthreads();

    // 6) fockp = phiS^T @ T1 -> Ab (+ diagonal copy into diagA);
    //    accumulate ||fockp||_F^2
    #pragma unroll
    for (int u = 0; u < 4; u++)
        #pragma unroll
        for (int v = 0; v < 4; v++) acc4[u][v] = 0.f;
    for (int k = 0; k < 64; k++) {
        union { float4 v4; float f[4]; } a4;
        a4.v4 = P4[k * 16 + ty];             // phiS[k, row0..row0+3]
        float bv[4];
        #pragma unroll
        for (int v = 0; v < 4; v++) bv[v] = Vb[k * LDV + col0 + v];
        #pragma unroll
        for (int u = 0; u < 4; u++)
            #pragma unroll
            for (int v = 0; v < 4; v++) acc4[u][v] += a4.f[u] * bv[v];
    }
    {
        float fr = 0.f;
        #pragma unroll
        for (int u = 0; u < 4; u++)
            #pragma unroll
            for (int v = 0; v < 4; v++) {
                Ab[(row0 + u) * LDA + col0 + v] = acc4[u][v];
                fr += acc4[u][v] * acc4[u][v];
            }
        if (tx == ty) {
            #pragma unroll
            for (int u = 0; u < 4; u++) diagA[row0 + u] = acc4[u][u];
        }
        red[tid] = fr;
    }
    __syncthreads();
    for (int sN = 128; sN > 0; sN >>= 1) {
        if (tid < sN) red[tid] += red[tid + sN];
        __syncthreads();
    }
    const float anorm2 = red[0];             // valid for all threads after barrier

    // 7) Vt = I (T1 dead)
    #pragma unroll
    for (int m = 0; m < 17; m++) {
        int e = tid + m * 256;
        if (e < Bc * LDV) Vb[e] = 0.f;
    }
    __syncthreads();
    if (tid < 64) { Vb[tid * LDV + tid] = 1.f; perm[tid] = tid; }

    const float skip2 = anorm2 * 1e-18f;
    const float conv2 = anorm2 * 4e-14f;

    // 8) fused-2x2 parallel cyclic Jacobi: 63 rounds/sweep.
    const int myi = tid & 31;                // own (row-)pair index
    const int jb  = tid >> 5;                // col-pair base (0..7)
    const int cb  = jb << 3;                 // Vt col chunk (8 cols)

    int iP, iQ, iPa, iQa, iPv, iQv;
    {
        iP = (myi == 0) ? 63 : myi;
        iQ = (myi == 0) ? 0  : 63 - myi;
        iPa = iP * LDA; iQa = iQ * LDA;
        iPv = iP * LDV; iQv = iQ * LDV;
    }
    int jP[4], jQ[4];
    #pragma unroll
    for (int k = 0; k < 4; k++) {
        int x = jb + (k << 3);
        jP[k] = (x == 0) ? 63 : x;
        jQ[k] = (x == 0) ? 0  : 63 - x;
    }
    const bool dgk[4] = { myi == jb, myi == jb + 8,
                          myi == jb + 16, myi == jb + 24 };

    for (int sweep = 0; sweep < 10; ++sweep) {
        float offacc = 0.f;                  // valid in lanes tid<32 only
        for (int r = 0; r < 63; r++) {
            // --- phase 1: wave0 lanes 0-31: angles + diagonal update
            if (tid < 32) {
                float app = diagA[iP];
                float aqq = diagA[iQ];
                float apq = Ab[iPa + iQ];
                float a2 = apq * apq;
                offacc += a2;
                float c = 1.f, s = 0.f;
                if (a2 > skip2) {
                    float tau = (aqq - app) * __builtin_amdgcn_rcpf(apq + apq);
                    float tt = __builtin_amdgcn_rcpf(
                        fabsf(tau) + __builtin_amdgcn_sqrtf(1.f + tau * tau));
                    tt = (tau < 0.f) ? -tt : tt;
                    c = __builtin_amdgcn_rsqf(1.f + tt * tt);
                    s = tt * c;
                    // closed-form diagonal 2x2 (off-diag pq zeroed in Ab)
                    diagA[iP] = app - tt * apq;
                    diagA[iQ] = aqq + tt * apq;
                    Ab[iPa + iQ] = 0.f;
                    Ab[iQa + iP] = 0.f;
                }
                csCS[myi] = make_float2(c, s);
            }
            __syncthreads();                 // angles + diag visible

            // --- phase 2: fused off-diag A update (4 blocks/thread, in place)
            float2 me = csCS[myi];
            const float cO = me.x, sO = me.y;
            #pragma unroll
            for (int k = 0; k < 4; k++) {
                float2 cj = csCS[jb + (k << 3)];
                float cc = cj.x, ss = cj.y;
                if (!dgk[k] && (sO != 0.f || ss != 0.f)) {
                    int aPP = iPa + jP[k], aPQ = iPa + jQ[k];
                    int aQP = iQa + jP[k], aQQ = iQa + jQ[k];
                    float a = Ab[aPP], b = Ab[aPQ];
                    float d = Ab[aQP], e = Ab[aQQ];
                    float a1 = cc * a - ss * b, b1 = ss * a + cc * b;
                    float d1 = cc * d - ss * e, e1 = ss * d + cc * e;
                    Ab[aPP] = cO * a1 - sO * d1;
                    Ab[aQP] = sO * a1 + cO * d1;
                    Ab[aPQ] = cO * b1 - sO * e1;
                    Ab[aQQ] = sO * b1 + cO * e1;
                }
            }
            // --- Vt row update (own angle, 8-col chunk, float2)
            if (sO != 0.f) {
                float2* vp = (float2*)&Vb[iPv + cb];
                float2* vq = (float2*)&Vb[iQv + cb];
                #pragma unroll
                for (int e2 = 0; e2 < 4; e2++) {
                    float2 xp = vp[e2], xq = vq[e2];
                    float2 np, nq;
                    np.x = cO * xp.x - sO * xq.x;  np.y = cO * xp.y - sO * xq.y;
                    nq.x = sO * xp.x + cO * xq.x;  nq.y = sO * xp.y + cO * xq.y;
                    vp[e2] = np; vq[e2] = nq;
                }
            }
            // --- advance pair indices r -> r+1 (wraps continue across sweeps)
            {
                int nP  = (iP == 62) ? 0 : ((iP == 63) ? 63 : iP + 1);
                int nPa = (iP == 62) ? 0 : ((iP == 63) ? iPa : iPa + LDA);
                int nPv = (iP == 62) ? 0 : ((iP == 63) ? iPv : iPv + LDV);
                int nQ  = (iQ == 62) ? 0 : iQ + 1;
                int nQa = (iQ == 62) ? 0 : iQa + LDA;
                int nQv = (iQ == 62) ? 0 : iQv + LDV;
                iP = nP; iPa = nPa; iPv = nPv; iQ = nQ; iQa = nQa; iQv = nQv;
            }
            #pragma unroll
            for (int k = 0; k < 4; k++) {
                int p = jP[k], q = jQ[k];
                jP[k] = (p == 62) ? 0 : ((p == 63) ? 63 : p + 1);
                jQ[k] = (q == 62) ? 0 : q + 1;
            }
            __syncthreads();                 // all writes done before next angles
        }
        // sweep-end convergence: each pair counted exactly once (lanes 0-31)
        float t2 = offacc;
        #pragma unroll
        for (int o = 1; o < 32; o <<= 1) t2 += __shfl_xor(t2, o, 64);
        if (tid == 0) sOffArr[0] = t2;
        __syncthreads();
        if (sOffArr[0] < conv2) break;
        // next write to sOffArr is 63 barrier-separated rounds away -> safe
    }

    // 9) eigenvalues (diagA) + ascending sort (rank by comparison, idx tiebreak)
    if (tid < 64) {
        float e = diagA[tid]; int rk = 0;
        for (int j = 0; j < 64; j++) {
            float ej = diagA[j];
            rk += (ej < e || (ej == e && j < tid)) ? 1 : 0;
        }
        rk &= 63;
        perm[rk] = tid;
        out[OFF_EORB + (size_t)g * 64 + rk] = e;
    }
    __syncthreads();

    // 10) orb = phiS @ V[:, perm] -> Ab ; V[k][pc] = Vt[pc][k]
    {
        int pc0 = perm[col0 + 0] & 63, pc1 = perm[col0 + 1] & 63;
        int pc2 = perm[col0 + 2] & 63, pc3 = perm[col0 + 3] & 63;
        #pragma unroll
        for (int u = 0; u < 4; u++)
            #pragma unroll
            for (int v = 0; v < 4; v++) acc4[u][v] = 0.f;
        for (int kk = 0; kk < 16; kk++) {
            union { float4 v4; float f[4]; } a0, a1, a2u, a3;
            a0.v4  = P4[(row0 + 0) * 16 + kk];
            a1.v4  = P4[(row0 + 1) * 16 + kk];
            a2u.v4 = P4[(row0 + 2) * 16 + kk];
            a3.v4  = P4[(row0 + 3) * 16 + kk];
            #pragma unroll
            for (int t = 0; t < 4; t++) {
                int k = (kk << 2) + t;
                float b0 = Vb[pc0*LDV + k], b1 = Vb[pc1*LDV + k];
                float b2 = Vb[pc2*LDV + k], b3 = Vb[pc3*LDV + k];
                acc4[0][0] += a0.f[t]  * b0; acc4[0][1] += a0.f[t]  * b1;
                acc4[0][2] += a0.f[t]  * b2; acc4[0][3] += a0.f[t]  * b3;
                acc4[1][0] += a1.f[t]  * b0; acc4[1][1] += a1.f[t]  * b1;
                acc4[1][2] += a1.f[t]  * b2; acc4[1][3] += a1.f[t]  * b3;
                acc4[2][0] += a2u.f[t] * b0; acc4[2][1] += a2u.f[t] * b1;
                acc4[2][2] += a2u.f[t] * b2; acc4[2][3] += a2u.f[t] * b3;
                acc4[3][0] += a3.f[t]  * b0; acc4[3][1] += a3.f[t]  * b1;
                acc4[3][2] += a3.f[t]  * b2; acc4[3][3] += a3.f[t]  * b3;
            }
        }
        __syncthreads();
        #pragma unroll
        for (int u = 0; u < 4; u++)
            #pragma unroll
            for (int v = 0; v < 4; v++) Ab[(row0 + u) * LDA + col0 + v] = acc4[u][v];
    }
    __syncthreads();
    #pragma unroll
    for (int m = 0; m < 16; m++) {
        int e = tid + m * 256;
        int i = e >> 6, j = e & 63;
        Ab[i*LDA + j] *= Mp[e];
    }
    __syncthreads();

    // 11) rho_out = 2 * Ab @ Ab^T ; ener1 = sum(rho_out * H)
    #pragma unroll
    for (int u = 0; u < 4; u++)
        #pragma unroll
        for (int v = 0; v < 4; v++) acc4[u][v] = 0.f;
    for (int k = 0; k < 64; k++) {
        float av[4], bv[4];
        #pragma unroll
        for (int u = 0; u < 4; u++) av[u] = Ab[(row0 + u) * LDA + k];
        #pragma unroll
        for (int v = 0; v < 4; v++) bv[v] = Ab[(col0 + v) * LDA + k];
        #pragma unroll
        for (int u = 0; u < 4; u++)
            #pragma unroll
            for (int v = 0; v < 4; v++) acc4[u][v] += av[u] * bv[v];
    }
    {
        float e1 = 0.f;
        float* outR = out + OFF_RHO + gb;
        #pragma unroll
        for (int u = 0; u < 4; u++)
            #pragma unroll
            for (int v = 0; v < 4; v++) {
                float rv = 2.f * acc4[u][v];
                int i = row0 + u, j = col0 + v;
                outR[i * 64 + j] = rv;
                e1 += rv * Hp[i * 64 + j];
            }
        red[tid] = e1;
    }
    __syncthreads();
    for (int sN = 128; sN > 0; sN >>= 1) {
        if (tid < sN) red[tid] += red[tid + sN];
        __syncthreads();
    }
    if (tid == 0) out[OFF_EELEC + g] = red[0] + ener2r;
    if (tid < 64) out[OFF_DQ + (size_t)g * 64 + tid] = dqs[tid];
}

// ---------------------------------------------------------------- launcher
extern "C" void kernel_launch(void* const* d_in, const int* in_sizes, int n_in,
                              void* d_out, int out_size, void* d_ws, size_t ws_size,
                              hipStream_t stream)
{
    (void)in_sizes; (void)n_in; (void)out_size;
    const float* net_vals    = (const float*)d_in[0];
    const float* rot_tensors = (const float*)d_in[1];
    const float* S           = (const float*)d_in[2];
    const float* G           = (const float*)d_in[3];
    const float* rho         = (const float*)d_in[4];
    const float* qneutral    = (const float*)d_in[5];
    const float* mask        = (const float*)d_in[6];
    const float* phiS        = (const float*)d_in[7];
    const float* zcounts     = (const float*)d_in[8];
    const float* ref_vars    = (const float*)d_in[9];
    const int* gather_rot    = (const int*)d_in[10];
    const int* gather_oper   = (const int*)d_in[11];
    const int* gather_rep    = (const int*)d_in[12];
    const int* segsum_rep    = (const int*)d_in[13];

    float* out = (float*)d_out;

    const size_t need = (size_t)Rc * 9 * sizeof(float);   // 36 MB
    if (d_ws && ws_size >= need) {
        k_rot<<<(Rc + 255) / 256, 256, 0, stream>>>(rot_tensors, gather_rot,
                                                    net_vals, (float*)d_ws);
        k_hgather4<<<4096, 256, 0, stream>>>(gather_oper, (const float*)d_ws, out);
    } else {
        k_hgather<<<16384, 256, 0, stream>>>(gather_oper, rot_tensors, gather_rot,
                                             net_vals, out);
    }
    k_erep_seg<<<NGc, 256, 0, stream>>>(net_vals, gather_rep, segsum_rep,
                                        zcounts, ref_vars, out);
    k_geom<<<NGc, 256, 0, stream>>>(S, G, rho, qneutral, mask, phiS, out);
}

// Round 8
// 1299.570 us; speedup vs baseline: 3.5890x; 1.0678x over previous
//
#include <hip/hip_runtime.h>

typedef unsigned int uint_t;

#define NGc     1024
#define Bc      64
#define LDA     67            // A stride: odd bank stride (3 mod 32) -> uniform banks
#define LDV     66            // V stride: 264B rows, 8B-aligned -> b64 float2 updates
#define Rc      1000000
#define NNETc   4000000
#define EREPc   2000000
#define ROTLENc 9000002       // 2 + 9*R

// output element offsets (fp32 elements, concatenated in return order)
#define OFF_H     0
#define OFF_DQ    4194304
#define OFF_EREP  4259840
#define OFF_EORB  4260864
#define OFF_RHO   4326400
#define OFF_EELEC 8520704
#define OFF_EREF  8521728

// ---------------------------------------------------------------- k_rot
__global__ void k_rot(const float* __restrict__ rot_t,
                      const int*   __restrict__ gather_rot,
                      const float* __restrict__ net_vals,
                      float*       __restrict__ ws)
{
    int r = blockIdx.x * 256 + threadIdx.x;
    if (r >= Rc) return;
    const int* gr = gather_rot + (size_t)r * 3;
    int i0 = gr[0], i1 = gr[1], i2 = gr[2];
    i0 = ((unsigned)i0 < (unsigned)NNETc) ? i0 : 0;
    i1 = ((unsigned)i1 < (unsigned)NNETc) ? i1 : 0;
    i2 = ((unsigned)i2 < (unsigned)NNETc) ? i2 : 0;
    float v0 = net_vals[i0], v1 = net_vals[i1], v2 = net_vals[i2];
    const float* tt = rot_t + (size_t)r * 27;
    float* wp = ws + (size_t)r * 9;
    #pragma unroll
    for (int c = 0; c < 9; c++)
        wp[c] = tt[c*3+0] * v0 + tt[c*3+1] * v1 + tt[c*3+2] * v2;
}

// ---------------------------------------------------------------- k_hgather4
__global__ void k_hgather4(const int*   __restrict__ idx,
                           const float* __restrict__ ws,
                           float*       __restrict__ out)
{
    int t4 = blockIdx.x * 256 + threadIdx.x;      // 1,048,576 threads
    const int4 id4 = ((const int4*)idx)[t4];
    float4 hv;
    {
        int id = id4.x;
        hv.x = (id >= 2 && id < ROTLENc) ? ws[id - 2] : ((id == 1) ? 1.0f : 0.0f);
    }
    {
        int id = id4.y;
        hv.y = (id >= 2 && id < ROTLENc) ? ws[id - 2] : ((id == 1) ? 1.0f : 0.0f);
    }
    {
        int id = id4.z;
        hv.z = (id >= 2 && id < ROTLENc) ? ws[id - 2] : ((id == 1) ? 1.0f : 0.0f);
    }
    {
        int id = id4.w;
        hv.w = (id >= 2 && id < ROTLENc) ? ws[id - 2] : ((id == 1) ? 1.0f : 0.0f);
    }
    ((float4*)(out + OFF_H))[t4] = hv;
}

// ---------------------------------------------------------------- k_hgather
// Fallback (no workspace): fused rotation + operator gather.
__global__ void k_hgather(const int*   __restrict__ idx,
                          const float* __restrict__ rot_t,
                          const int*   __restrict__ gather_rot,
                          const float* __restrict__ net_vals,
                          float*       __restrict__ out)
{
    int t = blockIdx.x * 256 + threadIdx.x;
    if (t >= NGc * Bc * Bc) return;
    int id = idx[t];
    float hv;
    if (id >= 2 && id < ROTLENc) {
        int k = id - 2;
        int r = k / 9;
        int c = k - r * 9;
        const float* tt = rot_t + (size_t)r * 27 + (size_t)c * 3;
        const int*   gr = gather_rot + (size_t)r * 3;
        int i0 = gr[0], i1 = gr[1], i2 = gr[2];
        i0 = ((unsigned)i0 < (unsigned)NNETc) ? i0 : 0;
        i1 = ((unsigned)i1 < (unsigned)NNETc) ? i1 : 0;
        i2 = ((unsigned)i2 < (unsigned)NNETc) ? i2 : 0;
        hv = tt[0] * net_vals[i0] + tt[1] * net_vals[i1] + tt[2] * net_vals[i2];
    } else {
        hv = (id == 1) ? 1.0f : 0.0f;
    }
    out[OFF_H + t] = hv;
}

// ---------------------------------------------------------------- k_erep_seg
__global__ void k_erep_seg(const float* __restrict__ net_vals,
                           const int*   __restrict__ gather_rep,
                           const int*   __restrict__ segsum,
                           const float* __restrict__ zcounts,
                           const float* __restrict__ ref_vars,
                           float*       __restrict__ out)
{
    __shared__ int   sB[2];
    __shared__ float red[256];
    const int g = blockIdx.x, tid = threadIdx.x;

    if (tid < 2) {
        int target = g + tid;
        int lo = 0, hi = EREPc;
        while (lo < hi) {
            int mid = (lo + hi) >> 1;
            if (segsum[mid] < target) lo = mid + 1; else hi = mid;
        }
        sB[tid] = lo;
    }
    __syncthreads();
    const int s = sB[0], e = sB[1];
    float acc = 0.f;
    for (int i = s + tid; i < e; i += 256) {
        int gi = gather_rep[i];
        gi = ((unsigned)gi < (unsigned)NNETc) ? gi : 0;
        acc += net_vals[gi];
    }
    red[tid] = acc;
    __syncthreads();
    for (int sN = 128; sN > 0; sN >>= 1) {
        if (tid < sN) red[tid] += red[tid + sN];
        __syncthreads();
    }
    if (tid == 0) out[OFF_EREP + g] = red[0];

    if (g == 0 && tid == 0) {
        float er = 0.f;
        for (int j = 0; j < 7; j++) er += zcounts[j] * ref_vars[j];
        out[OFF_EREF] = er;
    }
}

// ---------------------------------------------------------------- k_geom
// One block per geometry. A kept as SYMMETRIC UPPER PAIR-TRIANGLE during
// Jacobi: each unordered pair-block {i<j} (496 total) is read+rotated+written
// ONCE per round (canonical cell addr (min,max)), halving A LDS traffic and
// rotation FMAs vs the ordered scheme. Thread t owns flat blocks {t, t+256}.
// Diag blocks: phase-1 closed-form into diagA (stride-1). Vt: transposed
// eigenvectors, float2 rows (LDV=66). Ab stride 67 (odd -> scattered accesses
// conflict-light).
__global__ __launch_bounds__(256, 4) void k_geom(
    const float* __restrict__ Sg_,  const float* __restrict__ Gg_,
    const float* __restrict__ rho_, const float* __restrict__ qn_,
    const float* __restrict__ mask_,const float* __restrict__ phiS_,
    float* out)
{
    __shared__ float Ab[Bc * LDA];
    __shared__ float Vb[Bc * LDV];       // holds T1 temp, then Vt
    __shared__ float dqs[Bc];
    __shared__ float epv[Bc];
    __shared__ float red[256];
    __shared__ float diagA[Bc];          // A diagonal (becomes eigenvalues)
    __shared__ int   perm[Bc];
    __shared__ float2 csCS[32];
    __shared__ float sOffArr[4];

    const int g    = blockIdx.x;
    const int tid  = threadIdx.x;
    const size_t gb = (size_t)g * 4096;

    const float* Sp = Sg_  + gb;
    const float* Gp = Gg_  + gb;
    const float* Rp = rho_ + gb;
    const float* Mp = mask_+ gb;
    const float* Pp = phiS_+ gb;
    const float4* P4 = (const float4*)Pp;
    const float* Hp = out + OFF_H + gb;      // fp32 H (written by gather stage)

    // 1) S -> Vb (temp)
    #pragma unroll
    for (int m = 0; m < 16; m++) {
        int e = tid + m * 256;               // 4096 floats
        int i = e >> 6, j = e & 63;
        Vb[i*LDV + j] = Sp[e];
    }
    __syncthreads();

    // 2) dQ[i] = qneutral[i] - sum_j rho_ij * S_ij   (4 threads per row)
    {
        int i = tid >> 2, qr = tid & 3;
        float acc = 0.f;
        #pragma unroll
        for (int jj = 0; jj < 16; jj++) {
            int j = qr * 16 + jj;
            acc += Rp[i * 64 + j] * Vb[i*LDV + j];
        }
        acc += __shfl_xor(acc, 1, 64);
        acc += __shfl_xor(acc, 2, 64);
        if (qr == 0) dqs[i] = qn_[(size_t)g * 64 + i] - acc;
    }
    // 3) G -> Ab (temp)
    #pragma unroll
    for (int m = 0; m < 16; m++) {
        int e = tid + m * 256;
        int i = e >> 6, j = e & 63;
        Ab[i*LDA + j] = Gp[e];
    }
    __syncthreads();
    // ep = G * dQ
    {
        int i = tid >> 2, qr = tid & 3;
        float acc = 0.f;
        #pragma unroll
        for (int jj = 0; jj < 16; jj++) {
            int j = qr * 16 + jj;
            acc += Ab[i*LDA + j] * dqs[j];
        }
        acc += __shfl_xor(acc, 1, 64);
        acc += __shfl_xor(acc, 2, 64);
        if (qr == 0) epv[i] = acc;
    }
    __syncthreads();
    float ener2r = 0.f;
    if (tid < 64) {     // ener2 = 0.5 * dQ^T ep  (kept in a tid-0 register)
        float v = dqs[tid] * epv[tid];
        #pragma unroll
        for (int o = 1; o < 64; o <<= 1) v += __shfl_xor(v, o, 64);
        if (tid == 0) ener2r = 0.5f * v;
    }
    // 4) F = H - 0.5*S*(ep_i + ep_j) -> Ab (overwrites G)
    #pragma unroll
    for (int m = 0; m < 16; m++) {
        int e = tid + m * 256;
        int i = e >> 6, j = e & 63;
        Ab[i*LDA + j] = Hp[e] - 0.5f * Vb[i*LDV + j] * (epv[i] + epv[j]);
    }
    __syncthreads();

    const int tx = tid & 15, ty = tid >> 4;
    const int row0 = ty * 4, col0 = tx * 4;
    float acc4[4][4];

    // 5) T1 = F @ phiS -> Vb   (phiS from global, float4; S dead)
    #pragma unroll
    for (int u = 0; u < 4; u++)
        #pragma unroll
        for (int v = 0; v < 4; v++) acc4[u][v] = 0.f;
    for (int k = 0; k < 64; k++) {
        float av[4];
        #pragma unroll
        for (int u = 0; u < 4; u++) av[u] = Ab[(row0 + u) * LDA + k];
        union { float4 v4; float f[4]; } b4;
        b4.v4 = P4[k * 16 + tx];             // phiS[k, col0..col0+3]
        #pragma unroll
        for (int u = 0; u < 4; u++)
            #pragma unroll
            for (int v = 0; v < 4; v++) acc4[u][v] += av[u] * b4.f[v];
    }
    #pragma unroll
    for (int u = 0; u < 4; u++)
        #pragma unroll
        for (int v = 0; v < 4; v++) Vb[(row0 + u) * LDV + col0 + v] = acc4[u][v];
    __syncthreads();

    // 6) fockp = phiS^T @ T1 -> Ab (+ diagonal copy into diagA);
    //    accumulate ||fockp||_F^2
    #pragma unroll
    for (int u = 0; u < 4; u++)
        #pragma unroll
        for (int v = 0; v < 4; v++) acc4[u][v] = 0.f;
    for (int k = 0; k < 64; k++) {
        union { float4 v4; float f[4]; } a4;
        a4.v4 = P4[k * 16 + ty];             // phiS[k, row0..row0+3]
        float bv[4];
        #pragma unroll
        for (int v = 0; v < 4; v++) bv[v] = Vb[k * LDV + col0 + v];
        #pragma unroll
        for (int u = 0; u < 4; u++)
            #pragma unroll
            for (int v = 0; v < 4; v++) acc4[u][v] += a4.f[u] * bv[v];
    }
    {
        float fr = 0.f;
        #pragma unroll
        for (int u = 0; u < 4; u++)
            #pragma unroll
            for (int v = 0; v < 4; v++) {
                Ab[(row0 + u) * LDA + col0 + v] = acc4[u][v];
                fr += acc4[u][v] * acc4[u][v];
            }
        if (tx == ty) {
            #pragma unroll
            for (int u = 0; u < 4; u++) diagA[row0 + u] = acc4[u][u];
        }
        red[tid] = fr;
    }
    __syncthreads();
    for (int sN = 128; sN > 0; sN >>= 1) {
        if (tid < sN) red[tid] += red[tid + sN];
        __syncthreads();
    }
    const float anorm2 = red[0];             // valid for all threads after barrier

    // 7) Vt = I (T1 dead)
    #pragma unroll
    for (int m = 0; m < 17; m++) {
        int e = tid + m * 256;
        if (e < Bc * LDV) Vb[e] = 0.f;
    }
    __syncthreads();
    if (tid < 64) { Vb[tid * LDV + tid] = 1.f; perm[tid] = tid; }

    const float skip2 = anorm2 * 1e-18f;
    const float conv2 = anorm2 * 4e-14f;

    // 8) upper-triangle fused 2x2 parallel cyclic Jacobi: 63 rounds/sweep.
    const int myi = tid & 31;                // own (Vt / phase-1) pair index
    const int jb  = tid >> 5;
    const int cb  = jb << 3;                 // Vt col chunk (8 cols)

    // own pair state (Vt rows; phase-1 angle inputs for tid<32)
    int myP = (myi == 0) ? 63 : myi;
    int myQ = (myi == 0) ? 0  : 63 - myi;
    int iPv = myP * LDV, iQv = myQ * LDV;

    // two unordered A-blocks per thread: flat upper-tri indices {tid, tid+256}
    int bi1, bj1, bi2 = 0, bj2 = 1;
    {
        int m = tid, i = 0;
        while (m >= 31 - i) { m -= 31 - i; ++i; }
        bi1 = i; bj1 = i + 1 + m;
    }
    const bool hasB2 = (tid + 256) < 496;
    if (hasB2) {
        int m = tid + 256, i = 0;
        while (m >= 31 - i) { m -= 31 - i; ++i; }
        bi2 = i; bj2 = i + 1 + m;
    }
    int pI1 = (bi1 == 0) ? 63 : bi1, qI1 = (bi1 == 0) ? 0 : 63 - bi1;
    int pJ1 = bj1,                   qJ1 = 63 - bj1;      // bj1 >= 1
    int pI2 = (bi2 == 0) ? 63 : bi2, qI2 = (bi2 == 0) ? 0 : 63 - bi2;
    int pJ2 = bj2,                   qJ2 = 63 - bj2;

    #define ADVI(v) v = ((v) == 62) ? 0 : (((v) == 63) ? 63 : (v) + 1)

    for (int sweep = 0; sweep < 10; ++sweep) {
        float offacc = 0.f;                  // valid in lanes tid<32 only
        for (int r = 0; r < 63; r++) {
            // --- phase 1: lanes 0-31: angles + closed-form diagonal update
            if (tid < 32) {
                float app = diagA[myP];
                float aqq = diagA[myQ];
                int mn = min(myP, myQ), mx = max(myP, myQ);
                int apqA = mn * LDA + mx;
                float apq = Ab[apqA];
                float a2 = apq * apq;
                offacc += a2;
                float c = 1.f, s = 0.f;
                if (a2 > skip2) {
                    float tau = (aqq - app) * __builtin_amdgcn_rcpf(apq + apq);
                    float tt = __builtin_amdgcn_rcpf(
                        fabsf(tau) + __builtin_amdgcn_sqrtf(1.f + tau * tau));
                    tt = (tau < 0.f) ? -tt : tt;
                    c = __builtin_amdgcn_rsqf(1.f + tt * tt);
                    s = tt * c;
                    diagA[myP] = app - tt * apq;
                    diagA[myQ] = aqq + tt * apq;
                    Ab[apqA] = 0.f;
                }
                csCS[myi] = make_float2(c, s);
            }
            __syncthreads();                 // angles + diag visible

            // --- phase 2: unordered A-blocks (canonical upper-tri cells)
            {
                float2 AI = csCS[bi1], AJ = csCS[bj1];
                if (AI.y != 0.f || AJ.y != 0.f) {
                    int mn, mx;
                    mn = min(pI1,pJ1); mx = max(pI1,pJ1); int aA = mn*LDA + mx;
                    mn = min(pI1,qJ1); mx = max(pI1,qJ1); int aB = mn*LDA + mx;
                    mn = min(qI1,pJ1); mx = max(qI1,pJ1); int aD = mn*LDA + mx;
                    mn = min(qI1,qJ1); mx = max(qI1,qJ1); int aE = mn*LDA + mx;
                    float a = Ab[aA], b = Ab[aB], d = Ab[aD], e = Ab[aE];
                    float a1 = AJ.x*a - AJ.y*b, b1 = AJ.y*a + AJ.x*b;
                    float d1 = AJ.x*d - AJ.y*e, e1 = AJ.y*d + AJ.x*e;
                    Ab[aA] = AI.x*a1 - AI.y*d1;
                    Ab[aD] = AI.y*a1 + AI.x*d1;
                    Ab[aB] = AI.x*b1 - AI.y*e1;
                    Ab[aE] = AI.y*b1 + AI.x*e1;
                }
            }
            if (hasB2) {
                float2 AI = csCS[bi2], AJ = csCS[bj2];
                if (AI.y != 0.f || AJ.y != 0.f) {
                    int mn, mx;
                    mn = min(pI2,pJ2); mx = max(pI2,pJ2); int aA = mn*LDA + mx;
                    mn = min(pI2,qJ2); mx = max(pI2,qJ2); int aB = mn*LDA + mx;
                    mn = min(qI2,pJ2); mx = max(qI2,pJ2); int aD = mn*LDA + mx;
                    mn = min(qI2,qJ2); mx = max(qI2,qJ2); int aE = mn*LDA + mx;
                    float a = Ab[aA], b = Ab[aB], d = Ab[aD], e = Ab[aE];
                    float a1 = AJ.x*a - AJ.y*b, b1 = AJ.y*a + AJ.x*b;
                    float d1 = AJ.x*d - AJ.y*e, e1 = AJ.y*d + AJ.x*e;
                    Ab[aA] = AI.x*a1 - AI.y*d1;
                    Ab[aD] = AI.y*a1 + AI.x*d1;
                    Ab[aB] = AI.x*b1 - AI.y*e1;
                    Ab[aE] = AI.y*b1 + AI.x*e1;
                }
            }
            // --- Vt row update (own angle, 8-col chunk, float2)
            {
                float2 me = csCS[myi];
                if (me.y != 0.f) {
                    const float cO = me.x, sO = me.y;
                    float2* vp = (float2*)&Vb[iPv + cb];
                    float2* vq = (float2*)&Vb[iQv + cb];
                    #pragma unroll
                    for (int e2 = 0; e2 < 4; e2++) {
                        float2 xp = vp[e2], xq = vq[e2];
                        float2 np, nq;
                        np.x = cO * xp.x - sO * xq.x;  np.y = cO * xp.y - sO * xq.y;
                        nq.x = sO * xp.x + cO * xq.x;  nq.y = sO * xp.y + cO * xq.y;
                        vp[e2] = np; vq[e2] = nq;
                    }
                }
            }
            // --- advance all pair states r -> r+1 (wraps continue across sweeps)
            iPv = (myP == 62) ? 0 : ((myP == 63) ? iPv : iPv + LDV);
            iQv = (myQ == 62) ? 0 : iQv + LDV;
            ADVI(myP); ADVI(myQ);
            ADVI(pI1); ADVI(qI1); ADVI(pJ1); ADVI(qJ1);
            ADVI(pI2); ADVI(qI2); ADVI(pJ2); ADVI(qJ2);
            __syncthreads();                 // all writes done before next angles
        }
        // sweep-end convergence: each pair counted exactly once (lanes 0-31)
        float t2 = offacc;
        #pragma unroll
        for (int o = 1; o < 32; o <<= 1) t2 += __shfl_xor(t2, o, 64);
        if (tid == 0) sOffArr[0] = t2;
        __syncthreads();
        if (sOffArr[0] < conv2) break;
        // next write to sOffArr is 63 barrier-separated rounds away -> safe
    }
    #undef ADVI

    // 9) eigenvalues (diagA) + ascending sort (rank by comparison, idx tiebreak)
    if (tid < 64) {
        float e = diagA[tid]; int rk = 0;
        for (int j = 0; j < 64; j++) {
            float ej = diagA[j];
            rk += (ej < e || (ej == e && j < tid)) ? 1 : 0;
        }
        rk &= 63;
        perm[rk] = tid;
        out[OFF_EORB + (size_t)g * 64 + rk] = e;
    }
    __syncthreads();

    // 10) orb = phiS @ V[:, perm] -> Ab ; V[k][pc] = Vt[pc][k]
    {
        int pc0 = perm[col0 + 0] & 63, pc1 = perm[col0 + 1] & 63;
        int pc2 = perm[col0 + 2] & 63, pc3 = perm[col0 + 3] & 63;
        #pragma unroll
        for (int u = 0; u < 4; u++)
            #pragma unroll
            for (int v = 0; v < 4; v++) acc4[u][v] = 0.f;
        for (int kk = 0; kk < 16; kk++) {
            union { float4 v4; float f[4]; } a0, a1, a2u, a3;
            a0.v4  = P4[(row0 + 0) * 16 + kk];
            a1.v4  = P4[(row0 + 1) * 16 + kk];
            a2u.v4 = P4[(row0 + 2) * 16 + kk];
            a3.v4  = P4[(row0 + 3) * 16 + kk];
            #pragma unroll
            for (int t = 0; t < 4; t++) {
                int k = (kk << 2) + t;
                float b0 = Vb[pc0*LDV + k], b1 = Vb[pc1*LDV + k];
                float b2 = Vb[pc2*LDV + k], b3 = Vb[pc3*LDV + k];
                acc4[0][0] += a0.f[t]  * b0; acc4[0][1] += a0.f[t]  * b1;
                acc4[0][2] += a0.f[t]  * b2; acc4[0][3] += a0.f[t]  * b3;
                acc4[1][0] += a1.f[t]  * b0; acc4[1][1] += a1.f[t]  * b1;
                acc4[1][2] += a1.f[t]  * b2; acc4[1][3] += a1.f[t]  * b3;
                acc4[2][0] += a2u.f[t] * b0; acc4[2][1] += a2u.f[t] * b1;
                acc4[2][2] += a2u.f[t] * b2; acc4[2][3] += a2u.f[t] * b3;
                acc4[3][0] += a3.f[t]  * b0; acc4[3][1] += a3.f[t]  * b1;
                acc4[3][2] += a3.f[t]  * b2; acc4[3][3] += a3.f[t]  * b3;
            }
        }
        __syncthreads();
        #pragma unroll
        for (int u = 0; u < 4; u++)
            #pragma unroll
            for (int v = 0; v < 4; v++) Ab[(row0 + u) * LDA + col0 + v] = acc4[u][v];
    }
    __syncthreads();
    #pragma unroll
    for (int m = 0; m < 16; m++) {
        int e = tid + m * 256;
        int i = e >> 6, j = e & 63;
        Ab[i*LDA + j] *= Mp[e];
    }
    __syncthreads();

    // 11) rho_out = 2 * Ab @ Ab^T ; ener1 = sum(rho_out * H)
    #pragma unroll
    for (int u = 0; u < 4; u++)
        #pragma unroll
        for (int v = 0; v < 4; v++) acc4[u][v] = 0.f;
    for (int k = 0; k < 64; k++) {
        float av[4], bv[4];
        #pragma unroll
        for (int u = 0; u < 4; u++) av[u] = Ab[(row0 + u) * LDA + k];
        #pragma unroll
        for (int v = 0; v < 4; v++) bv[v] = Ab[(col0 + v) * LDA + k];
        #pragma unroll
        for (int u = 0; u < 4; u++)
            #pragma unroll
            for (int v = 0; v < 4; v++) acc4[u][v] += av[u] * bv[v];
    }
    {
        float e1 = 0.f;
        float* outR = out + OFF_RHO + gb;
        #pragma unroll
        for (int u = 0; u < 4; u++)
            #pragma unroll
            for (int v = 0; v < 4; v++) {
                float rv = 2.f * acc4[u][v];
                int i = row0 + u, j = col0 + v;
                outR[i * 64 + j] = rv;
                e1 += rv * Hp[i * 64 + j];
            }
        red[tid] = e1;
    }
    __syncthreads();
    for (int sN = 128; sN > 0; sN >>= 1) {
        if (tid < sN) red[tid] += red[tid + sN];
        __syncthreads();
    }
    if (tid == 0) out[OFF_EELEC + g] = red[0] + ener2r;
    if (tid < 64) out[OFF_DQ + (size_t)g * 64 + tid] = dqs[tid];
}

// ---------------------------------------------------------------- launcher
extern "C" void kernel_launch(void* const* d_in, const int* in_sizes, int n_in,
                              void* d_out, int out_size, void* d_ws, size_t ws_size,
                              hipStream_t stream)
{
    (void)in_sizes; (void)n_in; (void)out_size;
    const float* net_vals    = (const float*)d_in[0];
    const float* rot_tensors = (const float*)d_in[1];
    const float* S           = (const float*)d_in[2];
    const float* G           = (const float*)d_in[3];
    const float* rho         = (const float*)d_in[4];
    const float* qneutral    = (const float*)d_in[5];
    const float* mask        = (const float*)d_in[6];
    const float* phiS        = (const float*)d_in[7];
    const float* zcounts     = (const float*)d_in[8];
    const float* ref_vars    = (const float*)d_in[9];
    const int* gather_rot    = (const int*)d_in[10];
    const int* gather_oper   = (const int*)d_in[11];
    const int* gather_rep    = (const int*)d_in[12];
    const int* segsum_rep    = (const int*)d_in[13];

    float* out = (float*)d_out;

    const size_t need = (size_t)Rc * 9 * sizeof(float);   // 36 MB
    if (d_ws && ws_size >= need) {
        k_rot<<<(Rc + 255) / 256, 256, 0, stream>>>(rot_tensors, gather_rot,
                                                    net_vals, (float*)d_ws);
        k_hgather4<<<4096, 256, 0, stream>>>(gather_oper, (const float*)d_ws, out);
    } else {
        k_hgather<<<16384, 256, 0, stream>>>(gather_oper, rot_tensors, gather_rot,
                                             net_vals, out);
    }
    k_erep_seg<<<NGc, 256, 0, stream>>>(net_vals, gather_rep, segsum_rep,
                                        zcounts, ref_vars, out);
    k_geom<<<NGc, 256, 0, stream>>>(S, G, rho, qneutral, mask, phiS, out);
}

// Round 9
// 1289.009 us; speedup vs baseline: 3.6184x; 1.0082x over previous
//
#include <hip/hip_runtime.h>

typedef unsigned int uint_t;

#define NGc     1024
#define Bc      64
#define LDA     67            // A stride: odd bank stride (3 mod 32) -> uniform banks
#define LDV     68            // V stride: 272B rows = 17x16B -> float4-aligned, uniform banks
#define Rc      1000000
#define NNETc   4000000
#define EREPc   2000000
#define ROTLENc 9000002       // 2 + 9*R

// output element offsets (fp32 elements, concatenated in return order)
#define OFF_H     0
#define OFF_DQ    4194304
#define OFF_EREP  4259840
#define OFF_EORB  4260864
#define OFF_RHO   4326400
#define OFF_EELEC 8520704
#define OFF_EREF  8521728

// ---------------------------------------------------------------- k_rot
__global__ void k_rot(const float* __restrict__ rot_t,
                      const int*   __restrict__ gather_rot,
                      const float* __restrict__ net_vals,
                      float*       __restrict__ ws)
{
    int r = blockIdx.x * 256 + threadIdx.x;
    if (r >= Rc) return;
    const int* gr = gather_rot + (size_t)r * 3;
    int i0 = gr[0], i1 = gr[1], i2 = gr[2];
    i0 = ((unsigned)i0 < (unsigned)NNETc) ? i0 : 0;
    i1 = ((unsigned)i1 < (unsigned)NNETc) ? i1 : 0;
    i2 = ((unsigned)i2 < (unsigned)NNETc) ? i2 : 0;
    float v0 = net_vals[i0], v1 = net_vals[i1], v2 = net_vals[i2];
    const float* tt = rot_t + (size_t)r * 27;
    float* wp = ws + (size_t)r * 9;
    #pragma unroll
    for (int c = 0; c < 9; c++)
        wp[c] = tt[c*3+0] * v0 + tt[c*3+1] * v1 + tt[c*3+2] * v2;
}

// ---------------------------------------------------------------- k_hgather4
__global__ void k_hgather4(const int*   __restrict__ idx,
                           const float* __restrict__ ws,
                           float*       __restrict__ out)
{
    int t4 = blockIdx.x * 256 + threadIdx.x;      // 1,048,576 threads
    const int4 id4 = ((const int4*)idx)[t4];
    float4 hv;
    {
        int id = id4.x;
        hv.x = (id >= 2 && id < ROTLENc) ? ws[id - 2] : ((id == 1) ? 1.0f : 0.0f);
    }
    {
        int id = id4.y;
        hv.y = (id >= 2 && id < ROTLENc) ? ws[id - 2] : ((id == 1) ? 1.0f : 0.0f);
    }
    {
        int id = id4.z;
        hv.z = (id >= 2 && id < ROTLENc) ? ws[id - 2] : ((id == 1) ? 1.0f : 0.0f);
    }
    {
        int id = id4.w;
        hv.w = (id >= 2 && id < ROTLENc) ? ws[id - 2] : ((id == 1) ? 1.0f : 0.0f);
    }
    ((float4*)(out + OFF_H))[t4] = hv;
}

// ---------------------------------------------------------------- k_hgather
// Fallback (no workspace): fused rotation + operator gather.
__global__ void k_hgather(const int*   __restrict__ idx,
                          const float* __restrict__ rot_t,
                          const int*   __restrict__ gather_rot,
                          const float* __restrict__ net_vals,
                          float*       __restrict__ out)
{
    int t = blockIdx.x * 256 + threadIdx.x;
    if (t >= NGc * Bc * Bc) return;
    int id = idx[t];
    float hv;
    if (id >= 2 && id < ROTLENc) {
        int k = id - 2;
        int r = k / 9;
        int c = k - r * 9;
        const float* tt = rot_t + (size_t)r * 27 + (size_t)c * 3;
        const int*   gr = gather_rot + (size_t)r * 3;
        int i0 = gr[0], i1 = gr[1], i2 = gr[2];
        i0 = ((unsigned)i0 < (unsigned)NNETc) ? i0 : 0;
        i1 = ((unsigned)i1 < (unsigned)NNETc) ? i1 : 0;
        i2 = ((unsigned)i2 < (unsigned)NNETc) ? i2 : 0;
        hv = tt[0] * net_vals[i0] + tt[1] * net_vals[i1] + tt[2] * net_vals[i2];
    } else {
        hv = (id == 1) ? 1.0f : 0.0f;
    }
    out[OFF_H + t] = hv;
}

// ---------------------------------------------------------------- k_erep_seg
__global__ void k_erep_seg(const float* __restrict__ net_vals,
                           const int*   __restrict__ gather_rep,
                           const int*   __restrict__ segsum,
                           const float* __restrict__ zcounts,
                           const float* __restrict__ ref_vars,
                           float*       __restrict__ out)
{
    __shared__ int   sB[2];
    __shared__ float red[256];
    const int g = blockIdx.x, tid = threadIdx.x;

    if (tid < 2) {
        int target = g + tid;
        int lo = 0, hi = EREPc;
        while (lo < hi) {
            int mid = (lo + hi) >> 1;
            if (segsum[mid] < target) lo = mid + 1; else hi = mid;
        }
        sB[tid] = lo;
    }
    __syncthreads();
    const int s = sB[0], e = sB[1];
    float acc = 0.f;
    for (int i = s + tid; i < e; i += 256) {
        int gi = gather_rep[i];
        gi = ((unsigned)gi < (unsigned)NNETc) ? gi : 0;
        acc += net_vals[gi];
    }
    red[tid] = acc;
    __syncthreads();
    for (int sN = 128; sN > 0; sN >>= 1) {
        if (tid < sN) red[tid] += red[tid + sN];
        __syncthreads();
    }
    if (tid == 0) out[OFF_EREP + g] = red[0];

    if (g == 0 && tid == 0) {
        float er = 0.f;
        for (int j = 0; j < 7; j++) er += zcounts[j] * ref_vars[j];
        out[OFF_EREF] = er;
    }
}

// ---------------------------------------------------------------- k_geom
// One block per geometry. A kept as SYMMETRIC UPPER PAIR-TRIANGLE during
// Jacobi (496 unordered blocks, canonical (min,max) cells, each updated once
// per round). Diag blocks: phase-1 closed-form into diagA. Vt: transposed
// eigenvectors with LDV=68 (272B rows, float4-aligned): the Vt rotation is
// 8 b128 ops/thread/round with EXACTLY uniform bank load (8 touches/bank) --
// replaces the r8 float2 scheme whose even-only bank pattern was a
// structural 4-way conflict (the dominant SQ_LDS_BANK_CONFLICT source).
__global__ __launch_bounds__(256, 4) void k_geom(
    const float* __restrict__ Sg_,  const float* __restrict__ Gg_,
    const float* __restrict__ rho_, const float* __restrict__ qn_,
    const float* __restrict__ mask_,const float* __restrict__ phiS_,
    float* out)
{
    __shared__ float Ab[Bc * LDA];
    __shared__ float Vb[Bc * LDV];       // holds T1 temp, then Vt
    __shared__ float dqs[Bc];
    __shared__ float epv[Bc];
    __shared__ float red[256];
    __shared__ float diagA[Bc];          // A diagonal (becomes eigenvalues)
    __shared__ int   perm[Bc];
    __shared__ float2 csCS[32];
    __shared__ float sOffArr[4];

    const int g    = blockIdx.x;
    const int tid  = threadIdx.x;
    const size_t gb = (size_t)g * 4096;

    const float* Sp = Sg_  + gb;
    const float* Gp = Gg_  + gb;
    const float* Rp = rho_ + gb;
    const float* Mp = mask_+ gb;
    const float* Pp = phiS_+ gb;
    const float4* P4 = (const float4*)Pp;
    const float* Hp = out + OFF_H + gb;      // fp32 H (written by gather stage)

    // 1) S -> Vb (temp)
    #pragma unroll
    for (int m = 0; m < 16; m++) {
        int e = tid + m * 256;               // 4096 floats
        int i = e >> 6, j = e & 63;
        Vb[i*LDV + j] = Sp[e];
    }
    __syncthreads();

    // 2) dQ[i] = qneutral[i] - sum_j rho_ij * S_ij   (4 threads per row)
    {
        int i = tid >> 2, qr = tid & 3;
        float acc = 0.f;
        #pragma unroll
        for (int jj = 0; jj < 16; jj++) {
            int j = qr * 16 + jj;
            acc += Rp[i * 64 + j] * Vb[i*LDV + j];
        }
        acc += __shfl_xor(acc, 1, 64);
        acc += __shfl_xor(acc, 2, 64);
        if (qr == 0) dqs[i] = qn_[(size_t)g * 64 + i] - acc;
    }
    // 3) G -> Ab (temp)
    #pragma unroll
    for (int m = 0; m < 16; m++) {
        int e = tid + m * 256;
        int i = e >> 6, j = e & 63;
        Ab[i*LDA + j] = Gp[e];
    }
    __syncthreads();
    // ep = G * dQ
    {
        int i = tid >> 2, qr = tid & 3;
        float acc = 0.f;
        #pragma unroll
        for (int jj = 0; jj < 16; jj++) {
            int j = qr * 16 + jj;
            acc += Ab[i*LDA + j] * dqs[j];
        }
        acc += __shfl_xor(acc, 1, 64);
        acc += __shfl_xor(acc, 2, 64);
        if (qr == 0) epv[i] = acc;
    }
    __syncthreads();
    float ener2r = 0.f;
    if (tid < 64) {     // ener2 = 0.5 * dQ^T ep  (kept in a tid-0 register)
        float v = dqs[tid] * epv[tid];
        #pragma unroll
        for (int o = 1; o < 64; o <<= 1) v += __shfl_xor(v, o, 64);
        if (tid == 0) ener2r = 0.5f * v;
    }
    // 4) F = H - 0.5*S*(ep_i + ep_j) -> Ab (overwrites G)
    #pragma unroll
    for (int m = 0; m < 16; m++) {
        int e = tid + m * 256;
        int i = e >> 6, j = e & 63;
        Ab[i*LDA + j] = Hp[e] - 0.5f * Vb[i*LDV + j] * (epv[i] + epv[j]);
    }
    __syncthreads();

    const int tx = tid & 15, ty = tid >> 4;
    const int row0 = ty * 4, col0 = tx * 4;
    float acc4[4][4];

    // 5) T1 = F @ phiS -> Vb   (phiS from global, float4; S dead)
    #pragma unroll
    for (int u = 0; u < 4; u++)
        #pragma unroll
        for (int v = 0; v < 4; v++) acc4[u][v] = 0.f;
    for (int k = 0; k < 64; k++) {
        float av[4];
        #pragma unroll
        for (int u = 0; u < 4; u++) av[u] = Ab[(row0 + u) * LDA + k];
        union { float4 v4; float f[4]; } b4;
        b4.v4 = P4[k * 16 + tx];             // phiS[k, col0..col0+3]
        #pragma unroll
        for (int u = 0; u < 4; u++)
            #pragma unroll
            for (int v = 0; v < 4; v++) acc4[u][v] += av[u] * b4.f[v];
    }
    #pragma unroll
    for (int u = 0; u < 4; u++)
        #pragma unroll
        for (int v = 0; v < 4; v++) Vb[(row0 + u) * LDV + col0 + v] = acc4[u][v];
    __syncthreads();

    // 6) fockp = phiS^T @ T1 -> Ab (+ diagonal copy into diagA);
    //    accumulate ||fockp||_F^2
    #pragma unroll
    for (int u = 0; u < 4; u++)
        #pragma unroll
        for (int v = 0; v < 4; v++) acc4[u][v] = 0.f;
    for (int k = 0; k < 64; k++) {
        union { float4 v4; float f[4]; } a4;
        a4.v4 = P4[k * 16 + ty];             // phiS[k, row0..row0+3]
        float bv[4];
        #pragma unroll
        for (int v = 0; v < 4; v++) bv[v] = Vb[k * LDV + col0 + v];
        #pragma unroll
        for (int u = 0; u < 4; u++)
            #pragma unroll
            for (int v = 0; v < 4; v++) acc4[u][v] += a4.f[u] * bv[v];
    }
    {
        float fr = 0.f;
        #pragma unroll
        for (int u = 0; u < 4; u++)
            #pragma unroll
            for (int v = 0; v < 4; v++) {
                Ab[(row0 + u) * LDA + col0 + v] = acc4[u][v];
                fr += acc4[u][v] * acc4[u][v];
            }
        if (tx == ty) {
            #pragma unroll
            for (int u = 0; u < 4; u++) diagA[row0 + u] = acc4[u][u];
        }
        red[tid] = fr;
    }
    __syncthreads();
    for (int sN = 128; sN > 0; sN >>= 1) {
        if (tid < sN) red[tid] += red[tid + sN];
        __syncthreads();
    }
    const float anorm2 = red[0];             // valid for all threads after barrier

    // 7) Vt = I (T1 dead)
    #pragma unroll
    for (int m = 0; m < 17; m++) {
        int e = tid + m * 256;
        if (e < Bc * LDV) Vb[e] = 0.f;
    }
    __syncthreads();
    if (tid < 64) { Vb[tid * LDV + tid] = 1.f; perm[tid] = tid; }

    const float skip2 = anorm2 * 1e-18f;
    const float conv2 = anorm2 * 4e-14f;

    // 8) upper-triangle fused 2x2 parallel cyclic Jacobi: 63 rounds/sweep.
    const int myi = tid & 31;                // own (Vt / phase-1) pair index
    const int jb  = tid >> 5;
    const int cb  = jb << 3;                 // Vt col chunk (8 cols)

    // own pair state (Vt rows; phase-1 angle inputs for tid<32)
    int myP = (myi == 0) ? 63 : myi;
    int myQ = (myi == 0) ? 0  : 63 - myi;
    int iPv = myP * LDV, iQv = myQ * LDV;

    // two unordered A-blocks per thread: flat upper-tri indices {tid, tid+256}
    int bi1, bj1, bi2 = 0, bj2 = 1;
    {
        int m = tid, i = 0;
        while (m >= 31 - i) { m -= 31 - i; ++i; }
        bi1 = i; bj1 = i + 1 + m;
    }
    const bool hasB2 = (tid + 256) < 496;
    if (hasB2) {
        int m = tid + 256, i = 0;
        while (m >= 31 - i) { m -= 31 - i; ++i; }
        bi2 = i; bj2 = i + 1 + m;
    }
    int pI1 = (bi1 == 0) ? 63 : bi1, qI1 = (bi1 == 0) ? 0 : 63 - bi1;
    int pJ1 = bj1,                   qJ1 = 63 - bj1;      // bj1 >= 1
    int pI2 = (bi2 == 0) ? 63 : bi2, qI2 = (bi2 == 0) ? 0 : 63 - bi2;
    int pJ2 = bj2,                   qJ2 = 63 - bj2;

    #define ADVI(v) v = ((v) == 62) ? 0 : (((v) == 63) ? 63 : (v) + 1)

    for (int sweep = 0; sweep < 10; ++sweep) {
        float offacc = 0.f;                  // valid in lanes tid<32 only
        for (int r = 0; r < 63; r++) {
            // --- phase 1: lanes 0-31: angles + closed-form diagonal update
            if (tid < 32) {
                float app = diagA[myP];
                float aqq = diagA[myQ];
                int mn = min(myP, myQ), mx = max(myP, myQ);
                int apqA = mn * LDA + mx;
                float apq = Ab[apqA];
                float a2 = apq * apq;
                offacc += a2;
                float c = 1.f, s = 0.f;
                if (a2 > skip2) {
                    float tau = (aqq - app) * __builtin_amdgcn_rcpf(apq + apq);
                    float tt = __builtin_amdgcn_rcpf(
                        fabsf(tau) + __builtin_amdgcn_sqrtf(1.f + tau * tau));
                    tt = (tau < 0.f) ? -tt : tt;
                    c = __builtin_amdgcn_rsqf(1.f + tt * tt);
                    s = tt * c;
                    diagA[myP] = app - tt * apq;
                    diagA[myQ] = aqq + tt * apq;
                    Ab[apqA] = 0.f;
                }
                csCS[myi] = make_float2(c, s);
            }
            __syncthreads();                 // angles + diag visible

            // --- phase 2: unordered A-blocks (canonical upper-tri cells)
            {
                float2 AI = csCS[bi1], AJ = csCS[bj1];
                if (AI.y != 0.f || AJ.y != 0.f) {
                    int mn, mx;
                    mn = min(pI1,pJ1); mx = max(pI1,pJ1); int aA = mn*LDA + mx;
                    mn = min(pI1,qJ1); mx = max(pI1,qJ1); int aB = mn*LDA + mx;
                    mn = min(qI1,pJ1); mx = max(qI1,pJ1); int aD = mn*LDA + mx;
                    mn = min(qI1,qJ1); mx = max(qI1,qJ1); int aE = mn*LDA + mx;
                    float a = Ab[aA], b = Ab[aB], d = Ab[aD], e = Ab[aE];
                    float a1 = AJ.x*a - AJ.y*b, b1 = AJ.y*a + AJ.x*b;
                    float d1 = AJ.x*d - AJ.y*e, e1 = AJ.y*d + AJ.x*e;
                    Ab[aA] = AI.x*a1 - AI.y*d1;
                    Ab[aD] = AI.y*a1 + AI.x*d1;
                    Ab[aB] = AI.x*b1 - AI.y*e1;
                    Ab[aE] = AI.y*b1 + AI.x*e1;
                }
            }
            if (hasB2) {
                float2 AI = csCS[bi2], AJ = csCS[bj2];
                if (AI.y != 0.f || AJ.y != 0.f) {
                    int mn, mx;
                    mn = min(pI2,pJ2); mx = max(pI2,pJ2); int aA = mn*LDA + mx;
                    mn = min(pI2,qJ2); mx = max(pI2,qJ2); int aB = mn*LDA + mx;
                    mn = min(qI2,pJ2); mx = max(qI2,pJ2); int aD = mn*LDA + mx;
                    mn = min(qI2,qJ2); mx = max(qI2,qJ2); int aE = mn*LDA + mx;
                    float a = Ab[aA], b = Ab[aB], d = Ab[aD], e = Ab[aE];
                    float a1 = AJ.x*a - AJ.y*b, b1 = AJ.y*a + AJ.x*b;
                    float d1 = AJ.x*d - AJ.y*e, e1 = AJ.y*d + AJ.x*e;
                    Ab[aA] = AI.x*a1 - AI.y*d1;
                    Ab[aD] = AI.y*a1 + AI.x*d1;
                    Ab[aB] = AI.x*b1 - AI.y*e1;
                    Ab[aE] = AI.y*b1 + AI.x*e1;
                }
            }
            // --- Vt row update (own angle, 8-col chunk, float4: uniform banks)
            {
                float2 me = csCS[myi];
                if (me.y != 0.f) {
                    const float cO = me.x, sO = me.y;
                    float4* vp = (float4*)&Vb[iPv + cb];
                    float4* vq = (float4*)&Vb[iQv + cb];
                    #pragma unroll
                    for (int e2 = 0; e2 < 2; e2++) {
                        float4 xp = vp[e2], xq = vq[e2];
                        float4 np, nq;
                        np.x = cO*xp.x - sO*xq.x;  nq.x = sO*xp.x + cO*xq.x;
                        np.y = cO*xp.y - sO*xq.y;  nq.y = sO*xp.y + cO*xq.y;
                        np.z = cO*xp.z - sO*xq.z;  nq.z = sO*xp.z + cO*xq.z;
                        np.w = cO*xp.w - sO*xq.w;  nq.w = sO*xp.w + cO*xq.w;
                        vp[e2] = np; vq[e2] = nq;
                    }
                }
            }
            // --- advance all pair states r -> r+1 (wraps continue across sweeps)
            iPv = (myP == 62) ? 0 : ((myP == 63) ? iPv : iPv + LDV);
            iQv = (myQ == 62) ? 0 : iQv + LDV;
            ADVI(myP); ADVI(myQ);
            ADVI(pI1); ADVI(qI1); ADVI(pJ1); ADVI(qJ1);
            ADVI(pI2); ADVI(qI2); ADVI(pJ2); ADVI(qJ2);
            __syncthreads();                 // all writes done before next angles
        }
        // sweep-end convergence: each pair counted exactly once (lanes 0-31)
        float t2 = offacc;
        #pragma unroll
        for (int o = 1; o < 32; o <<= 1) t2 += __shfl_xor(t2, o, 64);
        if (tid == 0) sOffArr[0] = t2;
        __syncthreads();
        if (sOffArr[0] < conv2) break;
        // next write to sOffArr is 63 barrier-separated rounds away -> safe
    }
    #undef ADVI

    // 9) eigenvalues (diagA) + ascending sort (rank by comparison, idx tiebreak)
    if (tid < 64) {
        float e = diagA[tid]; int rk = 0;
        for (int j = 0; j < 64; j++) {
            float ej = diagA[j];
            rk += (ej < e || (ej == e && j < tid)) ? 1 : 0;
        }
        rk &= 63;
        perm[rk] = tid;
        out[OFF_EORB + (size_t)g * 64 + rk] = e;
    }
    __syncthreads();

    // 10) orb = phiS @ V[:, perm] -> Ab ; V[k][pc] = Vt[pc][k]
    {
        int pc0 = perm[col0 + 0] & 63, pc1 = perm[col0 + 1] & 63;
        int pc2 = perm[col0 + 2] & 63, pc3 = perm[col0 + 3] & 63;
        #pragma unroll
        for (int u = 0; u < 4; u++)
            #pragma unroll
            for (int v = 0; v < 4; v++) acc4[u][v] = 0.f;
        for (int kk = 0; kk < 16; kk++) {
            union { float4 v4; float f[4]; } a0, a1, a2u, a3;
            a0.v4  = P4[(row0 + 0) * 16 + kk];
            a1.v4  = P4[(row0 + 1) * 16 + kk];
            a2u.v4 = P4[(row0 + 2) * 16 + kk];
            a3.v4  = P4[(row0 + 3) * 16 + kk];
            #pragma unroll
            for (int t = 0; t < 4; t++) {
                int k = (kk << 2) + t;
                float b0 = Vb[pc0*LDV + k], b1 = Vb[pc1*LDV + k];
                float b2 = Vb[pc2*LDV + k], b3 = Vb[pc3*LDV + k];
                acc4[0][0] += a0.f[t]  * b0; acc4[0][1] += a0.f[t]  * b1;
                acc4[0][2] += a0.f[t]  * b2; acc4[0][3] += a0.f[t]  * b3;
                acc4[1][0] += a1.f[t]  * b0; acc4[1][1] += a1.f[t]  * b1;
                acc4[1][2] += a1.f[t]  * b2; acc4[1][3] += a1.f[t]  * b3;
                acc4[2][0] += a2u.f[t] * b0; acc4[2][1] += a2u.f[t] * b1;
                acc4[2][2] += a2u.f[t] * b2; acc4[2][3] += a2u.f[t] * b3;
                acc4[3][0] += a3.f[t]  * b0; acc4[3][1] += a3.f[t]  * b1;
                acc4[3][2] += a3.f[t]  * b2; acc4[3][3] += a3.f[t]  * b3;
            }
        }
        __syncthreads();
        #pragma unroll
        for (int u = 0; u < 4; u++)
            #pragma unroll
            for (int v = 0; v < 4; v++) Ab[(row0 + u) * LDA + col0 + v] = acc4[u][v];
    }
    __syncthreads();
    #pragma unroll
    for (int m = 0; m < 16; m++) {
        int e = tid + m * 256;
        int i = e >> 6, j = e & 63;
        Ab[i*LDA + j] *= Mp[e];
    }
    __syncthreads();

    // 11) rho_out = 2 * Ab @ Ab^T ; ener1 = sum(rho_out * H)
    #pragma unroll
    for (int u = 0; u < 4; u++)
        #pragma unroll
        for (int v = 0; v < 4; v++) acc4[u][v] = 0.f;
    for (int k = 0; k < 64; k++) {
        float av[4], bv[4];
        #pragma unroll
        for (int u = 0; u < 4; u++) av[u] = Ab[(row0 + u) * LDA + k];
        #pragma unroll
        for (int v = 0; v < 4; v++) bv[v] = Ab[(col0 + v) * LDA + k];
        #pragma unroll
        for (int u = 0; u < 4; u++)
            #pragma unroll
            for (int v = 0; v < 4; v++) acc4[u][v] += av[u] * bv[v];
    }
    {
        float e1 = 0.f;
        float* outR = out + OFF_RHO + gb;
        #pragma unroll
        for (int u = 0; u < 4; u++)
            #pragma unroll
            for (int v = 0; v < 4; v++) {
                float rv = 2.f * acc4[u][v];
                int i = row0 + u, j = col0 + v;
                outR[i * 64 + j] = rv;
                e1 += rv * Hp[i * 64 + j];
            }
        red[tid] = e1;
    }
    __syncthreads();
    for (int sN = 128; sN > 0; sN >>= 1) {
        if (tid < sN) red[tid] += red[tid + sN];
        __syncthreads();
    }
    if (tid == 0) out[OFF_EELEC + g] = red[0] + ener2r;
    if (tid < 64) out[OFF_DQ + (size_t)g * 64 + tid] = dqs[tid];
}

// ---------------------------------------------------------------- launcher
extern "C" void kernel_launch(void* const* d_in, const int* in_sizes, int n_in,
                              void* d_out, int out_size, void* d_ws, size_t ws_size,
                              hipStream_t stream)
{
    (void)in_sizes; (void)n_in; (void)out_size;
    const float* net_vals    = (const float*)d_in[0];
    const float* rot_tensors = (const float*)d_in[1];
    const float* S           = (const float*)d_in[2];
    const float* G           = (const float*)d_in[3];
    const float* rho         = (const float*)d_in[4];
    const float* qneutral    = (const float*)d_in[5];
    const float* mask        = (const float*)d_in[6];
    const float* phiS        = (const float*)d_in[7];
    const float* zcounts     = (const float*)d_in[8];
    const float* ref_vars    = (const float*)d_in[9];
    const int* gather_rot    = (const int*)d_in[10];
    const int* gather_oper   = (const int*)d_in[11];
    const int* gather_rep    = (const int*)d_in[12];
    const int* segsum_rep    = (const int*)d_in[13];

    float* out = (float*)d_out;

    const size_t need = (size_t)Rc * 9 * sizeof(float);   // 36 MB
    if (d_ws && ws_size >= need) {
        k_rot<<<(Rc + 255) / 256, 256, 0, stream>>>(rot_tensors, gather_rot,
                                                    net_vals, (float*)d_ws);
        k_hgather4<<<4096, 256, 0, stream>>>(gather_oper, (const float*)d_ws, out);
    } else {
        k_hgather<<<16384, 256, 0, stream>>>(gather_oper, rot_tensors, gather_rot,
                                             net_vals, out);
    }
    k_erep_seg<<<NGc, 256, 0, stream>>>(net_vals, gather_rep, segsum_rep,
                                        zcounts, ref_vars, out);
    k_geom<<<NGc, 256, 0, stream>>>(S, G, rho, qneutral, mask, phiS, out);
}

// Round 10
// 1269.773 us; speedup vs baseline: 3.6732x; 1.0151x over previous
//
#include <hip/hip_runtime.h>

typedef unsigned int uint_t;

#define NGc     1024
#define Bc      64
#define LDA     67            // A stride: odd bank stride (3 mod 32) -> uniform banks
#define LDV     68            // V stride: 272B rows = 17x16B -> float4-aligned
#define Rc      1000000
#define NNETc   4000000
#define EREPc   2000000
#define ROTLENc 9000002       // 2 + 9*R

// output element offsets (fp32 elements, concatenated in return order)
#define OFF_H     0
#define OFF_DQ    4194304
#define OFF_EREP  4259840
#define OFF_EORB  4260864
#define OFF_RHO   4326400
#define OFF_EELEC 8520704
#define OFF_EREF  8521728

// ---------------------------------------------------------------- k_rot
__global__ void k_rot(const float* __restrict__ rot_t,
                      const int*   __restrict__ gather_rot,
                      const float* __restrict__ net_vals,
                      float*       __restrict__ ws)
{
    int r = blockIdx.x * 256 + threadIdx.x;
    if (r >= Rc) return;
    const int* gr = gather_rot + (size_t)r * 3;
    int i0 = gr[0], i1 = gr[1], i2 = gr[2];
    i0 = ((unsigned)i0 < (unsigned)NNETc) ? i0 : 0;
    i1 = ((unsigned)i1 < (unsigned)NNETc) ? i1 : 0;
    i2 = ((unsigned)i2 < (unsigned)NNETc) ? i2 : 0;
    float v0 = net_vals[i0], v1 = net_vals[i1], v2 = net_vals[i2];
    const float* tt = rot_t + (size_t)r * 27;
    float* wp = ws + (size_t)r * 9;
    #pragma unroll
    for (int c = 0; c < 9; c++)
        wp[c] = tt[c*3+0] * v0 + tt[c*3+1] * v1 + tt[c*3+2] * v2;
}

// ---------------------------------------------------------------- k_hgather
// Fallback (no workspace): fused rotation + operator gather.
__global__ void k_hgather(const int*   __restrict__ idx,
                          const float* __restrict__ rot_t,
                          const int*   __restrict__ gather_rot,
                          const float* __restrict__ net_vals,
                          float*       __restrict__ out)
{
    int t = blockIdx.x * 256 + threadIdx.x;
    if (t >= NGc * Bc * Bc) return;
    int id = idx[t];
    float hv;
    if (id >= 2 && id < ROTLENc) {
        int k = id - 2;
        int r = k / 9;
        int c = k - r * 9;
        const float* tt = rot_t + (size_t)r * 27 + (size_t)c * 3;
        const int*   gr = gather_rot + (size_t)r * 3;
        int i0 = gr[0], i1 = gr[1], i2 = gr[2];
        i0 = ((unsigned)i0 < (unsigned)NNETc) ? i0 : 0;
        i1 = ((unsigned)i1 < (unsigned)NNETc) ? i1 : 0;
        i2 = ((unsigned)i2 < (unsigned)NNETc) ? i2 : 0;
        hv = tt[0] * net_vals[i0] + tt[1] * net_vals[i1] + tt[2] * net_vals[i2];
    } else {
        hv = (id == 1) ? 1.0f : 0.0f;
    }
    out[OFF_H + t] = hv;
}

// ---------------------------------------------------------------- k_erep_seg
// Fallback (no workspace) only.
__global__ void k_erep_seg(const float* __restrict__ net_vals,
                           const int*   __restrict__ gather_rep,
                           const int*   __restrict__ segsum,
                           const float* __restrict__ zcounts,
                           const float* __restrict__ ref_vars,
                           float*       __restrict__ out)
{
    __shared__ int   sB[2];
    __shared__ float red[256];
    const int g = blockIdx.x, tid = threadIdx.x;

    if (tid < 2) {
        int target = g + tid;
        int lo = 0, hi = EREPc;
        while (lo < hi) {
            int mid = (lo + hi) >> 1;
            if (segsum[mid] < target) lo = mid + 1; else hi = mid;
        }
        sB[tid] = lo;
    }
    __syncthreads();
    const int s = sB[0], e = sB[1];
    float acc = 0.f;
    for (int i = s + tid; i < e; i += 256) {
        int gi = gather_rep[i];
        gi = ((unsigned)gi < (unsigned)NNETc) ? gi : 0;
        acc += net_vals[gi];
    }
    red[tid] = acc;
    __syncthreads();
    for (int sN = 128; sN > 0; sN >>= 1) {
        if (tid < sN) red[tid] += red[tid + sN];
        __syncthreads();
    }
    if (tid == 0) out[OFF_EREP + g] = red[0];

    if (g == 0 && tid == 0) {
        float er = 0.f;
        for (int j = 0; j < 7; j++) er += zcounts[j] * ref_vars[j];
        out[OFF_EREF] = er;
    }
}

// ---------------------------------------------------------------- k_geom
// One block per geometry. FUSED=1: the H operator gather (idx+ws) runs inside
// step 4 (H written to out, consumed directly for F) and the per-geometry
// repulsive-energy segment sum + Eref are folded in (binary search hidden
// under the S load; gather-sum register-accumulated; reduced at the end via
// wave shfl + sOffArr). FUSED=0: legacy path (reads H from out; no erep).
// Jacobi: upper-pair-triangle fused 2x2 scheme (r8) with split LDS layout
// (LDA=67 odd stride, LDV=68 float4 rows, diagA separate).
template<int FUSED>
__global__ __launch_bounds__(256, 4) void k_geom(
    const float* __restrict__ Sg_,  const float* __restrict__ Gg_,
    const float* __restrict__ rho_, const float* __restrict__ qn_,
    const float* __restrict__ mask_,const float* __restrict__ phiS_,
    const int*   __restrict__ idx_, const float* __restrict__ ws_,
    const float* __restrict__ net_vals_,
    const int*   __restrict__ grep_,const int* __restrict__ segsum_,
    const float* __restrict__ zcounts_, const float* __restrict__ ref_vars_,
    float* out)
{
    __shared__ float Ab[Bc * LDA];
    __shared__ float Vb[Bc * LDV];       // holds T1 temp, then Vt
    __shared__ float dqs[Bc];
    __shared__ float epv[Bc];
    __shared__ float red[256];
    __shared__ float diagA[Bc];          // A diagonal (becomes eigenvalues)
    __shared__ int   perm[Bc];
    __shared__ float2 csCS[32];
    __shared__ float sOffArr[4];
    __shared__ int   sB[2];

    const int g    = blockIdx.x;
    const int tid  = threadIdx.x;
    const size_t gb = (size_t)g * 4096;

    const float* Sp = Sg_  + gb;
    const float* Gp = Gg_  + gb;
    const float* Rp = rho_ + gb;
    const float* Mp = mask_+ gb;
    const float* Pp = phiS_+ gb;
    const float4* P4 = (const float4*)Pp;
    float* outH = out + OFF_H + gb;      // fp32 H region for this geometry

    // 0) fused-path setup: segment binary search (lanes 0,1) + Eref (lane 255)
    if (FUSED) {
        if (tid < 2) {
            int target = g + tid;
            int lo = 0, hi = EREPc;
            while (lo < hi) {
                int mid = (lo + hi) >> 1;
                if (segsum_[mid] < target) lo = mid + 1; else hi = mid;
            }
            sB[tid] = lo;
        }
        if (g == 0 && tid == 255) {
            float er = 0.f;
            for (int j = 0; j < 7; j++) er += zcounts_[j] * ref_vars_[j];
            out[OFF_EREF] = er;
        }
    }

    // 1) S -> Vb (temp)
    #pragma unroll
    for (int m = 0; m < 16; m++) {
        int e = tid + m * 256;               // 4096 floats
        int i = e >> 6, j = e & 63;
        Vb[i*LDV + j] = Sp[e];
    }
    __syncthreads();                         // also publishes sB

    // 2) dQ[i] = qneutral[i] - sum_j rho_ij * S_ij   (4 threads per row)
    {
        int i = tid >> 2, qr = tid & 3;
        float acc = 0.f;
        #pragma unroll
        for (int jj = 0; jj < 16; jj++) {
            int j = qr * 16 + jj;
            acc += Rp[i * 64 + j] * Vb[i*LDV + j];
        }
        acc += __shfl_xor(acc, 1, 64);
        acc += __shfl_xor(acc, 2, 64);
        if (qr == 0) dqs[i] = qn_[(size_t)g * 64 + i] - acc;
    }
    // 2b) fused erep gather-sum into a register (latency hides under steps 3-6)
    float racc = 0.f;
    if (FUSED) {
        const int s = sB[0], e = sB[1];
        for (int i = s + tid; i < e; i += 256) {
            int gi = grep_[i];
            gi = ((unsigned)gi < (unsigned)NNETc) ? gi : 0;
            racc += net_vals_[gi];
        }
    }
    // 3) G -> Ab (temp)
    #pragma unroll
    for (int m = 0; m < 16; m++) {
        int e = tid + m * 256;
        int i = e >> 6, j = e & 63;
        Ab[i*LDA + j] = Gp[e];
    }
    __syncthreads();
    // ep = G * dQ
    {
        int i = tid >> 2, qr = tid & 3;
        float acc = 0.f;
        #pragma unroll
        for (int jj = 0; jj < 16; jj++) {
            int j = qr * 16 + jj;
            acc += Ab[i*LDA + j] * dqs[j];
        }
        acc += __shfl_xor(acc, 1, 64);
        acc += __shfl_xor(acc, 2, 64);
        if (qr == 0) epv[i] = acc;
    }
    __syncthreads();
    float ener2r = 0.f;
    if (tid < 64) {     // ener2 = 0.5 * dQ^T ep  (kept in a tid-0 register)
        float v = dqs[tid] * epv[tid];
        #pragma unroll
        for (int o = 1; o < 64; o <<= 1) v += __shfl_xor(v, o, 64);
        if (tid == 0) ener2r = 0.5f * v;
    }
    // 4) F = H - 0.5*S*(ep_i + ep_j) -> Ab.  FUSED: gather H here (idx+ws),
    //    write it to out (required output) and consume directly.
    #pragma unroll
    for (int m = 0; m < 16; m++) {
        int e = tid + m * 256;
        int i = e >> 6, j = e & 63;
        float hv;
        if (FUSED) {
            int id = idx_[gb + e];
            hv = (id >= 2 && id < ROTLENc) ? ws_[id - 2]
                                           : ((id == 1) ? 1.0f : 0.0f);
            outH[e] = hv;
        } else {
            hv = outH[e];
        }
        Ab[i*LDA + j] = hv - 0.5f * Vb[i*LDV + j] * (epv[i] + epv[j]);
    }
    __syncthreads();

    const int tx = tid & 15, ty = tid >> 4;
    const int row0 = ty * 4, col0 = tx * 4;
    float acc4[4][4];

    // 5) T1 = F @ phiS -> Vb   (phiS from global, float4; S dead)
    #pragma unroll
    for (int u = 0; u < 4; u++)
        #pragma unroll
        for (int v = 0; v < 4; v++) acc4[u][v] = 0.f;
    for (int k = 0; k < 64; k++) {
        float av[4];
        #pragma unroll
        for (int u = 0; u < 4; u++) av[u] = Ab[(row0 + u) * LDA + k];
        union { float4 v4; float f[4]; } b4;
        b4.v4 = P4[k * 16 + tx];             // phiS[k, col0..col0+3]
        #pragma unroll
        for (int u = 0; u < 4; u++)
            #pragma unroll
            for (int v = 0; v < 4; v++) acc4[u][v] += av[u] * b4.f[v];
    }
    #pragma unroll
    for (int u = 0; u < 4; u++)
        #pragma unroll
        for (int v = 0; v < 4; v++) Vb[(row0 + u) * LDV + col0 + v] = acc4[u][v];
    __syncthreads();

    // 6) fockp = phiS^T @ T1 -> Ab (+ diagonal copy into diagA);
    //    accumulate ||fockp||_F^2
    #pragma unroll
    for (int u = 0; u < 4; u++)
        #pragma unroll
        for (int v = 0; v < 4; v++) acc4[u][v] = 0.f;
    for (int k = 0; k < 64; k++) {
        union { float4 v4; float f[4]; } a4;
        a4.v4 = P4[k * 16 + ty];             // phiS[k, row0..row0+3]
        float bv[4];
        #pragma unroll
        for (int v = 0; v < 4; v++) bv[v] = Vb[k * LDV + col0 + v];
        #pragma unroll
        for (int u = 0; u < 4; u++)
            #pragma unroll
            for (int v = 0; v < 4; v++) acc4[u][v] += a4.f[u] * bv[v];
    }
    {
        float fr = 0.f;
        #pragma unroll
        for (int u = 0; u < 4; u++)
            #pragma unroll
            for (int v = 0; v < 4; v++) {
                Ab[(row0 + u) * LDA + col0 + v] = acc4[u][v];
                fr += acc4[u][v] * acc4[u][v];
            }
        if (tx == ty) {
            #pragma unroll
            for (int u = 0; u < 4; u++) diagA[row0 + u] = acc4[u][u];
        }
        red[tid] = fr;
    }
    __syncthreads();
    for (int sN = 128; sN > 0; sN >>= 1) {
        if (tid < sN) red[tid] += red[tid + sN];
        __syncthreads();
    }
    const float anorm2 = red[0];             // valid for all threads after barrier

    // 7) Vt = I (T1 dead)
    #pragma unroll
    for (int m = 0; m < 17; m++) {
        int e = tid + m * 256;
        if (e < Bc * LDV) Vb[e] = 0.f;
    }
    __syncthreads();
    if (tid < 64) { Vb[tid * LDV + tid] = 1.f; perm[tid] = tid; }

    const float skip2 = anorm2 * 1e-18f;
    const float conv2 = anorm2 * 4e-14f;

    // 8) upper-triangle fused 2x2 parallel cyclic Jacobi: 63 rounds/sweep.
    const int myi = tid & 31;                // own (Vt / phase-1) pair index
    const int jb  = tid >> 5;
    const int cb  = jb << 3;                 // Vt col chunk (8 cols)

    // own pair state (Vt rows; phase-1 angle inputs for tid<32)
    int myP = (myi == 0) ? 63 : myi;
    int myQ = (myi == 0) ? 0  : 63 - myi;
    int iPv = myP * LDV, iQv = myQ * LDV;

    // two unordered A-blocks per thread: flat upper-tri indices {tid, tid+256}
    int bi1, bj1, bi2 = 0, bj2 = 1;
    {
        int m = tid, i = 0;
        while (m >= 31 - i) { m -= 31 - i; ++i; }
        bi1 = i; bj1 = i + 1 + m;
    }
    const bool hasB2 = (tid + 256) < 496;
    if (hasB2) {
        int m = tid + 256, i = 0;
        while (m >= 31 - i) { m -= 31 - i; ++i; }
        bi2 = i; bj2 = i + 1 + m;
    }
    int pI1 = (bi1 == 0) ? 63 : bi1, qI1 = (bi1 == 0) ? 0 : 63 - bi1;
    int pJ1 = bj1,                   qJ1 = 63 - bj1;      // bj1 >= 1
    int pI2 = (bi2 == 0) ? 63 : bi2, qI2 = (bi2 == 0) ? 0 : 63 - bi2;
    int pJ2 = bj2,                   qJ2 = 63 - bj2;

    #define ADVI(v) v = ((v) == 62) ? 0 : (((v) == 63) ? 63 : (v) + 1)

    for (int sweep = 0; sweep < 10; ++sweep) {
        float offacc = 0.f;                  // valid in lanes tid<32 only
        for (int r = 0; r < 63; r++) {
            // --- phase 1: lanes 0-31: angles + closed-form diagonal update
            if (tid < 32) {
                float app = diagA[myP];
                float aqq = diagA[myQ];
                int mn = min(myP, myQ), mx = max(myP, myQ);
                int apqA = mn * LDA + mx;
                float apq = Ab[apqA];
                float a2 = apq * apq;
                offacc += a2;
                float c = 1.f, s = 0.f;
                if (a2 > skip2) {
                    float tau = (aqq - app) * __builtin_amdgcn_rcpf(apq + apq);
                    float tt = __builtin_amdgcn_rcpf(
                        fabsf(tau) + __builtin_amdgcn_sqrtf(1.f + tau * tau));
                    tt = (tau < 0.f) ? -tt : tt;
                    c = __builtin_amdgcn_rsqf(1.f + tt * tt);
                    s = tt * c;
                    diagA[myP] = app - tt * apq;
                    diagA[myQ] = aqq + tt * apq;
                    Ab[apqA] = 0.f;
                }
                csCS[myi] = make_float2(c, s);
            }
            __syncthreads();                 // angles + diag visible

            // --- phase 2: unordered A-blocks (canonical upper-tri cells)
            {
                float2 AI = csCS[bi1], AJ = csCS[bj1];
                if (AI.y != 0.f || AJ.y != 0.f) {
                    int mn, mx;
                    mn = min(pI1,pJ1); mx = max(pI1,pJ1); int aA = mn*LDA + mx;
                    mn = min(pI1,qJ1); mx = max(pI1,qJ1); int aB = mn*LDA + mx;
                    mn = min(qI1,pJ1); mx = max(qI1,pJ1); int aD = mn*LDA + mx;
                    mn = min(qI1,qJ1); mx = max(qI1,qJ1); int aE = mn*LDA + mx;
                    float a = Ab[aA], b = Ab[aB], d = Ab[aD], e = Ab[aE];
                    float a1 = AJ.x*a - AJ.y*b, b1 = AJ.y*a + AJ.x*b;
                    float d1 = AJ.x*d - AJ.y*e, e1 = AJ.y*d + AJ.x*e;
                    Ab[aA] = AI.x*a1 - AI.y*d1;
                    Ab[aD] = AI.y*a1 + AI.x*d1;
                    Ab[aB] = AI.x*b1 - AI.y*e1;
                    Ab[aE] = AI.y*b1 + AI.x*e1;
                }
            }
            if (hasB2) {
                float2 AI = csCS[bi2], AJ = csCS[bj2];
                if (AI.y != 0.f || AJ.y != 0.f) {
                    int mn, mx;
                    mn = min(pI2,pJ2); mx = max(pI2,pJ2); int aA = mn*LDA + mx;
                    mn = min(pI2,qJ2); mx = max(pI2,qJ2); int aB = mn*LDA + mx;
                    mn = min(qI2,pJ2); mx = max(qI2,pJ2); int aD = mn*LDA + mx;
                    mn = min(qI2,qJ2); mx = max(qI2,qJ2); int aE = mn*LDA + mx;
                    float a = Ab[aA], b = Ab[aB], d = Ab[aD], e = Ab[aE];
                    float a1 = AJ.x*a - AJ.y*b, b1 = AJ.y*a + AJ.x*b;
                    float d1 = AJ.x*d - AJ.y*e, e1 = AJ.y*d + AJ.x*e;
                    Ab[aA] = AI.x*a1 - AI.y*d1;
                    Ab[aD] = AI.y*a1 + AI.x*d1;
                    Ab[aB] = AI.x*b1 - AI.y*e1;
                    Ab[aE] = AI.y*b1 + AI.x*e1;
                }
            }
            // --- Vt row update (own angle, 8-col chunk, float4: uniform banks)
            {
                float2 me = csCS[myi];
                if (me.y != 0.f) {
                    const float cO = me.x, sO = me.y;
                    float4* vp = (float4*)&Vb[iPv + cb];
                    float4* vq = (float4*)&Vb[iQv + cb];
                    #pragma unroll
                    for (int e2 = 0; e2 < 2; e2++) {
                        float4 xp = vp[e2], xq = vq[e2];
                        float4 np, nq;
                        np.x = cO*xp.x - sO*xq.x;  nq.x = sO*xp.x + cO*xq.x;
                        np.y = cO*xp.y - sO*xq.y;  nq.y = sO*xp.y + cO*xq.y;
                        np.z = cO*xp.z - sO*xq.z;  nq.z = sO*xp.z + cO*xq.z;
                        np.w = cO*xp.w - sO*xq.w;  nq.w = sO*xp.w + cO*xq.w;
                        vp[e2] = np; vq[e2] = nq;
                    }
                }
            }
            // --- advance all pair states r -> r+1 (wraps continue across sweeps)
            iPv = (myP == 62) ? 0 : ((myP == 63) ? iPv : iPv + LDV);
            iQv = (myQ == 62) ? 0 : iQv + LDV;
            ADVI(myP); ADVI(myQ);
            ADVI(pI1); ADVI(qI1); ADVI(pJ1); ADVI(qJ1);
            ADVI(pI2); ADVI(qI2); ADVI(pJ2); ADVI(qJ2);
            __syncthreads();                 // all writes done before next angles
        }
        // sweep-end convergence: each pair counted exactly once (lanes 0-31)
        float t2 = offacc;
        #pragma unroll
        for (int o = 1; o < 32; o <<= 1) t2 += __shfl_xor(t2, o, 64);
        if (tid == 0) sOffArr[0] = t2;
        __syncthreads();
        if (sOffArr[0] < conv2) break;
        // next write to sOffArr is 63 barrier-separated rounds away -> safe
    }
    #undef ADVI

    // 9) eigenvalues (diagA) + ascending sort (rank by comparison, idx tiebreak)
    if (tid < 64) {
        float e = diagA[tid]; int rk = 0;
        for (int j = 0; j < 64; j++) {
            float ej = diagA[j];
            rk += (ej < e || (ej == e && j < tid)) ? 1 : 0;
        }
        rk &= 63;
        perm[rk] = tid;
        out[OFF_EORB + (size_t)g * 64 + rk] = e;
    }
    __syncthreads();

    // 10) orb = phiS @ V[:, perm] -> Ab ; V[k][pc] = Vt[pc][k]
    {
        int pc0 = perm[col0 + 0] & 63, pc1 = perm[col0 + 1] & 63;
        int pc2 = perm[col0 + 2] & 63, pc3 = perm[col0 + 3] & 63;
        #pragma unroll
        for (int u = 0; u < 4; u++)
            #pragma unroll
            for (int v = 0; v < 4; v++) acc4[u][v] = 0.f;
        for (int kk = 0; kk < 16; kk++) {
            union { float4 v4; float f[4]; } a0, a1, a2u, a3;
            a0.v4  = P4[(row0 + 0) * 16 + kk];
            a1.v4  = P4[(row0 + 1) * 16 + kk];
            a2u.v4 = P4[(row0 + 2) * 16 + kk];
            a3.v4  = P4[(row0 + 3) * 16 + kk];
            #pragma unroll
            for (int t = 0; t < 4; t++) {
                int k = (kk << 2) + t;
                float b0 = Vb[pc0*LDV + k], b1 = Vb[pc1*LDV + k];
                float b2 = Vb[pc2*LDV + k], b3 = Vb[pc3*LDV + k];
                acc4[0][0] += a0.f[t]  * b0; acc4[0][1] += a0.f[t]  * b1;
                acc4[0][2] += a0.f[t]  * b2; acc4[0][3] += a0.f[t]  * b3;
                acc4[1][0] += a1.f[t]  * b0; acc4[1][1] += a1.f[t]  * b1;
                acc4[1][2] += a1.f[t]  * b2; acc4[1][3] += a1.f[t]  * b3;
                acc4[2][0] += a2u.f[t] * b0; acc4[2][1] += a2u.f[t] * b1;
                acc4[2][2] += a2u.f[t] * b2; acc4[2][3] += a2u.f[t] * b3;
                acc4[3][0] += a3.f[t]  * b0; acc4[3][1] += a3.f[t]  * b1;
                acc4[3][2] += a3.f[t]  * b2; acc4[3][3] += a3.f[t]  * b3;
            }
        }
        __syncthreads();
        #pragma unroll
        for (int u = 0; u < 4; u++)
            #pragma unroll
            for (int v = 0; v < 4; v++) Ab[(row0 + u) * LDA + col0 + v] = acc4[u][v];
    }
    __syncthreads();
    #pragma unroll
    for (int m = 0; m < 16; m++) {
        int e = tid + m * 256;
        int i = e >> 6, j = e & 63;
        Ab[i*LDA + j] *= Mp[e];
    }
    __syncthreads();

    // 11) rho_out = 2 * Ab @ Ab^T ; ener1 = sum(rho_out * H)
    #pragma unroll
    for (int u = 0; u < 4; u++)
        #pragma unroll
        for (int v = 0; v < 4; v++) acc4[u][v] = 0.f;
    for (int k = 0; k < 64; k++) {
        float av[4], bv[4];
        #pragma unroll
        for (int u = 0; u < 4; u++) av[u] = Ab[(row0 + u) * LDA + k];
        #pragma unroll
        for (int v = 0; v < 4; v++) bv[v] = Ab[(col0 + v) * LDA + k];
        #pragma unroll
        for (int u = 0; u < 4; u++)
            #pragma unroll
            for (int v = 0; v < 4; v++) acc4[u][v] += av[u] * bv[v];
    }
    {
        float e1 = 0.f;
        float* outR = out + OFF_RHO + gb;
        #pragma unroll
        for (int u = 0; u < 4; u++)
            #pragma unroll
            for (int v = 0; v < 4; v++) {
                float rv = 2.f * acc4[u][v];
                int i = row0 + u, j = col0 + v;
                outR[i * 64 + j] = rv;
                e1 += rv * outH[i * 64 + j];
            }
        red[tid] = e1;
    }
    __syncthreads();
    for (int sN = 128; sN > 0; sN >>= 1) {
        if (tid < sN) red[tid] += red[tid + sN];
        __syncthreads();
    }
    if (tid == 0) out[OFF_EELEC + g] = red[0] + ener2r;
    if (tid < 64) out[OFF_DQ + (size_t)g * 64 + tid] = dqs[tid];

    // 12) fused erep reduction (sOffArr free after Jacobi; barrier above
    //     separates its last Jacobi read from this write)
    if (FUSED) {
        #pragma unroll
        for (int o = 1; o < 64; o <<= 1) racc += __shfl_xor(racc, o, 64);
        if ((tid & 63) == 0) sOffArr[tid >> 6] = racc;
        __syncthreads();
        if (tid == 0)
            out[OFF_EREP + g] = sOffArr[0] + sOffArr[1] + sOffArr[2] + sOffArr[3];
    }
}

// ---------------------------------------------------------------- launcher
extern "C" void kernel_launch(void* const* d_in, const int* in_sizes, int n_in,
                              void* d_out, int out_size, void* d_ws, size_t ws_size,
                              hipStream_t stream)
{
    (void)in_sizes; (void)n_in; (void)out_size;
    const float* net_vals    = (const float*)d_in[0];
    const float* rot_tensors = (const float*)d_in[1];
    const float* S           = (const float*)d_in[2];
    const float* G           = (const float*)d_in[3];
    const float* rho         = (const float*)d_in[4];
    const float* qneutral    = (const float*)d_in[5];
    const float* mask        = (const float*)d_in[6];
    const float* phiS        = (const float*)d_in[7];
    const float* zcounts     = (const float*)d_in[8];
    const float* ref_vars    = (const float*)d_in[9];
    const int* gather_rot    = (const int*)d_in[10];
    const int* gather_oper   = (const int*)d_in[11];
    const int* gather_rep    = (const int*)d_in[12];
    const int* segsum_rep    = (const int*)d_in[13];

    float* out = (float*)d_out;

    const size_t need = (size_t)Rc * 9 * sizeof(float);   // 36 MB
    if (d_ws && ws_size >= need) {
        k_rot<<<(Rc + 255) / 256, 256, 0, stream>>>(rot_tensors, gather_rot,
                                                    net_vals, (float*)d_ws);
        k_geom<1><<<NGc, 256, 0, stream>>>(S, G, rho, qneutral, mask, phiS,
                                           gather_oper, (const float*)d_ws,
                                           net_vals, gather_rep, segsum_rep,
                                           zcounts, ref_vars, out);
    } else {
        k_hgather<<<16384, 256, 0, stream>>>(gather_oper, rot_tensors, gather_rot,
                                             net_vals, out);
        k_erep_seg<<<NGc, 256, 0, stream>>>(net_vals, gather_rep, segsum_rep,
                                            zcounts, ref_vars, out);
        k_geom<0><<<NGc, 256, 0, stream>>>(S, G, rho, qneutral, mask, phiS,
                                           nullptr, nullptr, nullptr,
                                           nullptr, nullptr, nullptr, nullptr,
                                           out);
    }
}